// Round 2
// baseline (2461.893 us; speedup 1.0000x reference)
//
#include <hip/hip_runtime.h>
#include <math.h>

// Problem constants
#define NN   20000     // nodes
#define NE   320000    // edges
#define NIN  128       // node input dim
#define HC   256       // heads(4) * hidden(64)

typedef unsigned short u16;

__device__ __forceinline__ float bf2f(u16 u) {
  union { unsigned int i; float f; } x;
  x.i = ((unsigned int)u) << 16;
  return x.f;
}
__device__ __forceinline__ u16 f2bf(float f) {
  union { float f; unsigned int i; } x;
  x.f = f;
  unsigned int r = x.i + 0x7fffu + ((x.i >> 16) & 1u);
  return (u16)(r >> 16);
}

// dtype-flexible loads (flags detected on device each launch)
__device__ __forceinline__ float ldf(const void* p, int i, bool fbf) {
  return fbf ? bf2f(((const u16*)p)[i]) : ((const float*)p)[i];
}
__device__ __forceinline__ int ldsrc(const void* p, int e, bool is64) {
  const int* p32 = (const int*)p;
  return is64 ? p32[2 * e] : p32[e];           // int64 little-endian low word
}
__device__ __forceinline__ int lddst(const void* p, int e, bool is64) {
  const int* p32 = (const int*)p;
  return is64 ? p32[2 * (NE + e)] : p32[NE + e];
}
__device__ __forceinline__ void stout(void* p, int i, float v, bool fbf) {
  if (fbf) ((u16*)p)[i] = f2bf(v);
  else ((float*)p)[i] = v;
}

// ---------------- detection + div_term init ----------------
__global__ void devinit_kernel(const void* __restrict__ eidx,
                               const void* __restrict__ nemb,
                               int* __restrict__ flags, float* __restrict__ divt) {
  int lane = threadIdx.x;
  if (lane < 32) {
    // match np: div = exp(f32( (2i) * f32(-ln(10000)/64) )), correctly rounded
    const float c32 = (float)(-0.14391156831212787);
    float prod = (float)(2 * lane) * c32;
    divt[lane] = (float)exp((double)prod);
  }
  if (lane == 0) {
    const int* p32 = (const int*)eidx;
    int is64 = 1;
    for (int i = 1; i < 128; i += 2)
      if (p32[i] != 0) { is64 = 0; break; }
    const u16* q16 = (const u16*)nemb;
    int fbf = 1;
    for (int i = 0; i < 128; i += 2) {   // even u16s = fp32 low halves if fp32
      unsigned e = (q16[i] >> 7) & 0xFF;
      if (e < 90 || e > 140) { fbf = 0; break; }
    }
    flags[0] = is64;
    flags[1] = fbf;
  }
}

__global__ void sentinel_kernel(const int* __restrict__ flags, void* __restrict__ out) {
  int i = blockIdx.x * 256 + threadIdx.x;
  if (i < NE) stout(out, i, 3000.0f, flags[1] != 0);
}
__global__ void raw_sentinel_kernel(u16* __restrict__ out) {
  int i = blockIdx.x * 256 + threadIdx.x;
  if (i < NE) out[i] = f2bf(3000.0f);
}

// ---------------- CSR build ----------------
__global__ void zero_kernel(int* __restrict__ p, int n) {
  int i = blockIdx.x * 256 + threadIdx.x;
  if (i < n) p[i] = 0;
}

__global__ void hist_kernel(const int* __restrict__ flags, const void* __restrict__ eidx,
                            int* __restrict__ cnt) {
  bool is64 = flags[0] != 0;
  int e = blockIdx.x * 256 + threadIdx.x;
  if (e < NE) {
    int d = lddst(eidx, e, is64);
    if ((unsigned)d < NN) atomicAdd(&cnt[d], 1);
  }
}

// single-wave exclusive scan: cnt[n] -> offsets[n+1]
__global__ void scan_kernel(const int* __restrict__ cnt, int* __restrict__ offsets, int n) {
  int lane = threadIdx.x;  // 64 threads, 1 block
  int carry = 0;
  for (int base = 0; base <= n; base += 64) {
    int i = base + lane;
    int self = (i < n) ? cnt[i] : 0;
    int x = self;
    for (int off = 1; off < 64; off <<= 1) {
      int y = __shfl_up(x, off);
      if (lane >= off) x += y;
    }
    if (i <= n) offsets[i] = carry + x - self;
    carry += __shfl(x, 63);
  }
}

__global__ void copy_kernel(const int* __restrict__ a, int* __restrict__ b, int n) {
  int i = blockIdx.x * 256 + threadIdx.x;
  if (i < n) b[i] = a[i];
}

__global__ void fill_kernel(const int* __restrict__ flags, const void* __restrict__ eidx,
                            int* __restrict__ cursor, int* __restrict__ esorted) {
  bool is64 = flags[0] != 0;
  int e = blockIdx.x * 256 + threadIdx.x;
  if (e < NE) {
    int d = lddst(eidx, e, is64);
    if ((unsigned)d < NN) {
      int pos = atomicAdd(&cursor[d], 1);
      if ((unsigned)pos < NE) esorted[pos] = e;
    }
  }
}

// ---------------- GEMM: C[M,256] = A[M,K] @ W[K,256] + bias (fp32 accum) ----------------
// AWS=false: A is a raw input (dtype per flag); AWS=true: A is fp32 workspace.
template <bool AWS>
__global__ __launch_bounds__(256) void gemm256(
    const int* __restrict__ flags, const void* __restrict__ Ap,
    const void* __restrict__ W, const void* __restrict__ bias,
    float* __restrict__ C, int M, int K) {
  bool fbf = flags[1] != 0;
  __shared__ float As[64][17];
  __shared__ float Ws[16][65];
  int tid = threadIdx.x;
  int rb = blockIdx.x * 64;
  int cb = blockIdx.y * 64;
  int ty = tid >> 4, tx = tid & 15;

  float acc[4][4] = {{0.f}};

  int ar = tid >> 2;          // 0..63
  int ak = (tid & 3) << 2;    // 0,4,8,12
  int wr = tid >> 4;          // 0..15
  int wc = (tid & 15) << 2;   // 0..60

  for (int kb = 0; kb < K; kb += 16) {
    int grow = rb + ar;
#pragma unroll
    for (int i = 0; i < 4; ++i) {
      float a = 0.f;
      if (grow < M) {
        int idx = grow * K + kb + ak + i;
        if constexpr (AWS) a = ((const float*)Ap)[idx];
        else               a = ldf(Ap, idx, fbf);
      }
      As[ar][ak + i] = a;
    }
#pragma unroll
    for (int i = 0; i < 4; ++i)
      Ws[wr][wc + i] = ldf(W, (kb + wr) * HC + cb + wc + i, fbf);

    __syncthreads();
#pragma unroll
    for (int kk = 0; kk < 16; ++kk) {
      float a[4], b[4];
#pragma unroll
      for (int i = 0; i < 4; ++i) a[i] = As[ty * 4 + i][kk];
#pragma unroll
      for (int j = 0; j < 4; ++j) b[j] = Ws[kk][tx * 4 + j];
#pragma unroll
      for (int i = 0; i < 4; ++i)
#pragma unroll
        for (int j = 0; j < 4; ++j) acc[i][j] += a[i] * b[j];
    }
    __syncthreads();
  }

  float bv[4];
#pragma unroll
  for (int j = 0; j < 4; ++j) bv[j] = ldf(bias, cb + tx * 4 + j, fbf);
#pragma unroll
  for (int i = 0; i < 4; ++i) {
    int r = rb + ty * 4 + i;
    if (r < M) {
      float* Cr = C + (size_t)r * HC + cb + tx * 4;
#pragma unroll
      for (int j = 0; j < 4; ++j) Cr[j] = acc[i][j] + bv[j];
    }
  }
}

// ---------------- qproj[n,h,j] = sum_c q[n,h*64+c]*wt[j,h*64+c]; qbt[n,h]=q_h . bt_h
__global__ __launch_bounds__(256) void qproj_kernel(
    const int* __restrict__ flags, const float* __restrict__ q,
    const void* __restrict__ wt, const void* __restrict__ bt,
    float* __restrict__ qproj, float* __restrict__ qbt) {
  bool fbf = flags[1] != 0;
  __shared__ float qs[256];
  int t = threadIdx.x;
  int h = t >> 6, j = t & 63;
  int n = blockIdx.x;
  qs[t] = q[(size_t)n * HC + t];
  __syncthreads();
  float acc = 0.f;
  const float* qrow = qs + h * 64;
  int wbase = j * HC + h * 64;
#pragma unroll 8
  for (int c = 0; c < 64; ++c) acc += qrow[c] * ldf(wt, wbase + c, fbf);
  qproj[(size_t)n * HC + h * 64 + j] = acc;
  float pb = qs[t] * ldf(bt, t, fbf);
  for (int off = 32; off; off >>= 1) pb += __shfl_xor(pb, off);
  if (j == 0) qbt[n * 4 + h] = pb;
}

// ---------------- per-edge alpha (sorted position), one wave per edge ----------------
__global__ __launch_bounds__(256) void alpha_kernel(
    const int* __restrict__ flags, const void* __restrict__ eidx,
    const int* __restrict__ esorted, const void* __restrict__ rawt,
    const void* __restrict__ noise, const float* __restrict__ q,
    const float* __restrict__ k, const float* __restrict__ qproj,
    const float* __restrict__ qbt, const float* __restrict__ divt,
    float4* __restrict__ alpha4) {
  bool is64 = flags[0] != 0, fbf = flags[1] != 0;
  int p = blockIdx.x * 4 + (threadIdx.x >> 6);
  if (p >= NE) return;
  int lane = threadIdx.x & 63;
  int e = esorted[p];
  if ((unsigned)e >= NE) {
    if (lane == 0) alpha4[p] = make_float4(0.f, 0.f, 0.f, 0.f);
    return;
  }
  int src = ldsrc(eidx, e, is64);
  int dst = lddst(eidx, e, is64);
  if ((unsigned)src >= NN) src = 0;
  if ((unsigned)dst >= NN) dst = 0;
  float tt = ldf(rawt, e, fbf) + ldf(noise, e, fbf);
  float arg = tt * divt[lane >> 1];
  float te = (lane & 1) ? cosf(arg) : sinf(arg);  // te[2i]=sin, te[2i+1]=cos
  const float* qrow = q + (size_t)dst * HC;
  const float* krow = k + (size_t)src * HC;
  const float* prow = qproj + (size_t)dst * HC;
  float a0 = qrow[lane]       * krow[lane]       + te * prow[lane];
  float a1 = qrow[64 + lane]  * krow[64 + lane]  + te * prow[64 + lane];
  float a2 = qrow[128 + lane] * krow[128 + lane] + te * prow[128 + lane];
  float a3 = qrow[192 + lane] * krow[192 + lane] + te * prow[192 + lane];
  for (int off = 32; off; off >>= 1) {
    a0 += __shfl_xor(a0, off);
    a1 += __shfl_xor(a1, off);
    a2 += __shfl_xor(a2, off);
    a3 += __shfl_xor(a3, off);
  }
  if (lane == 0) {
    const float* qb = qbt + dst * 4;
    alpha4[p] = make_float4((a0 + qb[0]) * 0.125f, (a1 + qb[1]) * 0.125f,
                            (a2 + qb[2]) * 0.125f, (a3 + qb[3]) * 0.125f);
  }
}

// ---------------- segment softmax + aggregation + relu ----------------
__global__ __launch_bounds__(256) void aggregate_kernel(
    const int* __restrict__ flags, const void* __restrict__ eidx,
    const int* __restrict__ esorted, const int* __restrict__ offsets,
    const float4* __restrict__ alpha4, const float* __restrict__ v,
    float* __restrict__ xout) {
  bool is64 = flags[0] != 0;
  int n = blockIdx.x;
  int t = threadIdx.x;
  int h = t >> 6;
  int s0 = offsets[n], s1 = offsets[n + 1];
  if (s0 < 0) s0 = 0;
  if (s1 > NE) s1 = NE;
  float m = -INFINITY;
  for (int p = s0; p < s1; ++p) {
    float4 a = alpha4[p];
    float av = (h == 0) ? a.x : (h == 1) ? a.y : (h == 2) ? a.z : a.w;
    m = fmaxf(m, av);
  }
  float denom = 0.f, acc = 0.f;
  for (int p = s0; p < s1; ++p) {
    float4 a = alpha4[p];
    float av = (h == 0) ? a.x : (h == 1) ? a.y : (h == 2) ? a.z : a.w;
    float ea = expf(av - m);
    denom += ea;
    int e = esorted[p];
    if ((unsigned)e >= NE) continue;
    int src = ldsrc(eidx, e, is64);
    if ((unsigned)src >= NN) src = 0;
    acc += ea * v[(size_t)src * HC + t];
  }
  float r = acc / (denom + 1e-16f);
  xout[(size_t)n * HC + t] = fmaxf(r, 0.f);
}

// ---------------- final: out[e] = (x[src]+x[dst]) . wc + bc ----------------
__global__ __launch_bounds__(256) void final_kernel(
    const int* __restrict__ flags, const void* __restrict__ eidx,
    const float* __restrict__ x, const void* __restrict__ wc,
    const void* __restrict__ bc, void* __restrict__ out) {
  bool is64 = flags[0] != 0, fbf = flags[1] != 0;
  int p = blockIdx.x * 4 + (threadIdx.x >> 6);
  if (p >= NE) return;
  int lane = threadIdx.x & 63;
  int src = ldsrc(eidx, p, is64);
  int dst = lddst(eidx, p, is64);
  if ((unsigned)src >= NN) src = 0;
  if ((unsigned)dst >= NN) dst = 0;
  const float* xs = x + (size_t)src * HC;
  const float* xd = x + (size_t)dst * HC;
  float s = 0.f;
#pragma unroll
  for (int r = 0; r < 4; ++r) {
    int t = r * 64 + lane;
    s += (xs[t] + xd[t]) * ldf(wc, t, fbf);
  }
  for (int off = 32; off; off >>= 1) s += __shfl_xor(s, off);
  if (lane == 0) stout(out, p, s + ldf(bc, 0, fbf), fbf);
}

extern "C" void kernel_launch(void* const* d_in, const int* in_sizes, int n_in,
                              void* d_out, int out_size, void* d_ws, size_t ws_size,
                              hipStream_t stream) {
  const void* eidx  = d_in[0];
  const void* rawt  = d_in[1];
  const void* noise = d_in[2];
  const void* nemb  = d_in[3];
  const void *wq1 = d_in[4],  *bq1 = d_in[5];
  const void *wk1 = d_in[6],  *bk1 = d_in[7];
  const void *wv1 = d_in[8],  *bv1 = d_in[9];
  const void *wt1 = d_in[10], *bt1 = d_in[11];
  const void *wq2 = d_in[12], *bq2 = d_in[13];
  const void *wk2 = d_in[14], *bk2 = d_in[15];
  const void *wv2 = d_in[16], *bv2 = d_in[17];
  const void *wt2 = d_in[18], *bt2 = d_in[19];
  const void *wcp = d_in[20], *bcp = d_in[21];

  char* ws = (char*)d_ws;
  size_t off = 0;
  auto alloc = [&](size_t bytes) -> void* {
    void* p = ws + off;
    off += (bytes + 255) & ~(size_t)255;
    return p;
  };
  int*   flags = (int*)alloc(256);
  float* divt  = (float*)alloc(256);
  float* q     = (float*)alloc((size_t)NN * HC * 4);
  float* k     = (float*)alloc((size_t)NN * HC * 4);
  float* v     = (float*)alloc((size_t)NN * HC * 4);
  float* qproj = (float*)alloc((size_t)NN * HC * 4);
  float* qbt   = (float*)alloc((size_t)NN * 4 * 4);
  int* offsets = (int*)alloc((size_t)(NN + 1) * 4);
  int* cursor  = (int*)alloc((size_t)NN * 4);
  int* esorted = (int*)alloc((size_t)NE * 4);
  float4* alpha = (float4*)alloc((size_t)NE * 16);
  float* x1 = qproj;  // aggregate L1 writes AFTER alpha L1 consumed qproj
  float* x2 = q;      // aggregate L2 writes AFTER alpha L2 consumed q
  size_t need = off;

  int gN = (NN + 255) / 256, gE = (NE + 255) / 256, gEdge = (NE + 3) / 4;

  if (ws_size < 1024) {  // can't even store flags: raw diagnostic
    raw_sentinel_kernel<<<gE, 256, 0, stream>>>((u16*)d_out);
    return;
  }
  devinit_kernel<<<1, 64, 0, stream>>>(eidx, nemb, flags, divt);
  if (need > ws_size) {  // workspace too small: diagnostic sentinel 3000
    sentinel_kernel<<<gE, 256, 0, stream>>>(flags, d_out);
    return;
  }

  // CSR by dst
  zero_kernel<<<gN, 256, 0, stream>>>(cursor, NN);
  hist_kernel<<<gE, 256, 0, stream>>>(flags, eidx, cursor);
  scan_kernel<<<1, 64, 0, stream>>>(cursor, offsets, NN);
  copy_kernel<<<gN, 256, 0, stream>>>(offsets, cursor, NN);
  fill_kernel<<<gE, 256, 0, stream>>>(flags, eidx, cursor, esorted);

  dim3 gg((NN + 63) / 64, 4);

  // Layer 1 (A = raw node_emb, K=128)
  gemm256<false><<<gg, 256, 0, stream>>>(flags, nemb, wq1, bq1, q, NN, NIN);
  gemm256<false><<<gg, 256, 0, stream>>>(flags, nemb, wk1, bk1, k, NN, NIN);
  gemm256<false><<<gg, 256, 0, stream>>>(flags, nemb, wv1, bv1, v, NN, NIN);
  qproj_kernel<<<NN, 256, 0, stream>>>(flags, q, wt1, bt1, qproj, qbt);
  alpha_kernel<<<gEdge, 256, 0, stream>>>(flags, eidx, esorted, rawt, noise, q, k, qproj, qbt, divt, alpha);
  aggregate_kernel<<<NN, 256, 0, stream>>>(flags, eidx, esorted, offsets, alpha, v, x1);

  // Layer 2 (A = fp32 x1, K=256)
  gemm256<true><<<gg, 256, 0, stream>>>(flags, x1, wq2, bq2, q, NN, HC);
  gemm256<true><<<gg, 256, 0, stream>>>(flags, x1, wk2, bk2, k, NN, HC);
  gemm256<true><<<gg, 256, 0, stream>>>(flags, x1, wv2, bv2, v, NN, HC);
  qproj_kernel<<<NN, 256, 0, stream>>>(flags, q, wt2, bt2, qproj, qbt);
  alpha_kernel<<<gEdge, 256, 0, stream>>>(flags, eidx, esorted, rawt, noise, q, k, qproj, qbt, divt, alpha);
  aggregate_kernel<<<NN, 256, 0, stream>>>(flags, eidx, esorted, offsets, alpha, v, x2);

  // Edge scorer
  final_kernel<<<gEdge, 256, 0, stream>>>(flags, eidx, x2, wcp, bcp, d_out);
}

// Round 3
// 1351.226 us; speedup vs baseline: 1.8220x; 1.8220x over previous
//
#include <hip/hip_runtime.h>
#include <math.h>

// Problem constants
#define NN   20000     // nodes
#define NE   320000    // edges
#define NIN  128       // node input dim
#define HC   256       // heads(4) * hidden(64)

typedef unsigned short u16;

__device__ __forceinline__ float bf2f(u16 u) {
  union { unsigned int i; float f; } x;
  x.i = ((unsigned int)u) << 16;
  return x.f;
}
__device__ __forceinline__ u16 f2bf(float f) {
  union { float f; unsigned int i; } x;
  x.f = f;
  unsigned int r = x.i + 0x7fffu + ((x.i >> 16) & 1u);
  return (u16)(r >> 16);
}

// dtype-flexible loads (flags detected on device each launch)
__device__ __forceinline__ float ldf(const void* p, int i, bool fbf) {
  return fbf ? bf2f(((const u16*)p)[i]) : ((const float*)p)[i];
}
__device__ __forceinline__ int ldsrc(const void* p, int e, bool is64) {
  const int* p32 = (const int*)p;
  return is64 ? p32[2 * e] : p32[e];
}
__device__ __forceinline__ int lddst(const void* p, int e, bool is64) {
  const int* p32 = (const int*)p;
  return is64 ? p32[2 * (NE + e)] : p32[NE + e];
}
__device__ __forceinline__ void stout(void* p, int i, float v, bool fbf) {
  if (fbf) ((u16*)p)[i] = f2bf(v);
  else ((float*)p)[i] = v;
}

// ---------------- detection + div_term init ----------------
__global__ void devinit_kernel(const void* __restrict__ eidx,
                               const void* __restrict__ nemb,
                               int* __restrict__ flags, float* __restrict__ divt) {
  int lane = threadIdx.x;
  if (lane < 32) {
    const float c32 = (float)(-0.14391156831212787);
    float prod = (float)(2 * lane) * c32;
    divt[lane] = (float)exp((double)prod);
  }
  if (lane == 0) {
    const int* p32 = (const int*)eidx;
    int is64 = 1;
    for (int i = 1; i < 128; i += 2)
      if (p32[i] != 0) { is64 = 0; break; }
    const u16* q16 = (const u16*)nemb;
    int fbf = 1;
    for (int i = 0; i < 128; i += 2) {
      unsigned e = (q16[i] >> 7) & 0xFF;
      if (e < 90 || e > 140) { fbf = 0; break; }
    }
    flags[0] = is64;
    flags[1] = fbf;
  }
}

__global__ void sentinel_kernel(const int* __restrict__ flags, void* __restrict__ out) {
  int i = blockIdx.x * 256 + threadIdx.x;
  if (i < NE) stout(out, i, 3000.0f, flags[1] != 0);
}
__global__ void raw_sentinel_kernel(u16* __restrict__ out) {
  int i = blockIdx.x * 256 + threadIdx.x;
  if (i < NE) out[i] = f2bf(3000.0f);
}

// ---------------- CSR build ----------------
__global__ void zero_kernel(int* __restrict__ p, int n) {
  int i = blockIdx.x * 256 + threadIdx.x;
  if (i < n) p[i] = 0;
}

__global__ void hist_kernel(const int* __restrict__ flags, const void* __restrict__ eidx,
                            int* __restrict__ cnt) {
  bool is64 = flags[0] != 0;
  int e = blockIdx.x * 256 + threadIdx.x;
  if (e < NE) {
    int d = lddst(eidx, e, is64);
    if ((unsigned)d < NN) atomicAdd(&cnt[d], 1);
  }
}

__global__ void scan_kernel(const int* __restrict__ cnt, int* __restrict__ offsets, int n) {
  int lane = threadIdx.x;  // 64 threads, 1 block
  int carry = 0;
  for (int base = 0; base <= n; base += 64) {
    int i = base + lane;
    int self = (i < n) ? cnt[i] : 0;
    int x = self;
    for (int off = 1; off < 64; off <<= 1) {
      int y = __shfl_up(x, off);
      if (lane >= off) x += y;
    }
    if (i <= n) offsets[i] = carry + x - self;
    carry += __shfl(x, 63);
  }
}

__global__ void copy_kernel(const int* __restrict__ a, int* __restrict__ b, int n) {
  int i = blockIdx.x * 256 + threadIdx.x;
  if (i < n) b[i] = a[i];
}

__global__ void fill_kernel(const int* __restrict__ flags, const void* __restrict__ eidx,
                            int* __restrict__ cursor, int* __restrict__ esorted) {
  bool is64 = flags[0] != 0;
  int e = blockIdx.x * 256 + threadIdx.x;
  if (e < NE) {
    int d = lddst(eidx, e, is64);
    if ((unsigned)d < NN) {
      int pos = atomicAdd(&cursor[d], 1);
      if ((unsigned)pos < NE) esorted[pos] = e;
    }
  }
}

// ---------------- build block-diagonal WT[256][256] (fp32) from wt[64,256] ----------------
// WT[h*64+c][h*64+j] = wt[j*HC + h*64 + c]; off-diagonal blocks = 0
__global__ void buildwt_kernel(const int* __restrict__ flags, const void* __restrict__ wt,
                               float* __restrict__ WT) {
  bool fbf = flags[1] != 0;
  int idx = blockIdx.x * 256 + threadIdx.x;   // 65536 total
  int r = idx >> 8, col = idx & 255;
  int hr = r >> 6, hc = col >> 6;
  float v = 0.f;
  if (hr == hc) {
    int c = r & 63, j = col & 63;
    v = ldf(wt, j * HC + hr * 64 + c, fbf);
  }
  WT[idx] = v;
}

// ---------------- qbt[n,h] = q[n,h,:] . bt[h,:] ----------------
__global__ __launch_bounds__(256) void qbt_kernel(
    const int* __restrict__ flags, const float* __restrict__ q,
    const void* __restrict__ bt, float* __restrict__ qbt) {
  bool fbf = flags[1] != 0;
  int t = threadIdx.x;
  int n = blockIdx.x;
  int h = t >> 6, j = t & 63;
  float pb = q[(size_t)n * HC + t] * ldf(bt, t, fbf);
  for (int off = 32; off; off >>= 1) pb += __shfl_xor(pb, off);
  if (j == 0) qbt[n * 4 + h] = pb;
}

// ---------------- GEMM: C[M,256] = A[M,K] @ W[K,256] + bias (fp32 accum) ----------------
// AWS: A is fp32 workspace (else raw input per flag). WF32: W/bias are fp32 ws.
template <bool AWS, bool WF32>
__global__ __launch_bounds__(256) void gemm256(
    const int* __restrict__ flags, const void* __restrict__ Ap,
    const void* __restrict__ W, const void* __restrict__ bias,
    float* __restrict__ C, int M, int K) {
  bool fbf = flags[1] != 0;
  __shared__ float As[64][17];
  __shared__ float Ws[16][65];
  int tid = threadIdx.x;
  int rb = blockIdx.x * 64;
  int cb = blockIdx.y * 64;
  int ty = tid >> 4, tx = tid & 15;

  float acc[4][4] = {{0.f}};

  int ar = tid >> 2;          // 0..63
  int ak = (tid & 3) << 2;    // 0,4,8,12
  int wr = tid >> 4;          // 0..15
  int wc = (tid & 15) << 2;   // 0..60

  for (int kb = 0; kb < K; kb += 16) {
    int grow = rb + ar;
#pragma unroll
    for (int i = 0; i < 4; ++i) {
      float a = 0.f;
      if (grow < M) {
        int idx = grow * K + kb + ak + i;
        if constexpr (AWS) a = ((const float*)Ap)[idx];
        else               a = ldf(Ap, idx, fbf);
      }
      As[ar][ak + i] = a;
    }
#pragma unroll
    for (int i = 0; i < 4; ++i) {
      int widx = (kb + wr) * HC + cb + wc + i;
      if constexpr (WF32) Ws[wr][wc + i] = ((const float*)W)[widx];
      else                Ws[wr][wc + i] = ldf(W, widx, fbf);
    }

    __syncthreads();
#pragma unroll
    for (int kk = 0; kk < 16; ++kk) {
      float a[4], b[4];
#pragma unroll
      for (int i = 0; i < 4; ++i) a[i] = As[ty * 4 + i][kk];
#pragma unroll
      for (int j = 0; j < 4; ++j) b[j] = Ws[kk][tx * 4 + j];
#pragma unroll
      for (int i = 0; i < 4; ++i)
#pragma unroll
        for (int j = 0; j < 4; ++j) acc[i][j] += a[i] * b[j];
    }
    __syncthreads();
  }

  float bv[4];
#pragma unroll
  for (int j = 0; j < 4; ++j) {
    int bidx = cb + tx * 4 + j;
    if constexpr (WF32) bv[j] = ((const float*)bias)[bidx];
    else                bv[j] = ldf(bias, bidx, fbf);
  }
#pragma unroll
  for (int i = 0; i < 4; ++i) {
    int r = rb + ty * 4 + i;
    if (r < M) {
      float* Cr = C + (size_t)r * HC + cb + tx * 4;
#pragma unroll
      for (int j = 0; j < 4; ++j) Cr[j] = acc[i][j] + bv[j];
    }
  }
}

// ---------------- per-edge alpha (sorted position), one wave per edge ----------------
__global__ __launch_bounds__(256) void alpha_kernel(
    const int* __restrict__ flags, const void* __restrict__ eidx,
    const int* __restrict__ esorted, const void* __restrict__ rawt,
    const void* __restrict__ noise, const float* __restrict__ q,
    const float* __restrict__ k, const float* __restrict__ qproj,
    const float* __restrict__ qbt, const float* __restrict__ divt,
    float4* __restrict__ alpha4) {
  bool is64 = flags[0] != 0, fbf = flags[1] != 0;
  int p = blockIdx.x * 4 + (threadIdx.x >> 6);
  if (p >= NE) return;
  int lane = threadIdx.x & 63;
  int e = esorted[p];
  if ((unsigned)e >= NE) {
    if (lane == 0) alpha4[p] = make_float4(0.f, 0.f, 0.f, 0.f);
    return;
  }
  int src = ldsrc(eidx, e, is64);
  int dst = lddst(eidx, e, is64);
  if ((unsigned)src >= NN) src = 0;
  if ((unsigned)dst >= NN) dst = 0;
  float tt = ldf(rawt, e, fbf) + ldf(noise, e, fbf);
  float arg = tt * divt[lane >> 1];
  float te = (lane & 1) ? cosf(arg) : sinf(arg);  // te[2i]=sin, te[2i+1]=cos
  const float* qrow = q + (size_t)dst * HC;
  const float* krow = k + (size_t)src * HC;
  const float* prow = qproj + (size_t)dst * HC;
  float a0 = qrow[lane]       * krow[lane]       + te * prow[lane];
  float a1 = qrow[64 + lane]  * krow[64 + lane]  + te * prow[64 + lane];
  float a2 = qrow[128 + lane] * krow[128 + lane] + te * prow[128 + lane];
  float a3 = qrow[192 + lane] * krow[192 + lane] + te * prow[192 + lane];
  for (int off = 32; off; off >>= 1) {
    a0 += __shfl_xor(a0, off);
    a1 += __shfl_xor(a1, off);
    a2 += __shfl_xor(a2, off);
    a3 += __shfl_xor(a3, off);
  }
  if (lane == 0) {
    const float* qb = qbt + dst * 4;
    alpha4[p] = make_float4((a0 + qb[0]) * 0.125f, (a1 + qb[1]) * 0.125f,
                            (a2 + qb[2]) * 0.125f, (a3 + qb[3]) * 0.125f);
  }
}

// ---------------- segment softmax + aggregation + relu ----------------
__global__ __launch_bounds__(256) void aggregate_kernel(
    const int* __restrict__ flags, const void* __restrict__ eidx,
    const int* __restrict__ esorted, const int* __restrict__ offsets,
    const float4* __restrict__ alpha4, const float* __restrict__ v,
    float* __restrict__ xout) {
  bool is64 = flags[0] != 0;
  int n = blockIdx.x;
  int t = threadIdx.x;
  int h = t >> 6;
  int s0 = offsets[n], s1 = offsets[n + 1];
  if (s0 < 0) s0 = 0;
  if (s1 > NE) s1 = NE;
  float m = -INFINITY;
  for (int p = s0; p < s1; ++p) {
    float4 a = alpha4[p];
    float av = (h == 0) ? a.x : (h == 1) ? a.y : (h == 2) ? a.z : a.w;
    m = fmaxf(m, av);
  }
  float denom = 0.f, acc = 0.f;
  for (int p = s0; p < s1; ++p) {
    float4 a = alpha4[p];
    float av = (h == 0) ? a.x : (h == 1) ? a.y : (h == 2) ? a.z : a.w;
    float ea = expf(av - m);
    denom += ea;
    int e = esorted[p];
    if ((unsigned)e >= NE) continue;
    int src = ldsrc(eidx, e, is64);
    if ((unsigned)src >= NN) src = 0;
    acc += ea * v[(size_t)src * HC + t];
  }
  float r = acc / (denom + 1e-16f);
  xout[(size_t)n * HC + t] = fmaxf(r, 0.f);
}

// ---------------- final: out[e] = (x[src]+x[dst]) . wc + bc ----------------
__global__ __launch_bounds__(256) void final_kernel(
    const int* __restrict__ flags, const void* __restrict__ eidx,
    const float* __restrict__ x, const void* __restrict__ wc,
    const void* __restrict__ bc, void* __restrict__ out) {
  bool is64 = flags[0] != 0, fbf = flags[1] != 0;
  int p = blockIdx.x * 4 + (threadIdx.x >> 6);
  if (p >= NE) return;
  int lane = threadIdx.x & 63;
  int src = ldsrc(eidx, p, is64);
  int dst = lddst(eidx, p, is64);
  if ((unsigned)src >= NN) src = 0;
  if ((unsigned)dst >= NN) dst = 0;
  const float* xs = x + (size_t)src * HC;
  const float* xd = x + (size_t)dst * HC;
  float s = 0.f;
#pragma unroll
  for (int r = 0; r < 4; ++r) {
    int t = r * 64 + lane;
    s += (xs[t] + xd[t]) * ldf(wc, t, fbf);
  }
  for (int off = 32; off; off >>= 1) s += __shfl_xor(s, off);
  if (lane == 0) stout(out, p, s + ldf(bc, 0, fbf), fbf);
}

extern "C" void kernel_launch(void* const* d_in, const int* in_sizes, int n_in,
                              void* d_out, int out_size, void* d_ws, size_t ws_size,
                              hipStream_t stream) {
  const void* eidx  = d_in[0];
  const void* rawt  = d_in[1];
  const void* noise = d_in[2];
  const void* nemb  = d_in[3];
  const void *wq1 = d_in[4],  *bq1 = d_in[5];
  const void *wk1 = d_in[6],  *bk1 = d_in[7];
  const void *wv1 = d_in[8],  *bv1 = d_in[9];
  const void *wt1 = d_in[10], *bt1 = d_in[11];
  const void *wq2 = d_in[12], *bq2 = d_in[13];
  const void *wk2 = d_in[14], *bk2 = d_in[15];
  const void *wv2 = d_in[16], *bv2 = d_in[17];
  const void *wt2 = d_in[18], *bt2 = d_in[19];
  const void *wcp = d_in[20], *bcp = d_in[21];

  char* ws = (char*)d_ws;
  size_t off = 0;
  auto alloc = [&](size_t bytes) -> void* {
    void* p = ws + off;
    off += (bytes + 255) & ~(size_t)255;
    return p;
  };
  int*   flags = (int*)alloc(256);
  float* divt  = (float*)alloc(256);
  float* zbias = (float*)alloc(HC * 4);          // zero bias for qproj GEMM
  float* WT    = (float*)alloc((size_t)HC * HC * 4);  // block-diag time weight (fp32)
  float* q     = (float*)alloc((size_t)NN * HC * 4);
  float* k     = (float*)alloc((size_t)NN * HC * 4);
  float* v     = (float*)alloc((size_t)NN * HC * 4);
  float* qproj = (float*)alloc((size_t)NN * HC * 4);
  float* qbt   = (float*)alloc((size_t)NN * 4 * 4);
  int* offsets = (int*)alloc((size_t)(NN + 1) * 4);
  int* cursor  = (int*)alloc((size_t)NN * 4);
  int* esorted = (int*)alloc((size_t)NE * 4);
  float4* alpha = (float4*)alloc((size_t)NE * 16);
  float* x1 = qproj;  // aggregate L1 writes AFTER alpha L1 consumed qproj
  float* x2 = q;      // aggregate L2 writes AFTER alpha L2 consumed q
  size_t need = off;

  int gN = (NN + 255) / 256, gE = (NE + 255) / 256, gEdge = (NE + 3) / 4;

  if (ws_size < 1024) {
    raw_sentinel_kernel<<<gE, 256, 0, stream>>>((u16*)d_out);
    return;
  }
  devinit_kernel<<<1, 64, 0, stream>>>(eidx, nemb, flags, divt);
  if (need > ws_size) {
    sentinel_kernel<<<gE, 256, 0, stream>>>(flags, d_out);
    return;
  }

  zero_kernel<<<1, 256, 0, stream>>>((int*)zbias, HC);

  // CSR by dst
  zero_kernel<<<gN, 256, 0, stream>>>(cursor, NN);
  hist_kernel<<<gE, 256, 0, stream>>>(flags, eidx, cursor);
  scan_kernel<<<1, 64, 0, stream>>>(cursor, offsets, NN);
  copy_kernel<<<gN, 256, 0, stream>>>(offsets, cursor, NN);
  fill_kernel<<<gE, 256, 0, stream>>>(flags, eidx, cursor, esorted);

  dim3 gg((NN + 63) / 64, 4);

  // Layer 1 (A = raw node_emb, K=128)
  gemm256<false, false><<<gg, 256, 0, stream>>>(flags, nemb, wq1, bq1, q, NN, NIN);
  gemm256<false, false><<<gg, 256, 0, stream>>>(flags, nemb, wk1, bk1, k, NN, NIN);
  gemm256<false, false><<<gg, 256, 0, stream>>>(flags, nemb, wv1, bv1, v, NN, NIN);
  buildwt_kernel<<<256, 256, 0, stream>>>(flags, wt1, WT);
  gemm256<true, true><<<gg, 256, 0, stream>>>(flags, q, WT, zbias, qproj, NN, HC);
  qbt_kernel<<<NN, 256, 0, stream>>>(flags, q, bt1, qbt);
  alpha_kernel<<<gEdge, 256, 0, stream>>>(flags, eidx, esorted, rawt, noise, q, k, qproj, qbt, divt, alpha);
  aggregate_kernel<<<NN, 256, 0, stream>>>(flags, eidx, esorted, offsets, alpha, v, x1);

  // Layer 2 (A = fp32 x1, K=256)
  gemm256<true, false><<<gg, 256, 0, stream>>>(flags, x1, wq2, bq2, q, NN, HC);
  gemm256<true, false><<<gg, 256, 0, stream>>>(flags, x1, wk2, bk2, k, NN, HC);
  gemm256<true, false><<<gg, 256, 0, stream>>>(flags, x1, wv2, bv2, v, NN, HC);
  buildwt_kernel<<<256, 256, 0, stream>>>(flags, wt2, WT);
  gemm256<true, true><<<gg, 256, 0, stream>>>(flags, q, WT, zbias, qproj, NN, HC);  // overwrites x1 after L2 GEMMs consumed it
  qbt_kernel<<<NN, 256, 0, stream>>>(flags, q, bt2, qbt);
  alpha_kernel<<<gEdge, 256, 0, stream>>>(flags, eidx, esorted, rawt, noise, q, k, qproj, qbt, divt, alpha);
  aggregate_kernel<<<NN, 256, 0, stream>>>(flags, eidx, esorted, offsets, alpha, v, x2);

  // Edge scorer
  final_kernel<<<gEdge, 256, 0, stream>>>(flags, eidx, x2, wcp, bcp, d_out);
}

// Round 4
// 940.358 us; speedup vs baseline: 2.6180x; 1.4369x over previous
//
#include <hip/hip_runtime.h>
#include <math.h>

// Problem constants
#define NN   20000     // nodes
#define NE   320000    // edges
#define NIN  128       // node input dim
#define HC   256       // heads(4) * hidden(64)

typedef unsigned short u16;
typedef __attribute__((ext_vector_type(8))) short bf16x8;
typedef __attribute__((ext_vector_type(4))) float f32x4;

__device__ __forceinline__ float bf2f(u16 u) {
  union { unsigned int i; float f; } x;
  x.i = ((unsigned int)u) << 16;
  return x.f;
}
__device__ __forceinline__ u16 f2bf(float f) {
  union { float f; unsigned int i; } x;
  x.f = f;
  unsigned int r = x.i + 0x7fffu + ((x.i >> 16) & 1u);
  return (u16)(r >> 16);
}

// dtype-flexible loads (flags detected on device each launch)
__device__ __forceinline__ float ldf(const void* p, int i, bool fbf) {
  return fbf ? bf2f(((const u16*)p)[i]) : ((const float*)p)[i];
}
__device__ __forceinline__ int ldsrc(const void* p, int e, bool is64) {
  const int* p32 = (const int*)p;
  return is64 ? p32[2 * e] : p32[e];
}
__device__ __forceinline__ int lddst(const void* p, int e, bool is64) {
  const int* p32 = (const int*)p;
  return is64 ? p32[2 * (NE + e)] : p32[NE + e];
}
__device__ __forceinline__ void stout(void* p, int i, float v, bool fbf) {
  if (fbf) ((u16*)p)[i] = f2bf(v);
  else ((float*)p)[i] = v;
}

// ---------------- detection + div_term init ----------------
__global__ void devinit_kernel(const void* __restrict__ eidx,
                               const void* __restrict__ nemb,
                               int* __restrict__ flags, float* __restrict__ divt) {
  int lane = threadIdx.x;
  if (lane < 32) {
    const float c32 = (float)(-0.14391156831212787);
    float prod = (float)(2 * lane) * c32;
    divt[lane] = (float)exp((double)prod);
  }
  if (lane == 0) {
    const int* p32 = (const int*)eidx;
    int is64 = 1;
    for (int i = 1; i < 128; i += 2)
      if (p32[i] != 0) { is64 = 0; break; }
    const u16* q16 = (const u16*)nemb;
    int fbf = 1;
    for (int i = 0; i < 128; i += 2) {
      unsigned e = (q16[i] >> 7) & 0xFF;
      if (e < 90 || e > 140) { fbf = 0; break; }
    }
    flags[0] = is64;
    flags[1] = fbf;
  }
}

__global__ void sentinel_kernel(const int* __restrict__ flags, void* __restrict__ out) {
  int i = blockIdx.x * 256 + threadIdx.x;
  if (i < NE) stout(out, i, 3000.0f, flags[1] != 0);
}
__global__ void raw_sentinel_kernel(u16* __restrict__ out) {
  int i = blockIdx.x * 256 + threadIdx.x;
  if (i < NE) out[i] = f2bf(3000.0f);
}

// ---------------- CSR build ----------------
__global__ void zero_kernel(int* __restrict__ p, int n) {
  int i = blockIdx.x * 256 + threadIdx.x;
  if (i < n) p[i] = 0;
}

__global__ void hist_kernel(const int* __restrict__ flags, const void* __restrict__ eidx,
                            int* __restrict__ cnt) {
  bool is64 = flags[0] != 0;
  int e = blockIdx.x * 256 + threadIdx.x;
  if (e < NE) {
    int d = lddst(eidx, e, is64);
    if ((unsigned)d < NN) atomicAdd(&cnt[d], 1);
  }
}

// hierarchical scan: phase 1 — per-block exclusive scan + block sums
__global__ void scan1_kernel(const int* __restrict__ cnt, int* __restrict__ offs,
                             int* __restrict__ bsum, int n) {
  __shared__ int s[256];
  int b = blockIdx.x, t = threadIdx.x, i = b * 256 + t;
  int x = (i < n) ? cnt[i] : 0;
  s[t] = x;
  __syncthreads();
  for (int off = 1; off < 256; off <<= 1) {
    int y = (t >= off) ? s[t - off] : 0;
    __syncthreads();
    s[t] += y;
    __syncthreads();
  }
  if (i < n) offs[i] = s[t] - x;
  if (t == 255) bsum[b] = s[t];
}

// phase 2 — single block scans block sums (nb <= 256), writes total to offs[n]
__global__ void scan2_kernel(int* __restrict__ bsum, int* __restrict__ offs,
                             int nb, int n) {
  __shared__ int s[256];
  int t = threadIdx.x;
  int x = (t < nb) ? bsum[t] : 0;
  s[t] = x;
  __syncthreads();
  for (int off = 1; off < 256; off <<= 1) {
    int y = (t >= off) ? s[t - off] : 0;
    __syncthreads();
    s[t] += y;
    __syncthreads();
  }
  if (t < nb) bsum[t] = s[t] - x;   // exclusive prefix of block sums
  if (t == 255) offs[n] = s[t];     // total
}

// phase 3 — add block prefix
__global__ void scan3_kernel(int* __restrict__ offs, const int* __restrict__ bsum, int n) {
  int i = blockIdx.x * 256 + threadIdx.x;
  if (i < n) offs[i] += bsum[blockIdx.x];
}

__global__ void copy_kernel(const int* __restrict__ a, int* __restrict__ b, int n) {
  int i = blockIdx.x * 256 + threadIdx.x;
  if (i < n) b[i] = a[i];
}

__global__ void fill_kernel(const int* __restrict__ flags, const void* __restrict__ eidx,
                            int* __restrict__ cursor, int* __restrict__ esorted) {
  bool is64 = flags[0] != 0;
  int e = blockIdx.x * 256 + threadIdx.x;
  if (e < NE) {
    int d = lddst(eidx, e, is64);
    if ((unsigned)d < NN) {
      int pos = atomicAdd(&cursor[d], 1);
      if ((unsigned)pos < NE) esorted[pos] = e;
    }
  }
}

// ---------------- weight transpose: W[K,256] -> Wt[256][K] bf16 ----------------
__global__ void transw_kernel(const int* __restrict__ flags, const void* __restrict__ W,
                              u16* __restrict__ Wt, int K) {
  bool fbf = flags[1] != 0;
  __shared__ u16 tile[64][65];
  int kb = blockIdx.x * 64, cb = blockIdx.y * 64;
  int tx = threadIdx.x & 63, ty = threadIdx.x >> 6;
  for (int i = ty; i < 64; i += 4)
    tile[tx][i] = f2bf(ldf(W, (kb + i) * HC + cb + tx, fbf));  // exact if already bf16
  __syncthreads();
  for (int i = ty; i < 64; i += 4)
    Wt[(size_t)(cb + i) * K + kb + tx] = tile[i][tx];
}

// block-diagonal time weight, pre-transposed bf16: WTt[col=h*64+j][k] = wt[j*HC+k] if k in head h
__global__ void buildwtt_kernel(const int* __restrict__ flags, const void* __restrict__ wt,
                                u16* __restrict__ WTt) {
  bool fbf = flags[1] != 0;
  int col = blockIdx.x;      // 0..255
  int k = threadIdx.x;       // 0..255
  int h = col >> 6, j = col & 63;
  u16 v = 0;
  if ((k >> 6) == h) v = f2bf(ldf(wt, j * HC + k, fbf));
  WTt[(size_t)col * HC + k] = v;
}

// ---------------- qbt[n,h] = q[n,h,:] . bt[h,:] ----------------
__global__ __launch_bounds__(256) void qbt_kernel(
    const int* __restrict__ flags, const float* __restrict__ q,
    const void* __restrict__ bt, float* __restrict__ qbt) {
  bool fbf = flags[1] != 0;
  int t = threadIdx.x;
  int n = blockIdx.x;
  int h = t >> 6, j = t & 63;
  float pb = q[(size_t)n * HC + t] * ldf(bt, t, fbf);
  for (int off = 32; off; off >>= 1) pb += __shfl_xor(pb, off);
  if (j == 0) qbt[n * 4 + h] = pb;
}

// ---------------- MFMA GEMM: C[M,256] = A[M,K] @ Wt^T + bias ----------------
// Wt is [256][K] bf16 (pre-transposed). AWS: A is fp32 ws (else raw input per flag).
// BF32: bias is fp32 ws (else raw input per flag).
// Block 256 thr = 4 waves; tile 64 rows x 64 cols; wave w covers cols [w*16, w*16+16).
template <bool AWS, bool BF32>
__global__ __launch_bounds__(256) void gemm_mfma(
    const int* __restrict__ flags, const void* __restrict__ Ap,
    const u16* __restrict__ Wt, const void* __restrict__ bias,
    float* __restrict__ C, int M, int K) {
  bool fbf = flags[1] != 0;
  __shared__ u16 As[64][56];   // row stride 112 B (16B-aligned, 2-way banks = free)
  __shared__ u16 Bs[64][56];   // Bs[col][k]
  int tid = threadIdx.x;
  int rb = blockIdx.x * 64, cb = blockIdx.y * 64;
  int wave = tid >> 6, lane = tid & 63;
  int l15 = lane & 15, quad = lane >> 4;

  f32x4 acc[4];
#pragma unroll
  for (int mt = 0; mt < 4; ++mt)
#pragma unroll
    for (int r = 0; r < 4; ++r) acc[mt][r] = 0.f;

  int srow = tid >> 2;        // 0..63
  int skq  = (tid & 3) * 8;   // 0,8,16,24

  for (int kk = 0; kk < K; kk += 32) {
    // stage A tile (64 x 32) as bf16
    bf16x8 av;
#pragma unroll
    for (int i = 0; i < 8; ++i) av[i] = 0;
    int grow = rb + srow;
    if (grow < M) {
      if constexpr (AWS) {
        const float* A = (const float*)Ap + (size_t)grow * K + kk + skq;
#pragma unroll
        for (int i = 0; i < 8; ++i) av[i] = (short)f2bf(A[i]);
      } else {
        if (fbf) {
          av = *(const bf16x8*)((const u16*)Ap + (size_t)grow * K + kk + skq);
        } else {
          const float* A = (const float*)Ap + (size_t)grow * K + kk + skq;
#pragma unroll
          for (int i = 0; i < 8; ++i) av[i] = (short)f2bf(A[i]);
        }
      }
    }
    *(bf16x8*)&As[srow][skq] = av;
    // stage B tile: Bs[col][k] from Wt[(cb+col)*K + kk + k] (coalesced 16B chunks)
    *(bf16x8*)&Bs[srow][skq] =
        *(const bf16x8*)(Wt + (size_t)(cb + srow) * K + kk + skq);
    __syncthreads();

    bf16x8 bfrag = *(const bf16x8*)&Bs[wave * 16 + l15][quad * 8];
#pragma unroll
    for (int mt = 0; mt < 4; ++mt) {
      bf16x8 afrag = *(const bf16x8*)&As[mt * 16 + l15][quad * 8];
      acc[mt] = __builtin_amdgcn_mfma_f32_16x16x32_bf16(afrag, bfrag, acc[mt], 0, 0, 0);
    }
    __syncthreads();
  }

  int gcol = cb + wave * 16 + l15;
  float bv;
  if constexpr (BF32) bv = ((const float*)bias)[gcol];
  else                bv = ldf(bias, gcol, fbf);
#pragma unroll
  for (int mt = 0; mt < 4; ++mt) {
#pragma unroll
    for (int r = 0; r < 4; ++r) {
      int grow = rb + mt * 16 + quad * 4 + r;
      if (grow < M) C[(size_t)grow * HC + gcol] = acc[mt][r] + bv;
    }
  }
}

// ---------------- per-edge alpha (sorted position), one wave per edge ----------------
__global__ __launch_bounds__(256) void alpha_kernel(
    const int* __restrict__ flags, const void* __restrict__ eidx,
    const int* __restrict__ esorted, const void* __restrict__ rawt,
    const void* __restrict__ noise, const float* __restrict__ q,
    const float* __restrict__ k, const float* __restrict__ qproj,
    const float* __restrict__ qbt, const float* __restrict__ divt,
    float4* __restrict__ alpha4) {
  bool is64 = flags[0] != 0, fbf = flags[1] != 0;
  int p = blockIdx.x * 4 + (threadIdx.x >> 6);
  if (p >= NE) return;
  int lane = threadIdx.x & 63;
  int e = esorted[p];
  if ((unsigned)e >= NE) {
    if (lane == 0) alpha4[p] = make_float4(0.f, 0.f, 0.f, 0.f);
    return;
  }
  int src = ldsrc(eidx, e, is64);
  int dst = lddst(eidx, e, is64);
  if ((unsigned)src >= NN) src = 0;
  if ((unsigned)dst >= NN) dst = 0;
  float tt = ldf(rawt, e, fbf) + ldf(noise, e, fbf);
  float arg = tt * divt[lane >> 1];
  float te = (lane & 1) ? cosf(arg) : sinf(arg);  // te[2i]=sin, te[2i+1]=cos
  const float* qrow = q + (size_t)dst * HC;
  const float* krow = k + (size_t)src * HC;
  const float* prow = qproj + (size_t)dst * HC;
  float a0 = qrow[lane]       * krow[lane]       + te * prow[lane];
  float a1 = qrow[64 + lane]  * krow[64 + lane]  + te * prow[64 + lane];
  float a2 = qrow[128 + lane] * krow[128 + lane] + te * prow[128 + lane];
  float a3 = qrow[192 + lane] * krow[192 + lane] + te * prow[192 + lane];
  for (int off = 32; off; off >>= 1) {
    a0 += __shfl_xor(a0, off);
    a1 += __shfl_xor(a1, off);
    a2 += __shfl_xor(a2, off);
    a3 += __shfl_xor(a3, off);
  }
  if (lane == 0) {
    const float* qb = qbt + dst * 4;
    alpha4[p] = make_float4((a0 + qb[0]) * 0.125f, (a1 + qb[1]) * 0.125f,
                            (a2 + qb[2]) * 0.125f, (a3 + qb[3]) * 0.125f);
  }
}

// ---------------- segment softmax + aggregation + relu ----------------
__global__ __launch_bounds__(256) void aggregate_kernel(
    const int* __restrict__ flags, const void* __restrict__ eidx,
    const int* __restrict__ esorted, const int* __restrict__ offsets,
    const float4* __restrict__ alpha4, const float* __restrict__ v,
    float* __restrict__ xout) {
  bool is64 = flags[0] != 0;
  int n = blockIdx.x;
  int t = threadIdx.x;
  int h = t >> 6;
  int s0 = offsets[n], s1 = offsets[n + 1];
  if (s0 < 0) s0 = 0;
  if (s1 > NE) s1 = NE;
  float m = -INFINITY;
  for (int p = s0; p < s1; ++p) {
    float4 a = alpha4[p];
    float av = (h == 0) ? a.x : (h == 1) ? a.y : (h == 2) ? a.z : a.w;
    m = fmaxf(m, av);
  }
  float denom = 0.f, acc = 0.f;
  for (int p = s0; p < s1; ++p) {
    float4 a = alpha4[p];
    float av = (h == 0) ? a.x : (h == 1) ? a.y : (h == 2) ? a.z : a.w;
    float ea = expf(av - m);
    denom += ea;
    int e = esorted[p];
    if ((unsigned)e >= NE) continue;
    int src = ldsrc(eidx, e, is64);
    if ((unsigned)src >= NN) src = 0;
    acc += ea * v[(size_t)src * HC + t];
  }
  float r = acc / (denom + 1e-16f);
  xout[(size_t)n * HC + t] = fmaxf(r, 0.f);
}

// ---------------- final: out[e] = (x[src]+x[dst]) . wc + bc ----------------
__global__ __launch_bounds__(256) void final_kernel(
    const int* __restrict__ flags, const void* __restrict__ eidx,
    const float* __restrict__ x, const void* __restrict__ wc,
    const void* __restrict__ bc, void* __restrict__ out) {
  bool is64 = flags[0] != 0, fbf = flags[1] != 0;
  int p = blockIdx.x * 4 + (threadIdx.x >> 6);
  if (p >= NE) return;
  int lane = threadIdx.x & 63;
  int src = ldsrc(eidx, p, is64);
  int dst = lddst(eidx, p, is64);
  if ((unsigned)src >= NN) src = 0;
  if ((unsigned)dst >= NN) dst = 0;
  const float* xs = x + (size_t)src * HC;
  const float* xd = x + (size_t)dst * HC;
  float s = 0.f;
#pragma unroll
  for (int r = 0; r < 4; ++r) {
    int t = r * 64 + lane;
    s += (xs[t] + xd[t]) * ldf(wc, t, fbf);
  }
  for (int off = 32; off; off >>= 1) s += __shfl_xor(s, off);
  if (lane == 0) stout(out, p, s + ldf(bc, 0, fbf), fbf);
}

extern "C" void kernel_launch(void* const* d_in, const int* in_sizes, int n_in,
                              void* d_out, int out_size, void* d_ws, size_t ws_size,
                              hipStream_t stream) {
  const void* eidx  = d_in[0];
  const void* rawt  = d_in[1];
  const void* noise = d_in[2];
  const void* nemb  = d_in[3];
  const void *wq1 = d_in[4],  *bq1 = d_in[5];
  const void *wk1 = d_in[6],  *bk1 = d_in[7];
  const void *wv1 = d_in[8],  *bv1 = d_in[9];
  const void *wt1 = d_in[10], *bt1 = d_in[11];
  const void *wq2 = d_in[12], *bq2 = d_in[13];
  const void *wk2 = d_in[14], *bk2 = d_in[15];
  const void *wv2 = d_in[16], *bv2 = d_in[17];
  const void *wt2 = d_in[18], *bt2 = d_in[19];
  const void *wcp = d_in[20], *bcp = d_in[21];

  char* ws = (char*)d_ws;
  size_t off = 0;
  auto alloc = [&](size_t bytes) -> void* {
    void* p = ws + off;
    off += (bytes + 255) & ~(size_t)255;
    return p;
  };
  int*   flags = (int*)alloc(256);
  float* divt  = (float*)alloc(256);
  float* zbias = (float*)alloc(HC * 4);                 // zero bias for qproj GEMM
  u16*   Wt    = (u16*)alloc((size_t)HC * HC * 2);      // transposed weight (bf16), reused
  u16*   WTt   = (u16*)alloc((size_t)HC * HC * 2);      // block-diag time weight^T (bf16)
  float* q     = (float*)alloc((size_t)NN * HC * 4);
  float* k     = (float*)alloc((size_t)NN * HC * 4);
  float* v     = (float*)alloc((size_t)NN * HC * 4);
  float* qproj = (float*)alloc((size_t)NN * HC * 4);
  float* qbt   = (float*)alloc((size_t)NN * 4 * 4);
  int* offsets = (int*)alloc((size_t)(NN + 1) * 4);
  int* cursor  = (int*)alloc((size_t)NN * 4);
  int* bsum    = (int*)alloc(256 * 4);
  int* esorted = (int*)alloc((size_t)NE * 4);
  float4* alpha = (float4*)alloc((size_t)NE * 16);
  float* x1 = qproj;  // aggregate L1 writes AFTER alpha L1 consumed qproj
  float* x2 = q;      // aggregate L2 writes AFTER alpha L2 consumed q
  size_t need = off;

  int gN = (NN + 255) / 256, gE = (NE + 255) / 256, gEdge = (NE + 3) / 4;
  int nb = (NN + 255) / 256;  // 79 scan blocks

  if (ws_size < 1024) {
    raw_sentinel_kernel<<<gE, 256, 0, stream>>>((u16*)d_out);
    return;
  }
  devinit_kernel<<<1, 64, 0, stream>>>(eidx, nemb, flags, divt);
  if (need > ws_size) {
    sentinel_kernel<<<gE, 256, 0, stream>>>(flags, d_out);
    return;
  }

  zero_kernel<<<1, 256, 0, stream>>>((int*)zbias, HC);

  // CSR by dst (hierarchical scan)
  zero_kernel<<<gN, 256, 0, stream>>>(cursor, NN);
  hist_kernel<<<gE, 256, 0, stream>>>(flags, eidx, cursor);
  scan1_kernel<<<nb, 256, 0, stream>>>(cursor, offsets, bsum, NN);
  scan2_kernel<<<1, 256, 0, stream>>>(bsum, offsets, nb, NN);
  scan3_kernel<<<nb, 256, 0, stream>>>(offsets, bsum, NN);
  copy_kernel<<<gN, 256, 0, stream>>>(offsets, cursor, NN);
  fill_kernel<<<gE, 256, 0, stream>>>(flags, eidx, cursor, esorted);

  dim3 gg((NN + 63) / 64, 4);
  dim3 gt1(NIN / 64, 4), gt2(HC / 64, 4);

  // Layer 1 (A = raw node_emb bf16, K=128)
  transw_kernel<<<gt1, 256, 0, stream>>>(flags, wq1, Wt, NIN);
  gemm_mfma<false, false><<<gg, 256, 0, stream>>>(flags, nemb, Wt, bq1, q, NN, NIN);
  transw_kernel<<<gt1, 256, 0, stream>>>(flags, wk1, Wt, NIN);
  gemm_mfma<false, false><<<gg, 256, 0, stream>>>(flags, nemb, Wt, bk1, k, NN, NIN);
  transw_kernel<<<gt1, 256, 0, stream>>>(flags, wv1, Wt, NIN);
  gemm_mfma<false, false><<<gg, 256, 0, stream>>>(flags, nemb, Wt, bv1, v, NN, NIN);
  buildwtt_kernel<<<HC, HC, 0, stream>>>(flags, wt1, WTt);
  gemm_mfma<true, true><<<gg, 256, 0, stream>>>(flags, q, WTt, zbias, qproj, NN, HC);
  qbt_kernel<<<NN, 256, 0, stream>>>(flags, q, bt1, qbt);
  alpha_kernel<<<gEdge, 256, 0, stream>>>(flags, eidx, esorted, rawt, noise, q, k, qproj, qbt, divt, alpha);
  aggregate_kernel<<<NN, 256, 0, stream>>>(flags, eidx, esorted, offsets, alpha, v, x1);

  // Layer 2 (A = fp32 x1, K=256)
  transw_kernel<<<gt2, 256, 0, stream>>>(flags, wq2, Wt, HC);
  gemm_mfma<true, false><<<gg, 256, 0, stream>>>(flags, x1, Wt, bq2, q, NN, HC);
  transw_kernel<<<gt2, 256, 0, stream>>>(flags, wk2, Wt, HC);
  gemm_mfma<true, false><<<gg, 256, 0, stream>>>(flags, x1, Wt, bk2, k, NN, HC);
  transw_kernel<<<gt2, 256, 0, stream>>>(flags, wv2, Wt, HC);
  gemm_mfma<true, false><<<gg, 256, 0, stream>>>(flags, x1, Wt, bv2, v, NN, HC);
  buildwtt_kernel<<<HC, HC, 0, stream>>>(flags, wt2, WTt);
  gemm_mfma<true, true><<<gg, 256, 0, stream>>>(flags, q, WTt, zbias, qproj, NN, HC);  // overwrites x1 after consumed
  qbt_kernel<<<NN, 256, 0, stream>>>(flags, q, bt2, qbt);
  alpha_kernel<<<gEdge, 256, 0, stream>>>(flags, eidx, esorted, rawt, noise, q, k, qproj, qbt, divt, alpha);
  aggregate_kernel<<<NN, 256, 0, stream>>>(flags, eidx, esorted, offsets, alpha, v, x2);

  // Edge scorer
  final_kernel<<<gEdge, 256, 0, stream>>>(flags, eidx, x2, wcp, bcp, d_out);
}

// Round 5
// 767.336 us; speedup vs baseline: 3.2084x; 1.2255x over previous
//
#include <hip/hip_runtime.h>
#include <math.h>

// Problem constants
#define NN   20000     // nodes
#define NE   320000    // edges
#define NIN  128       // node input dim
#define HC   256       // heads(4) * hidden(64)

typedef unsigned short u16;
typedef __attribute__((ext_vector_type(8))) short bf16x8;
typedef __attribute__((ext_vector_type(4))) float f32x4;

__device__ __forceinline__ float bf2f(u16 u) {
  union { unsigned int i; float f; } x;
  x.i = ((unsigned int)u) << 16;
  return x.f;
}
__device__ __forceinline__ u16 f2bf(float f) {
  union { float f; unsigned int i; } x;
  x.f = f;
  unsigned int r = x.i + 0x7fffu + ((x.i >> 16) & 1u);
  return (u16)(r >> 16);
}

// dtype-flexible loads (flags detected on device each launch)
__device__ __forceinline__ float ldf(const void* p, int i, bool fbf) {
  return fbf ? bf2f(((const u16*)p)[i]) : ((const float*)p)[i];
}
__device__ __forceinline__ int ldsrc(const void* p, int e, bool is64) {
  const int* p32 = (const int*)p;
  return is64 ? p32[2 * e] : p32[e];
}
__device__ __forceinline__ int lddst(const void* p, int e, bool is64) {
  const int* p32 = (const int*)p;
  return is64 ? p32[2 * (NE + e)] : p32[NE + e];
}
__device__ __forceinline__ void stout(void* p, int i, float v, bool fbf) {
  if (fbf) ((u16*)p)[i] = f2bf(v);
  else ((float*)p)[i] = v;
}

// ---------------- detection + div_term init ----------------
__global__ void devinit_kernel(const void* __restrict__ eidx,
                               const void* __restrict__ nemb,
                               int* __restrict__ flags, float* __restrict__ divt) {
  int lane = threadIdx.x;
  if (lane < 32) {
    const float c32 = (float)(-0.14391156831212787);
    float prod = (float)(2 * lane) * c32;
    divt[lane] = (float)exp((double)prod);
  }
  if (lane == 0) {
    const int* p32 = (const int*)eidx;
    int is64 = 1;
    for (int i = 1; i < 128; i += 2)
      if (p32[i] != 0) { is64 = 0; break; }
    const u16* q16 = (const u16*)nemb;
    int fbf = 1;
    for (int i = 0; i < 128; i += 2) {
      unsigned e = (q16[i] >> 7) & 0xFF;
      if (e < 90 || e > 140) { fbf = 0; break; }
    }
    flags[0] = is64;
    flags[1] = fbf;
  }
}

__global__ void sentinel_kernel(const int* __restrict__ flags, void* __restrict__ out) {
  int i = blockIdx.x * 256 + threadIdx.x;
  if (i < NE) stout(out, i, 3000.0f, flags[1] != 0);
}
__global__ void raw_sentinel_kernel(u16* __restrict__ out) {
  int i = blockIdx.x * 256 + threadIdx.x;
  if (i < NE) out[i] = f2bf(3000.0f);
}

// ---------------- CSR build ----------------
__global__ void zero_kernel(int* __restrict__ p, int n) {
  int i = blockIdx.x * 256 + threadIdx.x;
  if (i < n) p[i] = 0;
}

__global__ void hist_kernel(const int* __restrict__ flags, const void* __restrict__ eidx,
                            int* __restrict__ cnt) {
  bool is64 = flags[0] != 0;
  int e = blockIdx.x * 256 + threadIdx.x;
  if (e < NE) {
    int d = lddst(eidx, e, is64);
    if ((unsigned)d < NN) atomicAdd(&cnt[d], 1);
  }
}

// hierarchical scan
__global__ void scan1_kernel(const int* __restrict__ cnt, int* __restrict__ offs,
                             int* __restrict__ bsum, int n) {
  __shared__ int s[256];
  int b = blockIdx.x, t = threadIdx.x, i = b * 256 + t;
  int x = (i < n) ? cnt[i] : 0;
  s[t] = x;
  __syncthreads();
  for (int off = 1; off < 256; off <<= 1) {
    int y = (t >= off) ? s[t - off] : 0;
    __syncthreads();
    s[t] += y;
    __syncthreads();
  }
  if (i < n) offs[i] = s[t] - x;
  if (t == 255) bsum[b] = s[t];
}

__global__ void scan2_kernel(int* __restrict__ bsum, int* __restrict__ offs,
                             int nb, int n) {
  __shared__ int s[256];
  int t = threadIdx.x;
  int x = (t < nb) ? bsum[t] : 0;
  s[t] = x;
  __syncthreads();
  for (int off = 1; off < 256; off <<= 1) {
    int y = (t >= off) ? s[t - off] : 0;
    __syncthreads();
    s[t] += y;
    __syncthreads();
  }
  if (t < nb) bsum[t] = s[t] - x;
  if (t == 255) offs[n] = s[t];
}

__global__ void scan3_kernel(int* __restrict__ offs, const int* __restrict__ bsum, int n) {
  int i = blockIdx.x * 256 + threadIdx.x;
  if (i < n) offs[i] += bsum[blockIdx.x];
}

__global__ void copy_kernel(const int* __restrict__ a, int* __restrict__ b, int n) {
  int i = blockIdx.x * 256 + threadIdx.x;
  if (i < n) b[i] = a[i];
}

__global__ void fill_kernel(const int* __restrict__ flags, const void* __restrict__ eidx,
                            int* __restrict__ cursor, int* __restrict__ esorted) {
  bool is64 = flags[0] != 0;
  int e = blockIdx.x * 256 + threadIdx.x;
  if (e < NE) {
    int d = lddst(eidx, e, is64);
    if ((unsigned)d < NN) {
      int pos = atomicAdd(&cursor[d], 1);
      if ((unsigned)pos < NE) esorted[pos] = e;
    }
  }
}

// ---------------- weight transpose: W[K,256] -> Wt[256][K] bf16 ----------------
__global__ void transw_kernel(const int* __restrict__ flags, const void* __restrict__ W,
                              u16* __restrict__ Wt, int K) {
  bool fbf = flags[1] != 0;
  __shared__ u16 tile[64][65];
  int kb = blockIdx.x * 64, cb = blockIdx.y * 64;
  int tx = threadIdx.x & 63, ty = threadIdx.x >> 6;
  for (int i = ty; i < 64; i += 4)
    tile[tx][i] = f2bf(ldf(W, (kb + i) * HC + cb + tx, fbf));
  __syncthreads();
  for (int i = ty; i < 64; i += 4)
    Wt[(size_t)(cb + i) * K + kb + tx] = tile[i][tx];
}

// block-diagonal time weight, pre-transposed bf16
__global__ void buildwtt_kernel(const int* __restrict__ flags, const void* __restrict__ wt,
                                u16* __restrict__ WTt) {
  bool fbf = flags[1] != 0;
  int col = blockIdx.x, k = threadIdx.x;
  int h = col >> 6, j = col & 63;
  u16 v = 0;
  if ((k >> 6) == h) v = f2bf(ldf(wt, j * HC + k, fbf));
  WTt[(size_t)col * HC + k] = v;
}

// ---------------- qbt[n,h] = q[n,h,:] . bt[h,:] (q bf16) ----------------
__global__ __launch_bounds__(256) void qbt_kernel(
    const int* __restrict__ flags, const u16* __restrict__ q,
    const void* __restrict__ bt, float* __restrict__ qbt) {
  bool fbf = flags[1] != 0;
  int t = threadIdx.x;
  int n = blockIdx.x;
  int h = t >> 6, j = t & 63;
  float pb = bf2f(q[(size_t)n * HC + t]) * ldf(bt, t, fbf);
  for (int off = 32; off; off >>= 1) pb += __shfl_xor(pb, off);
  if (j == 0) qbt[n * 4 + h] = pb;
}

// ---------------- MFMA GEMM: C[M,256](bf16) = A[M,K] @ Wt^T + bias ----------------
// AWS: A is bf16 ws (u16). else raw input per flag. BF32: bias is fp32 ws.
template <bool AWS, bool BF32>
__global__ __launch_bounds__(256) void gemm_mfma(
    const int* __restrict__ flags, const void* __restrict__ Ap,
    const u16* __restrict__ Wt, const void* __restrict__ bias,
    u16* __restrict__ C, int M, int K) {
  bool fbf = flags[1] != 0;
  __shared__ u16 As[64][56];   // row stride 112 B (16B-aligned)
  __shared__ u16 Bs[64][56];
  int tid = threadIdx.x;
  int rb = blockIdx.x * 64, cb = blockIdx.y * 64;
  int wave = tid >> 6, lane = tid & 63;
  int l15 = lane & 15, quad = lane >> 4;

  f32x4 acc[4];
#pragma unroll
  for (int mt = 0; mt < 4; ++mt)
#pragma unroll
    for (int r = 0; r < 4; ++r) acc[mt][r] = 0.f;

  int srow = tid >> 2;
  int skq  = (tid & 3) * 8;

  for (int kk = 0; kk < K; kk += 32) {
    bf16x8 av;
#pragma unroll
    for (int i = 0; i < 8; ++i) av[i] = 0;
    int grow = rb + srow;
    if (grow < M) {
      if constexpr (AWS) {
        av = *(const bf16x8*)((const u16*)Ap + (size_t)grow * K + kk + skq);
      } else {
        if (fbf) {
          av = *(const bf16x8*)((const u16*)Ap + (size_t)grow * K + kk + skq);
        } else {
          const float* A = (const float*)Ap + (size_t)grow * K + kk + skq;
#pragma unroll
          for (int i = 0; i < 8; ++i) av[i] = (short)f2bf(A[i]);
        }
      }
    }
    *(bf16x8*)&As[srow][skq] = av;
    *(bf16x8*)&Bs[srow][skq] =
        *(const bf16x8*)(Wt + (size_t)(cb + srow) * K + kk + skq);
    __syncthreads();

    bf16x8 bfrag = *(const bf16x8*)&Bs[wave * 16 + l15][quad * 8];
#pragma unroll
    for (int mt = 0; mt < 4; ++mt) {
      bf16x8 afrag = *(const bf16x8*)&As[mt * 16 + l15][quad * 8];
      acc[mt] = __builtin_amdgcn_mfma_f32_16x16x32_bf16(afrag, bfrag, acc[mt], 0, 0, 0);
    }
    __syncthreads();
  }

  int gcol = cb + wave * 16 + l15;
  float bv;
  if constexpr (BF32) bv = ((const float*)bias)[gcol];
  else                bv = ldf(bias, gcol, fbf);
#pragma unroll
  for (int mt = 0; mt < 4; ++mt) {
#pragma unroll
    for (int r = 0; r < 4; ++r) {
      int grow = rb + mt * 16 + quad * 4 + r;
      if (grow < M) C[(size_t)grow * HC + gcol] = f2bf(acc[mt][r] + bv);
    }
  }
}

// ---------------- per-edge alpha: one wave per sorted position, ushort4 lanes --------
__global__ __launch_bounds__(256) void alpha_kernel(
    const int* __restrict__ flags, const void* __restrict__ eidx,
    const int* __restrict__ esorted, const void* __restrict__ rawt,
    const void* __restrict__ noise, const u16* __restrict__ q,
    const u16* __restrict__ k, const u16* __restrict__ qproj,
    const float* __restrict__ qbt, const float* __restrict__ divt,
    float* __restrict__ alphaS) {
  bool is64 = flags[0] != 0, fbf = flags[1] != 0;
  int p = blockIdx.x * 4 + (threadIdx.x >> 6);
  if (p >= NE) return;
  int lane = threadIdx.x & 63;
  int h = lane >> 4;
  int e = esorted[p];
  if ((unsigned)e >= NE) {
    if ((lane & 15) == 0) alphaS[p * 4 + h] = 0.f;
    return;
  }
  int src = ldsrc(eidx, e, is64);
  int dst = lddst(eidx, e, is64);
  if ((unsigned)src >= NN) src = 0;
  if ((unsigned)dst >= NN) dst = 0;
  float tt = ldf(rawt, e, fbf) + ldf(noise, e, fbf);
  int c = lane * 4;          // 4 channels per lane
  int jb = c & 63;           // time-channel base within head
  float a0 = tt * divt[jb >> 1];
  float a1 = tt * divt[(jb >> 1) + 1];
  float te0 = sinf(a0), te1 = cosf(a0), te2 = sinf(a1), te3 = cosf(a1);
  ushort4 q4 = *(const ushort4*)(q + (size_t)dst * HC + c);
  ushort4 k4 = *(const ushort4*)(k + (size_t)src * HC + c);
  ushort4 p4 = *(const ushort4*)(qproj + (size_t)dst * HC + c);
  float s = bf2f(q4.x) * bf2f(k4.x) + te0 * bf2f(p4.x);
  s += bf2f(q4.y) * bf2f(k4.y) + te1 * bf2f(p4.y);
  s += bf2f(q4.z) * bf2f(k4.z) + te2 * bf2f(p4.z);
  s += bf2f(q4.w) * bf2f(k4.w) + te3 * bf2f(p4.w);
  s += __shfl_xor(s, 1);
  s += __shfl_xor(s, 2);
  s += __shfl_xor(s, 4);
  s += __shfl_xor(s, 8);
  if ((lane & 15) == 0)
    alphaS[p * 4 + h] = (s + qbt[dst * 4 + h]) * 0.125f;
}

// ---------------- segment softmax + aggregation + relu: one wave per node ----------
__global__ __launch_bounds__(256) void aggregate_kernel(
    const int* __restrict__ flags, const void* __restrict__ eidx,
    const int* __restrict__ esorted, const int* __restrict__ offsets,
    const float* __restrict__ alphaS, const u16* __restrict__ v,
    u16* __restrict__ xout) {
  bool is64 = flags[0] != 0;
  int n = blockIdx.x * 4 + (threadIdx.x >> 6);
  if (n >= NN) return;
  int lane = threadIdx.x & 63;
  int h = lane >> 4;
  int c = lane * 4;
  int s0 = offsets[n], s1 = offsets[n + 1];
  if (s0 < 0) s0 = 0;
  if (s1 > NE) s1 = NE;
  float m = -INFINITY;
  for (int p = s0; p < s1; ++p) m = fmaxf(m, alphaS[p * 4 + h]);
  float denom = 0.f;
  float acc0 = 0.f, acc1 = 0.f, acc2 = 0.f, acc3 = 0.f;
  for (int p = s0; p < s1; ++p) {
    float ea = expf(alphaS[p * 4 + h] - m);
    denom += ea;
    int e = esorted[p];
    if ((unsigned)e >= NE) continue;
    int src = ldsrc(eidx, e, is64);
    if ((unsigned)src >= NN) src = 0;
    ushort4 v4 = *(const ushort4*)(v + (size_t)src * HC + c);
    acc0 += ea * bf2f(v4.x);
    acc1 += ea * bf2f(v4.y);
    acc2 += ea * bf2f(v4.z);
    acc3 += ea * bf2f(v4.w);
  }
  float inv = 1.f / (denom + 1e-16f);
  ushort4 r;
  r.x = f2bf(fmaxf(acc0 * inv, 0.f));
  r.y = f2bf(fmaxf(acc1 * inv, 0.f));
  r.z = f2bf(fmaxf(acc2 * inv, 0.f));
  r.w = f2bf(fmaxf(acc3 * inv, 0.f));
  *(ushort4*)(xout + (size_t)n * HC + c) = r;
}

// ---------------- final: out[e] = (x[src]+x[dst]) . wc + bc ----------------
__global__ __launch_bounds__(256) void final_kernel(
    const int* __restrict__ flags, const void* __restrict__ eidx,
    const u16* __restrict__ x, const void* __restrict__ wc,
    const void* __restrict__ bc, void* __restrict__ out) {
  bool is64 = flags[0] != 0, fbf = flags[1] != 0;
  int p = blockIdx.x * 4 + (threadIdx.x >> 6);
  if (p >= NE) return;
  int lane = threadIdx.x & 63;
  int c = lane * 4;
  int src = ldsrc(eidx, p, is64);
  int dst = lddst(eidx, p, is64);
  if ((unsigned)src >= NN) src = 0;
  if ((unsigned)dst >= NN) dst = 0;
  ushort4 xs4 = *(const ushort4*)(x + (size_t)src * HC + c);
  ushort4 xd4 = *(const ushort4*)(x + (size_t)dst * HC + c);
  float s = (bf2f(xs4.x) + bf2f(xd4.x)) * ldf(wc, c + 0, fbf);
  s += (bf2f(xs4.y) + bf2f(xd4.y)) * ldf(wc, c + 1, fbf);
  s += (bf2f(xs4.z) + bf2f(xd4.z)) * ldf(wc, c + 2, fbf);
  s += (bf2f(xs4.w) + bf2f(xd4.w)) * ldf(wc, c + 3, fbf);
  for (int off = 32; off; off >>= 1) s += __shfl_xor(s, off);
  if (lane == 0) stout(out, p, s + ldf(bc, 0, fbf), fbf);
}

extern "C" void kernel_launch(void* const* d_in, const int* in_sizes, int n_in,
                              void* d_out, int out_size, void* d_ws, size_t ws_size,
                              hipStream_t stream) {
  const void* eidx  = d_in[0];
  const void* rawt  = d_in[1];
  const void* noise = d_in[2];
  const void* nemb  = d_in[3];
  const void *wq1 = d_in[4],  *bq1 = d_in[5];
  const void *wk1 = d_in[6],  *bk1 = d_in[7];
  const void *wv1 = d_in[8],  *bv1 = d_in[9];
  const void *wt1 = d_in[10], *bt1 = d_in[11];
  const void *wq2 = d_in[12], *bq2 = d_in[13];
  const void *wk2 = d_in[14], *bk2 = d_in[15];
  const void *wv2 = d_in[16], *bv2 = d_in[17];
  const void *wt2 = d_in[18], *bt2 = d_in[19];
  const void *wcp = d_in[20], *bcp = d_in[21];

  char* ws = (char*)d_ws;
  size_t off = 0;
  auto alloc = [&](size_t bytes) -> void* {
    void* p = ws + off;
    off += (bytes + 255) & ~(size_t)255;
    return p;
  };
  int*   flags = (int*)alloc(256);
  float* divt  = (float*)alloc(256);
  float* zbias = (float*)alloc(HC * 4);
  u16*   Wt    = (u16*)alloc((size_t)HC * HC * 2);
  u16*   WTt   = (u16*)alloc((size_t)HC * HC * 2);
  u16*   q     = (u16*)alloc((size_t)NN * HC * 2);
  u16*   k     = (u16*)alloc((size_t)NN * HC * 2);
  u16*   v     = (u16*)alloc((size_t)NN * HC * 2);
  u16*   qproj = (u16*)alloc((size_t)NN * HC * 2);
  float* qbt   = (float*)alloc((size_t)NN * 4 * 4);
  int* offsets = (int*)alloc((size_t)(NN + 1) * 4);
  int* cursor  = (int*)alloc((size_t)NN * 4);
  int* bsum    = (int*)alloc(256 * 4);
  int* esorted = (int*)alloc((size_t)NE * 4);
  float* alphaS = (float*)alloc((size_t)NE * 4 * 4);
  u16* x1 = qproj;  // aggregate L1 writes AFTER alpha L1 consumed qproj
  u16* x2 = q;      // aggregate L2 writes AFTER alpha L2 consumed q
  size_t need = off;

  int gN = (NN + 255) / 256, gE = (NE + 255) / 256, gEdge = (NE + 3) / 4;
  int nb = (NN + 255) / 256;

  if (ws_size < 1024) {
    raw_sentinel_kernel<<<gE, 256, 0, stream>>>((u16*)d_out);
    return;
  }
  devinit_kernel<<<1, 64, 0, stream>>>(eidx, nemb, flags, divt);
  if (need > ws_size) {
    sentinel_kernel<<<gE, 256, 0, stream>>>(flags, d_out);
    return;
  }

  zero_kernel<<<1, 256, 0, stream>>>((int*)zbias, HC);

  // CSR by dst
  zero_kernel<<<gN, 256, 0, stream>>>(cursor, NN);
  hist_kernel<<<gE, 256, 0, stream>>>(flags, eidx, cursor);
  scan1_kernel<<<nb, 256, 0, stream>>>(cursor, offsets, bsum, NN);
  scan2_kernel<<<1, 256, 0, stream>>>(bsum, offsets, nb, NN);
  scan3_kernel<<<nb, 256, 0, stream>>>(offsets, bsum, NN);
  copy_kernel<<<gN, 256, 0, stream>>>(offsets, cursor, NN);
  fill_kernel<<<gE, 256, 0, stream>>>(flags, eidx, cursor, esorted);

  dim3 gg((NN + 63) / 64, 4);
  dim3 gt1(NIN / 64, 4), gt2(HC / 64, 4);
  int gNode = (NN + 3) / 4;

  // Layer 1 (A = raw node_emb, K=128)
  transw_kernel<<<gt1, 256, 0, stream>>>(flags, wq1, Wt, NIN);
  gemm_mfma<false, false><<<gg, 256, 0, stream>>>(flags, nemb, Wt, bq1, q, NN, NIN);
  transw_kernel<<<gt1, 256, 0, stream>>>(flags, wk1, Wt, NIN);
  gemm_mfma<false, false><<<gg, 256, 0, stream>>>(flags, nemb, Wt, bk1, k, NN, NIN);
  transw_kernel<<<gt1, 256, 0, stream>>>(flags, wv1, Wt, NIN);
  gemm_mfma<false, false><<<gg, 256, 0, stream>>>(flags, nemb, Wt, bv1, v, NN, NIN);
  buildwtt_kernel<<<HC, HC, 0, stream>>>(flags, wt1, WTt);
  gemm_mfma<true, true><<<gg, 256, 0, stream>>>(flags, q, WTt, zbias, qproj, NN, HC);
  qbt_kernel<<<NN, 256, 0, stream>>>(flags, q, bt1, qbt);
  alpha_kernel<<<gEdge, 256, 0, stream>>>(flags, eidx, esorted, rawt, noise, q, k, qproj, qbt, divt, alphaS);
  aggregate_kernel<<<gNode, 256, 0, stream>>>(flags, eidx, esorted, offsets, alphaS, v, x1);

  // Layer 2 (A = bf16 x1, K=256)
  transw_kernel<<<gt2, 256, 0, stream>>>(flags, wq2, Wt, HC);
  gemm_mfma<true, false><<<gg, 256, 0, stream>>>(flags, x1, Wt, bq2, q, NN, HC);
  transw_kernel<<<gt2, 256, 0, stream>>>(flags, wk2, Wt, HC);
  gemm_mfma<true, false><<<gg, 256, 0, stream>>>(flags, x1, Wt, bk2, k, NN, HC);
  transw_kernel<<<gt2, 256, 0, stream>>>(flags, wv2, Wt, HC);
  gemm_mfma<true, false><<<gg, 256, 0, stream>>>(flags, x1, Wt, bv2, v, NN, HC);
  buildwtt_kernel<<<HC, HC, 0, stream>>>(flags, wt2, WTt);
  gemm_mfma<true, true><<<gg, 256, 0, stream>>>(flags, q, WTt, zbias, qproj, NN, HC);  // after x1 consumed
  qbt_kernel<<<NN, 256, 0, stream>>>(flags, q, bt2, qbt);
  alpha_kernel<<<gEdge, 256, 0, stream>>>(flags, eidx, esorted, rawt, noise, q, k, qproj, qbt, divt, alphaS);
  aggregate_kernel<<<gNode, 256, 0, stream>>>(flags, eidx, esorted, offsets, alphaS, v, x2);

  // Edge scorer
  final_kernel<<<gEdge, 256, 0, stream>>>(flags, eidx, x2, wcp, bcp, d_out);
}

// Round 6
// 758.288 us; speedup vs baseline: 3.2466x; 1.0119x over previous
//
#include <hip/hip_runtime.h>
#include <math.h>

// Problem constants
#define NN   20000     // nodes
#define NE   320000    // edges
#define NIN  128       // node input dim
#define HC   256       // heads(4) * hidden(64)

typedef unsigned short u16;
typedef __attribute__((ext_vector_type(8))) short bf16x8;
typedef __attribute__((ext_vector_type(4))) float f32x4;

__device__ __forceinline__ float bf2f(u16 u) {
  union { unsigned int i; float f; } x;
  x.i = ((unsigned int)u) << 16;
  return x.f;
}
__device__ __forceinline__ u16 f2bf(float f) {
  union { float f; unsigned int i; } x;
  x.f = f;
  unsigned int r = x.i + 0x7fffu + ((x.i >> 16) & 1u);
  return (u16)(r >> 16);
}

// dtype-flexible loads (flags detected on device each launch)
__device__ __forceinline__ float ldf(const void* p, int i, bool fbf) {
  return fbf ? bf2f(((const u16*)p)[i]) : ((const float*)p)[i];
}
__device__ __forceinline__ int ldsrc(const void* p, int e, bool is64) {
  const int* p32 = (const int*)p;
  return is64 ? p32[2 * e] : p32[e];
}
__device__ __forceinline__ int lddst(const void* p, int e, bool is64) {
  const int* p32 = (const int*)p;
  return is64 ? p32[2 * (NE + e)] : p32[NE + e];
}
__device__ __forceinline__ void stout(void* p, int i, float v, bool fbf) {
  if (fbf) ((u16*)p)[i] = f2bf(v);
  else ((float*)p)[i] = v;
}

// ---------------- detection + div_term init ----------------
__global__ void devinit_kernel(const void* __restrict__ eidx,
                               const void* __restrict__ nemb,
                               int* __restrict__ flags, float* __restrict__ divt) {
  int lane = threadIdx.x;
  if (lane < 32) {
    const float c32 = (float)(-0.14391156831212787);
    float prod = (float)(2 * lane) * c32;
    divt[lane] = (float)exp((double)prod);
  }
  if (lane == 0) {
    const int* p32 = (const int*)eidx;
    int is64 = 1;
    for (int i = 1; i < 128; i += 2)
      if (p32[i] != 0) { is64 = 0; break; }
    const u16* q16 = (const u16*)nemb;
    int fbf = 1;
    for (int i = 0; i < 128; i += 2) {
      unsigned e = (q16[i] >> 7) & 0xFF;
      if (e < 90 || e > 140) { fbf = 0; break; }
    }
    flags[0] = is64;
    flags[1] = fbf;
  }
}

__global__ void sentinel_kernel(const int* __restrict__ flags, void* __restrict__ out) {
  int i = blockIdx.x * 256 + threadIdx.x;
  if (i < NE) stout(out, i, 3000.0f, flags[1] != 0);
}
__global__ void raw_sentinel_kernel(u16* __restrict__ out) {
  int i = blockIdx.x * 256 + threadIdx.x;
  if (i < NE) out[i] = f2bf(3000.0f);
}

// ---------------- CSR build ----------------
__global__ void zero_kernel(int* __restrict__ p, int n) {
  int i = blockIdx.x * 256 + threadIdx.x;
  if (i < n) p[i] = 0;
}

__global__ void hist_kernel(const int* __restrict__ flags, const void* __restrict__ eidx,
                            int* __restrict__ cnt) {
  bool is64 = flags[0] != 0;
  int e = blockIdx.x * 256 + threadIdx.x;
  if (e < NE) {
    int d = lddst(eidx, e, is64);
    if ((unsigned)d < NN) atomicAdd(&cnt[d], 1);
  }
}

// hierarchical scan
__global__ void scan1_kernel(const int* __restrict__ cnt, int* __restrict__ offs,
                             int* __restrict__ bsum, int n) {
  __shared__ int s[256];
  int b = blockIdx.x, t = threadIdx.x, i = b * 256 + t;
  int x = (i < n) ? cnt[i] : 0;
  s[t] = x;
  __syncthreads();
  for (int off = 1; off < 256; off <<= 1) {
    int y = (t >= off) ? s[t - off] : 0;
    __syncthreads();
    s[t] += y;
    __syncthreads();
  }
  if (i < n) offs[i] = s[t] - x;
  if (t == 255) bsum[b] = s[t];
}

__global__ void scan2_kernel(int* __restrict__ bsum, int* __restrict__ offs,
                             int nb, int n) {
  __shared__ int s[256];
  int t = threadIdx.x;
  int x = (t < nb) ? bsum[t] : 0;
  s[t] = x;
  __syncthreads();
  for (int off = 1; off < 256; off <<= 1) {
    int y = (t >= off) ? s[t - off] : 0;
    __syncthreads();
    s[t] += y;
    __syncthreads();
  }
  if (t < nb) bsum[t] = s[t] - x;
  if (t == 255) offs[n] = s[t];
}

__global__ void scan3_kernel(int* __restrict__ offs, const int* __restrict__ bsum, int n) {
  int i = blockIdx.x * 256 + threadIdx.x;
  if (i < n) offs[i] += bsum[blockIdx.x];
}

__global__ void copy_kernel(const int* __restrict__ a, int* __restrict__ b, int n) {
  int i = blockIdx.x * 256 + threadIdx.x;
  if (i < n) b[i] = a[i];
}

__global__ void fill_kernel(const int* __restrict__ flags, const void* __restrict__ eidx,
                            int* __restrict__ cursor, int* __restrict__ esorted) {
  bool is64 = flags[0] != 0;
  int e = blockIdx.x * 256 + threadIdx.x;
  if (e < NE) {
    int d = lddst(eidx, e, is64);
    if ((unsigned)d < NN) {
      int pos = atomicAdd(&cursor[d], 1);
      if ((unsigned)pos < NE) esorted[pos] = e;
    }
  }
}

// ---------------- weight transpose: W[K,256] -> Wt[256][K] bf16 ----------------
__global__ void transw_kernel(const int* __restrict__ flags, const void* __restrict__ W,
                              u16* __restrict__ Wt, int K) {
  bool fbf = flags[1] != 0;
  __shared__ u16 tile[64][65];
  int kb = blockIdx.x * 64, cb = blockIdx.y * 64;
  int tx = threadIdx.x & 63, ty = threadIdx.x >> 6;
  for (int i = ty; i < 64; i += 4)
    tile[tx][i] = f2bf(ldf(W, (kb + i) * HC + cb + tx, fbf));
  __syncthreads();
  for (int i = ty; i < 64; i += 4)
    Wt[(size_t)(cb + i) * K + kb + tx] = tile[i][tx];
}

// block-diagonal time weight, pre-transposed bf16
__global__ void buildwtt_kernel(const int* __restrict__ flags, const void* __restrict__ wt,
                                u16* __restrict__ WTt) {
  bool fbf = flags[1] != 0;
  int col = blockIdx.x, k = threadIdx.x;
  int h = col >> 6, j = col & 63;
  u16 v = 0;
  if ((k >> 6) == h) v = f2bf(ldf(wt, j * HC + k, fbf));
  WTt[(size_t)col * HC + k] = v;
}

// ---------------- qbt[n,h] = q[n,h,:] . bt[h,:] (q bf16) ----------------
__global__ __launch_bounds__(256) void qbt_kernel(
    const int* __restrict__ flags, const u16* __restrict__ q,
    const void* __restrict__ bt, float* __restrict__ qbt) {
  bool fbf = flags[1] != 0;
  int t = threadIdx.x;
  int n = blockIdx.x;
  int h = t >> 6, j = t & 63;
  float pb = bf2f(q[(size_t)n * HC + t]) * ldf(bt, t, fbf);
  for (int off = 32; off; off >>= 1) pb += __shfl_xor(pb, off);
  if (j == 0) qbt[n * 4 + h] = pb;
}

// ---------------- MFMA GEMM: C[M,256](bf16) = A[M,K] @ Wt^T + bias ----------------
template <bool AWS, bool BF32>
__global__ __launch_bounds__(256) void gemm_mfma(
    const int* __restrict__ flags, const void* __restrict__ Ap,
    const u16* __restrict__ Wt, const void* __restrict__ bias,
    u16* __restrict__ C, int M, int K) {
  bool fbf = flags[1] != 0;
  __shared__ u16 As[64][56];
  __shared__ u16 Bs[64][56];
  int tid = threadIdx.x;
  int rb = blockIdx.x * 64, cb = blockIdx.y * 64;
  int wave = tid >> 6, lane = tid & 63;
  int l15 = lane & 15, quad = lane >> 4;

  f32x4 acc[4];
#pragma unroll
  for (int mt = 0; mt < 4; ++mt)
#pragma unroll
    for (int r = 0; r < 4; ++r) acc[mt][r] = 0.f;

  int srow = tid >> 2;
  int skq  = (tid & 3) * 8;

  for (int kk = 0; kk < K; kk += 32) {
    bf16x8 av;
#pragma unroll
    for (int i = 0; i < 8; ++i) av[i] = 0;
    int grow = rb + srow;
    if (grow < M) {
      if constexpr (AWS) {
        av = *(const bf16x8*)((const u16*)Ap + (size_t)grow * K + kk + skq);
      } else {
        if (fbf) {
          av = *(const bf16x8*)((const u16*)Ap + (size_t)grow * K + kk + skq);
        } else {
          const float* A = (const float*)Ap + (size_t)grow * K + kk + skq;
#pragma unroll
          for (int i = 0; i < 8; ++i) av[i] = (short)f2bf(A[i]);
        }
      }
    }
    *(bf16x8*)&As[srow][skq] = av;
    *(bf16x8*)&Bs[srow][skq] =
        *(const bf16x8*)(Wt + (size_t)(cb + srow) * K + kk + skq);
    __syncthreads();

    bf16x8 bfrag = *(const bf16x8*)&Bs[wave * 16 + l15][quad * 8];
#pragma unroll
    for (int mt = 0; mt < 4; ++mt) {
      bf16x8 afrag = *(const bf16x8*)&As[mt * 16 + l15][quad * 8];
      acc[mt] = __builtin_amdgcn_mfma_f32_16x16x32_bf16(afrag, bfrag, acc[mt], 0, 0, 0);
    }
    __syncthreads();
  }

  int gcol = cb + wave * 16 + l15;
  float bv;
  if constexpr (BF32) bv = ((const float*)bias)[gcol];
  else                bv = ldf(bias, gcol, fbf);
#pragma unroll
  for (int mt = 0; mt < 4; ++mt) {
#pragma unroll
    for (int r = 0; r < 4; ++r) {
      int grow = rb + mt * 16 + quad * 4 + r;
      if (grow < M) C[(size_t)grow * HC + gcol] = f2bf(acc[mt][r] + bv);
    }
  }
}

// ---------------- per-edge alpha: one wave per sorted position ----------------
// One transcendental per lane (te for channel index `lane`), then __shfl
// distributes the 4 values each lane needs for its channels 4l..4l+3.
__global__ __launch_bounds__(256) void alpha_kernel(
    const int* __restrict__ flags, const void* __restrict__ eidx,
    const int* __restrict__ esorted, const void* __restrict__ rawt,
    const void* __restrict__ noise, const u16* __restrict__ q,
    const u16* __restrict__ k, const u16* __restrict__ qproj,
    const float* __restrict__ qbt, const float* __restrict__ divt,
    float* __restrict__ alphaS) {
  bool is64 = flags[0] != 0, fbf = flags[1] != 0;
  int p = blockIdx.x * 4 + (threadIdx.x >> 6);
  if (p >= NE) return;
  int lane = threadIdx.x & 63;
  int h = lane >> 4;
  int e = esorted[p];
  if ((unsigned)e >= NE) {
    if ((lane & 15) == 0) alphaS[p * 4 + h] = 0.f;
    return;
  }
  int src = ldsrc(eidx, e, is64);
  int dst = lddst(eidx, e, is64);
  if ((unsigned)src >= NN) src = 0;
  if ((unsigned)dst >= NN) dst = 0;
  float tt = ldf(rawt, e, fbf) + ldf(noise, e, fbf);
  // lane computes te for channel index `lane`: even -> sin, odd -> cos
  float argl = tt * divt[lane >> 1];
  float tel = (lane & 1) ? cosf(argl) : sinf(argl);
  int base = (lane * 4) & 63;   // {0,4,...,60}
  float te0 = __shfl(tel, base);
  float te1 = __shfl(tel, base + 1);
  float te2 = __shfl(tel, base + 2);
  float te3 = __shfl(tel, base + 3);
  int c = lane * 4;
  ushort4 q4 = *(const ushort4*)(q + (size_t)dst * HC + c);
  ushort4 k4 = *(const ushort4*)(k + (size_t)src * HC + c);
  ushort4 p4 = *(const ushort4*)(qproj + (size_t)dst * HC + c);
  float s = bf2f(q4.x) * bf2f(k4.x) + te0 * bf2f(p4.x);
  s += bf2f(q4.y) * bf2f(k4.y) + te1 * bf2f(p4.y);
  s += bf2f(q4.z) * bf2f(k4.z) + te2 * bf2f(p4.z);
  s += bf2f(q4.w) * bf2f(k4.w) + te3 * bf2f(p4.w);
  s += __shfl_xor(s, 1);
  s += __shfl_xor(s, 2);
  s += __shfl_xor(s, 4);
  s += __shfl_xor(s, 8);
  if ((lane & 15) == 0)
    alphaS[p * 4 + h] = (s + qbt[dst * 4 + h]) * 0.125f;
}

// ---------------- segment softmax + aggregation + relu: one wave per node ----------
__global__ __launch_bounds__(256) void aggregate_kernel(
    const int* __restrict__ flags, const void* __restrict__ eidx,
    const int* __restrict__ esorted, const int* __restrict__ offsets,
    const float* __restrict__ alphaS, const u16* __restrict__ v,
    u16* __restrict__ xout) {
  bool is64 = flags[0] != 0;
  int n = blockIdx.x * 4 + (threadIdx.x >> 6);
  if (n >= NN) return;
  int lane = threadIdx.x & 63;
  int h = lane >> 4;
  int c = lane * 4;
  int s0 = offsets[n], s1 = offsets[n + 1];
  if (s0 < 0) s0 = 0;
  if (s1 > NE) s1 = NE;
  float m = -INFINITY;
  for (int p = s0; p < s1; ++p) m = fmaxf(m, alphaS[p * 4 + h]);
  float denom = 0.f;
  float acc0 = 0.f, acc1 = 0.f, acc2 = 0.f, acc3 = 0.f;
  for (int p = s0; p < s1; ++p) {
    float ea = expf(alphaS[p * 4 + h] - m);
    denom += ea;
    int e = esorted[p];
    if ((unsigned)e >= NE) continue;
    int src = ldsrc(eidx, e, is64);
    if ((unsigned)src >= NN) src = 0;
    ushort4 v4 = *(const ushort4*)(v + (size_t)src * HC + c);
    acc0 += ea * bf2f(v4.x);
    acc1 += ea * bf2f(v4.y);
    acc2 += ea * bf2f(v4.z);
    acc3 += ea * bf2f(v4.w);
  }
  float inv = 1.f / (denom + 1e-16f);
  ushort4 r;
  r.x = f2bf(fmaxf(acc0 * inv, 0.f));
  r.y = f2bf(fmaxf(acc1 * inv, 0.f));
  r.z = f2bf(fmaxf(acc2 * inv, 0.f));
  r.w = f2bf(fmaxf(acc3 * inv, 0.f));
  *(ushort4*)(xout + (size_t)n * HC + c) = r;
}

// ---------------- final: out[e] = (x[src]+x[dst]) . wc + bc ----------------
__global__ __launch_bounds__(256) void final_kernel(
    const int* __restrict__ flags, const void* __restrict__ eidx,
    const u16* __restrict__ x, const void* __restrict__ wc,
    const void* __restrict__ bc, void* __restrict__ out) {
  bool is64 = flags[0] != 0, fbf = flags[1] != 0;
  int p = blockIdx.x * 4 + (threadIdx.x >> 6);
  if (p >= NE) return;
  int lane = threadIdx.x & 63;
  int c = lane * 4;
  int src = ldsrc(eidx, p, is64);
  int dst = lddst(eidx, p, is64);
  if ((unsigned)src >= NN) src = 0;
  if ((unsigned)dst >= NN) dst = 0;
  ushort4 xs4 = *(const ushort4*)(x + (size_t)src * HC + c);
  ushort4 xd4 = *(const ushort4*)(x + (size_t)dst * HC + c);
  float s = (bf2f(xs4.x) + bf2f(xd4.x)) * ldf(wc, c + 0, fbf);
  s += (bf2f(xs4.y) + bf2f(xd4.y)) * ldf(wc, c + 1, fbf);
  s += (bf2f(xs4.z) + bf2f(xd4.z)) * ldf(wc, c + 2, fbf);
  s += (bf2f(xs4.w) + bf2f(xd4.w)) * ldf(wc, c + 3, fbf);
  for (int off = 32; off; off >>= 1) s += __shfl_xor(s, off);
  if (lane == 0) stout(out, p, s + ldf(bc, 0, fbf), fbf);
}

extern "C" void kernel_launch(void* const* d_in, const int* in_sizes, int n_in,
                              void* d_out, int out_size, void* d_ws, size_t ws_size,
                              hipStream_t stream) {
  const void* eidx  = d_in[0];
  const void* rawt  = d_in[1];
  const void* noise = d_in[2];
  const void* nemb  = d_in[3];
  const void *wq1 = d_in[4],  *bq1 = d_in[5];
  const void *wk1 = d_in[6],  *bk1 = d_in[7];
  const void *wv1 = d_in[8],  *bv1 = d_in[9];
  const void *wt1 = d_in[10], *bt1 = d_in[11];
  const void *wq2 = d_in[12], *bq2 = d_in[13];
  const void *wk2 = d_in[14], *bk2 = d_in[15];
  const void *wv2 = d_in[16], *bv2 = d_in[17];
  const void *wt2 = d_in[18], *bt2 = d_in[19];
  const void *wcp = d_in[20], *bcp = d_in[21];

  char* ws = (char*)d_ws;
  size_t off = 0;
  auto alloc = [&](size_t bytes) -> void* {
    void* p = ws + off;
    off += (bytes + 255) & ~(size_t)255;
    return p;
  };
  int*   flags = (int*)alloc(256);
  float* divt  = (float*)alloc(256);
  float* zbias = (float*)alloc(HC * 4);
  u16*   Wt    = (u16*)alloc((size_t)HC * HC * 2);
  u16*   WTt   = (u16*)alloc((size_t)HC * HC * 2);
  u16*   q     = (u16*)alloc((size_t)NN * HC * 2);
  u16*   k     = (u16*)alloc((size_t)NN * HC * 2);
  u16*   v     = (u16*)alloc((size_t)NN * HC * 2);
  u16*   qproj = (u16*)alloc((size_t)NN * HC * 2);
  float* qbt   = (float*)alloc((size_t)NN * 4 * 4);
  int* offsets = (int*)alloc((size_t)(NN + 1) * 4);
  int* cursor  = (int*)alloc((size_t)NN * 4);
  int* bsum    = (int*)alloc(256 * 4);
  int* esorted = (int*)alloc((size_t)NE * 4);
  float* alphaS = (float*)alloc((size_t)NE * 4 * 4);
  u16* x1 = qproj;
  u16* x2 = q;
  size_t need = off;

  int gN = (NN + 255) / 256, gE = (NE + 255) / 256, gEdge = (NE + 3) / 4;
  int nb = (NN + 255) / 256;

  if (ws_size < 1024) {
    raw_sentinel_kernel<<<gE, 256, 0, stream>>>((u16*)d_out);
    return;
  }
  devinit_kernel<<<1, 64, 0, stream>>>(eidx, nemb, flags, divt);
  if (need > ws_size) {
    sentinel_kernel<<<gE, 256, 0, stream>>>(flags, d_out);
    return;
  }

  zero_kernel<<<1, 256, 0, stream>>>((int*)zbias, HC);

  // CSR by dst
  zero_kernel<<<gN, 256, 0, stream>>>(cursor, NN);
  hist_kernel<<<gE, 256, 0, stream>>>(flags, eidx, cursor);
  scan1_kernel<<<nb, 256, 0, stream>>>(cursor, offsets, bsum, NN);
  scan2_kernel<<<1, 256, 0, stream>>>(bsum, offsets, nb, NN);
  scan3_kernel<<<nb, 256, 0, stream>>>(offsets, bsum, NN);
  copy_kernel<<<gN, 256, 0, stream>>>(offsets, cursor, NN);
  fill_kernel<<<gE, 256, 0, stream>>>(flags, eidx, cursor, esorted);

  dim3 gg((NN + 63) / 64, 4);
  dim3 gt1(NIN / 64, 4), gt2(HC / 64, 4);
  int gNode = (NN + 3) / 4;

  // Layer 1 (A = raw node_emb, K=128)
  transw_kernel<<<gt1, 256, 0, stream>>>(flags, wq1, Wt, NIN);
  gemm_mfma<false, false><<<gg, 256, 0, stream>>>(flags, nemb, Wt, bq1, q, NN, NIN);
  transw_kernel<<<gt1, 256, 0, stream>>>(flags, wk1, Wt, NIN);
  gemm_mfma<false, false><<<gg, 256, 0, stream>>>(flags, nemb, Wt, bk1, k, NN, NIN);
  transw_kernel<<<gt1, 256, 0, stream>>>(flags, wv1, Wt, NIN);
  gemm_mfma<false, false><<<gg, 256, 0, stream>>>(flags, nemb, Wt, bv1, v, NN, NIN);
  buildwtt_kernel<<<HC, HC, 0, stream>>>(flags, wt1, WTt);
  gemm_mfma<true, true><<<gg, 256, 0, stream>>>(flags, q, WTt, zbias, qproj, NN, HC);
  qbt_kernel<<<NN, 256, 0, stream>>>(flags, q, bt1, qbt);
  alpha_kernel<<<gEdge, 256, 0, stream>>>(flags, eidx, esorted, rawt, noise, q, k, qproj, qbt, divt, alphaS);
  aggregate_kernel<<<gNode, 256, 0, stream>>>(flags, eidx, esorted, offsets, alphaS, v, x1);

  // Layer 2 (A = bf16 x1, K=256)
  transw_kernel<<<gt2, 256, 0, stream>>>(flags, wq2, Wt, HC);
  gemm_mfma<true, false><<<gg, 256, 0, stream>>>(flags, x1, Wt, bq2, q, NN, HC);
  transw_kernel<<<gt2, 256, 0, stream>>>(flags, wk2, Wt, HC);
  gemm_mfma<true, false><<<gg, 256, 0, stream>>>(flags, x1, Wt, bk2, k, NN, HC);
  transw_kernel<<<gt2, 256, 0, stream>>>(flags, wv2, Wt, HC);
  gemm_mfma<true, false><<<gg, 256, 0, stream>>>(flags, x1, Wt, bv2, v, NN, HC);
  buildwtt_kernel<<<HC, HC, 0, stream>>>(flags, wt2, WTt);
  gemm_mfma<true, true><<<gg, 256, 0, stream>>>(flags, q, WTt, zbias, qproj, NN, HC);
  qbt_kernel<<<NN, 256, 0, stream>>>(flags, q, bt2, qbt);
  alpha_kernel<<<gEdge, 256, 0, stream>>>(flags, eidx, esorted, rawt, noise, q, k, qproj, qbt, divt, alphaS);
  aggregate_kernel<<<gNode, 256, 0, stream>>>(flags, eidx, esorted, offsets, alphaS, v, x2);

  // Edge scorer
  final_kernel<<<gEdge, 256, 0, stream>>>(flags, eidx, x2, wcp, bcp, d_out);
}

// Round 7
// 671.304 us; speedup vs baseline: 3.6673x; 1.1296x over previous
//
#include <hip/hip_runtime.h>
#include <math.h>

// Problem constants
#define NN   20000     // nodes
#define NE   320000    // edges
#define NIN  128       // node input dim
#define HC   256       // heads(4) * hidden(64)

typedef unsigned short u16;
typedef __attribute__((ext_vector_type(8))) short bf16x8;
typedef __attribute__((ext_vector_type(4))) float f32x4;

__device__ __forceinline__ float bf2f(u16 u) {
  union { unsigned int i; float f; } x;
  x.i = ((unsigned int)u) << 16;
  return x.f;
}
__device__ __forceinline__ u16 f2bf(float f) {
  union { float f; unsigned int i; } x;
  x.f = f;
  unsigned int r = x.i + 0x7fffu + ((x.i >> 16) & 1u);
  return (u16)(r >> 16);
}

// dtype-flexible loads (flags detected on device each launch)
__device__ __forceinline__ float ldf(const void* p, int i, bool fbf) {
  return fbf ? bf2f(((const u16*)p)[i]) : ((const float*)p)[i];
}
__device__ __forceinline__ int ldsrc(const void* p, int e, bool is64) {
  const int* p32 = (const int*)p;
  return is64 ? p32[2 * e] : p32[e];
}
__device__ __forceinline__ int lddst(const void* p, int e, bool is64) {
  const int* p32 = (const int*)p;
  return is64 ? p32[2 * (NE + e)] : p32[NE + e];
}
__device__ __forceinline__ void stout(void* p, int i, float v, bool fbf) {
  if (fbf) ((u16*)p)[i] = f2bf(v);
  else ((float*)p)[i] = v;
}

// ---------------- detection + div_term init ----------------
__global__ void devinit_kernel(const void* __restrict__ eidx,
                               const void* __restrict__ nemb,
                               int* __restrict__ flags, float* __restrict__ divt) {
  int lane = threadIdx.x;
  if (lane < 32) {
    const float c32 = (float)(-0.14391156831212787);
    float prod = (float)(2 * lane) * c32;
    divt[lane] = (float)exp((double)prod);
  }
  if (lane == 0) {
    const int* p32 = (const int*)eidx;
    int is64 = 1;
    for (int i = 1; i < 128; i += 2)
      if (p32[i] != 0) { is64 = 0; break; }
    const u16* q16 = (const u16*)nemb;
    int fbf = 1;
    for (int i = 0; i < 128; i += 2) {
      unsigned e = (q16[i] >> 7) & 0xFF;
      if (e < 90 || e > 140) { fbf = 0; break; }
    }
    flags[0] = is64;
    flags[1] = fbf;
  }
}

__global__ void sentinel_kernel(const int* __restrict__ flags, void* __restrict__ out) {
  int i = blockIdx.x * 256 + threadIdx.x;
  if (i < NE) stout(out, i, 3000.0f, flags[1] != 0);
}
__global__ void raw_sentinel_kernel(u16* __restrict__ out) {
  int i = blockIdx.x * 256 + threadIdx.x;
  if (i < NE) out[i] = f2bf(3000.0f);
}

// ---------------- CSR build ----------------
__global__ void zero_kernel(int* __restrict__ p, int n) {
  int i = blockIdx.x * 256 + threadIdx.x;
  if (i < n) p[i] = 0;
}

__global__ void hist_kernel(const int* __restrict__ flags, const void* __restrict__ eidx,
                            int* __restrict__ cnt) {
  bool is64 = flags[0] != 0;
  int e = blockIdx.x * 256 + threadIdx.x;
  if (e < NE) {
    int d = lddst(eidx, e, is64);
    if ((unsigned)d < NN) atomicAdd(&cnt[d], 1);
  }
}

// hierarchical scan
__global__ void scan1_kernel(const int* __restrict__ cnt, int* __restrict__ offs,
                             int* __restrict__ bsum, int n) {
  __shared__ int s[256];
  int b = blockIdx.x, t = threadIdx.x, i = b * 256 + t;
  int x = (i < n) ? cnt[i] : 0;
  s[t] = x;
  __syncthreads();
  for (int off = 1; off < 256; off <<= 1) {
    int y = (t >= off) ? s[t - off] : 0;
    __syncthreads();
    s[t] += y;
    __syncthreads();
  }
  if (i < n) offs[i] = s[t] - x;
  if (t == 255) bsum[b] = s[t];
}

__global__ void scan2_kernel(int* __restrict__ bsum, int* __restrict__ offs,
                             int nb, int n) {
  __shared__ int s[256];
  int t = threadIdx.x;
  int x = (t < nb) ? bsum[t] : 0;
  s[t] = x;
  __syncthreads();
  for (int off = 1; off < 256; off <<= 1) {
    int y = (t >= off) ? s[t - off] : 0;
    __syncthreads();
    s[t] += y;
    __syncthreads();
  }
  if (t < nb) bsum[t] = s[t] - x;
  if (t == 255) offs[n] = s[t];
}

__global__ void scan3_kernel(int* __restrict__ offs, const int* __restrict__ bsum, int n) {
  int i = blockIdx.x * 256 + threadIdx.x;
  if (i < n) offs[i] += bsum[blockIdx.x];
}

__global__ void copy_kernel(const int* __restrict__ a, int* __restrict__ b, int n) {
  int i = blockIdx.x * 256 + threadIdx.x;
  if (i < n) b[i] = a[i];
}

__global__ void fill_kernel(const int* __restrict__ flags, const void* __restrict__ eidx,
                            int* __restrict__ cursor, int* __restrict__ esorted) {
  bool is64 = flags[0] != 0;
  int e = blockIdx.x * 256 + threadIdx.x;
  if (e < NE) {
    int d = lddst(eidx, e, is64);
    if ((unsigned)d < NN) {
      int pos = atomicAdd(&cursor[d], 1);
      if ((unsigned)pos < NE) esorted[pos] = e;
    }
  }
}

// ---------------- weight transpose: W[K,256] -> Wt[256][K] bf16 ----------------
__global__ void transw_kernel(const int* __restrict__ flags, const void* __restrict__ W,
                              u16* __restrict__ Wt, int K) {
  bool fbf = flags[1] != 0;
  __shared__ u16 tile[64][65];
  int kb = blockIdx.x * 64, cb = blockIdx.y * 64;
  int tx = threadIdx.x & 63, ty = threadIdx.x >> 6;
  for (int i = ty; i < 64; i += 4)
    tile[tx][i] = f2bf(ldf(W, (kb + i) * HC + cb + tx, fbf));
  __syncthreads();
  for (int i = ty; i < 64; i += 4)
    Wt[(size_t)(cb + i) * K + kb + tx] = tile[i][tx];
}

// block-diagonal time weight, pre-transposed bf16
__global__ void buildwtt_kernel(const int* __restrict__ flags, const void* __restrict__ wt,
                                u16* __restrict__ WTt) {
  bool fbf = flags[1] != 0;
  int col = blockIdx.x, k = threadIdx.x;
  int h = col >> 6, j = col & 63;
  u16 v = 0;
  if ((k >> 6) == h) v = f2bf(ldf(wt, j * HC + k, fbf));
  WTt[(size_t)col * HC + k] = v;
}

// ---------------- qbt[n,h] = q[n,h,:] . bt[h,:] (q bf16) ----------------
__global__ __launch_bounds__(256) void qbt_kernel(
    const int* __restrict__ flags, const u16* __restrict__ q,
    const void* __restrict__ bt, float* __restrict__ qbt) {
  bool fbf = flags[1] != 0;
  int t = threadIdx.x;
  int n = blockIdx.x;
  int h = t >> 6, j = t & 63;
  float pb = bf2f(q[(size_t)n * HC + t]) * ldf(bt, t, fbf);
  for (int off = 32; off; off >>= 1) pb += __shfl_xor(pb, off);
  if (j == 0) qbt[n * 4 + h] = pb;
}

// ---------------- MFMA GEMM: C[M,256](bf16) = A[M,K] @ Wt^T + bias ----------------
template <bool AWS, bool BF32>
__global__ __launch_bounds__(256) void gemm_mfma(
    const int* __restrict__ flags, const void* __restrict__ Ap,
    const u16* __restrict__ Wt, const void* __restrict__ bias,
    u16* __restrict__ C, int M, int K) {
  bool fbf = flags[1] != 0;
  __shared__ u16 As[64][56];
  __shared__ u16 Bs[64][56];
  int tid = threadIdx.x;
  int rb = blockIdx.x * 64, cb = blockIdx.y * 64;
  int wave = tid >> 6, lane = tid & 63;
  int l15 = lane & 15, quad = lane >> 4;

  f32x4 acc[4];
#pragma unroll
  for (int mt = 0; mt < 4; ++mt)
#pragma unroll
    for (int r = 0; r < 4; ++r) acc[mt][r] = 0.f;

  int srow = tid >> 2;
  int skq  = (tid & 3) * 8;

  for (int kk = 0; kk < K; kk += 32) {
    bf16x8 av;
#pragma unroll
    for (int i = 0; i < 8; ++i) av[i] = 0;
    int grow = rb + srow;
    if (grow < M) {
      if constexpr (AWS) {
        av = *(const bf16x8*)((const u16*)Ap + (size_t)grow * K + kk + skq);
      } else {
        if (fbf) {
          av = *(const bf16x8*)((const u16*)Ap + (size_t)grow * K + kk + skq);
        } else {
          const float* A = (const float*)Ap + (size_t)grow * K + kk + skq;
#pragma unroll
          for (int i = 0; i < 8; ++i) av[i] = (short)f2bf(A[i]);
        }
      }
    }
    *(bf16x8*)&As[srow][skq] = av;
    *(bf16x8*)&Bs[srow][skq] =
        *(const bf16x8*)(Wt + (size_t)(cb + srow) * K + kk + skq);
    __syncthreads();

    bf16x8 bfrag = *(const bf16x8*)&Bs[wave * 16 + l15][quad * 8];
#pragma unroll
    for (int mt = 0; mt < 4; ++mt) {
      bf16x8 afrag = *(const bf16x8*)&As[mt * 16 + l15][quad * 8];
      acc[mt] = __builtin_amdgcn_mfma_f32_16x16x32_bf16(afrag, bfrag, acc[mt], 0, 0, 0);
    }
    __syncthreads();
  }

  int gcol = cb + wave * 16 + l15;
  float bv;
  if constexpr (BF32) bv = ((const float*)bias)[gcol];
  else                bv = ldf(bias, gcol, fbf);
#pragma unroll
  for (int mt = 0; mt < 4; ++mt) {
#pragma unroll
    for (int r = 0; r < 4; ++r) {
      int grow = rb + mt * 16 + quad * 4 + r;
      if (grow < M) C[(size_t)grow * HC + gcol] = f2bf(acc[mt][r] + bv);
    }
  }
}

// ---------------- per-edge alpha: one wave per sorted position ----------------
__global__ __launch_bounds__(256) void alpha_kernel(
    const int* __restrict__ flags, const void* __restrict__ eidx,
    const int* __restrict__ esorted, const void* __restrict__ rawt,
    const void* __restrict__ noise, const u16* __restrict__ q,
    const u16* __restrict__ k, const u16* __restrict__ qproj,
    const float* __restrict__ qbt, const float* __restrict__ divt,
    float* __restrict__ alphaS) {
  bool is64 = flags[0] != 0, fbf = flags[1] != 0;
  int p = blockIdx.x * 4 + (threadIdx.x >> 6);
  if (p >= NE) return;
  int lane = threadIdx.x & 63;
  int h = lane >> 4;
  int e = esorted[p];
  if ((unsigned)e >= NE) {
    if ((lane & 15) == 0) alphaS[p * 4 + h] = 0.f;
    return;
  }
  int src = ldsrc(eidx, e, is64);
  int dst = lddst(eidx, e, is64);
  if ((unsigned)src >= NN) src = 0;
  if ((unsigned)dst >= NN) dst = 0;
  float tt = ldf(rawt, e, fbf) + ldf(noise, e, fbf);
  // lane computes te for channel index `lane`: even -> sin, odd -> cos
  float argl = tt * divt[lane >> 1];
  float tel = (lane & 1) ? cosf(argl) : sinf(argl);
  int base = (lane * 4) & 63;
  float te0 = __shfl(tel, base);
  float te1 = __shfl(tel, base + 1);
  float te2 = __shfl(tel, base + 2);
  float te3 = __shfl(tel, base + 3);
  int c = lane * 4;
  ushort4 q4 = *(const ushort4*)(q + (size_t)dst * HC + c);
  ushort4 k4 = *(const ushort4*)(k + (size_t)src * HC + c);
  ushort4 p4 = *(const ushort4*)(qproj + (size_t)dst * HC + c);
  float s = bf2f(q4.x) * bf2f(k4.x) + te0 * bf2f(p4.x);
  s += bf2f(q4.y) * bf2f(k4.y) + te1 * bf2f(p4.y);
  s += bf2f(q4.z) * bf2f(k4.z) + te2 * bf2f(p4.z);
  s += bf2f(q4.w) * bf2f(k4.w) + te3 * bf2f(p4.w);
  s += __shfl_xor(s, 1);
  s += __shfl_xor(s, 2);
  s += __shfl_xor(s, 4);
  s += __shfl_xor(s, 8);
  if ((lane & 15) == 0)
    alphaS[p * 4 + h] = (s + qbt[dst * 4 + h]) * 0.125f;
}

// ---------------- segment softmax + aggregation + relu: one wave per node ----------
__global__ __launch_bounds__(256) void aggregate_kernel(
    const int* __restrict__ flags, const void* __restrict__ eidx,
    const int* __restrict__ esorted, const int* __restrict__ offsets,
    const float* __restrict__ alphaS, const u16* __restrict__ v,
    u16* __restrict__ xout) {
  bool is64 = flags[0] != 0;
  int n = blockIdx.x * 4 + (threadIdx.x >> 6);
  if (n >= NN) return;
  int lane = threadIdx.x & 63;
  int h = lane >> 4;
  int c = lane * 4;
  int s0 = offsets[n], s1 = offsets[n + 1];
  if (s0 < 0) s0 = 0;
  if (s1 > NE) s1 = NE;
  float m = -INFINITY;
  for (int p = s0; p < s1; ++p) m = fmaxf(m, alphaS[p * 4 + h]);
  float denom = 0.f;
  float acc0 = 0.f, acc1 = 0.f, acc2 = 0.f, acc3 = 0.f;
  for (int p = s0; p < s1; ++p) {
    float ea = expf(alphaS[p * 4 + h] - m);
    denom += ea;
    int e = esorted[p];
    if ((unsigned)e >= NE) continue;
    int src = ldsrc(eidx, e, is64);
    if ((unsigned)src >= NN) src = 0;
    ushort4 v4 = *(const ushort4*)(v + (size_t)src * HC + c);
    acc0 += ea * bf2f(v4.x);
    acc1 += ea * bf2f(v4.y);
    acc2 += ea * bf2f(v4.z);
    acc3 += ea * bf2f(v4.w);
  }
  float inv = 1.f / (denom + 1e-16f);
  ushort4 r;
  r.x = f2bf(fmaxf(acc0 * inv, 0.f));
  r.y = f2bf(fmaxf(acc1 * inv, 0.f));
  r.z = f2bf(fmaxf(acc2 * inv, 0.f));
  r.w = f2bf(fmaxf(acc3 * inv, 0.f));
  *(ushort4*)(xout + (size_t)n * HC + c) = r;
}

// ---------------- y[n] = x[n,:] . wc  (per-node edge-scorer projection) ----------
__global__ __launch_bounds__(256) void xwc_kernel(
    const int* __restrict__ flags, const u16* __restrict__ x,
    const void* __restrict__ wc, float* __restrict__ y) {
  bool fbf = flags[1] != 0;
  int n = blockIdx.x * 4 + (threadIdx.x >> 6);
  if (n >= NN) return;
  int lane = threadIdx.x & 63;
  int c = lane * 4;
  ushort4 x4 = *(const ushort4*)(x + (size_t)n * HC + c);
  float s = bf2f(x4.x) * ldf(wc, c + 0, fbf);
  s += bf2f(x4.y) * ldf(wc, c + 1, fbf);
  s += bf2f(x4.z) * ldf(wc, c + 2, fbf);
  s += bf2f(x4.w) * ldf(wc, c + 3, fbf);
  for (int off = 32; off; off >>= 1) s += __shfl_xor(s, off);
  if (lane == 0) y[n] = s;
}

// ---------------- out[e] = y[src] + y[dst] + bc (y is 80 KB, L2-resident) --------
__global__ __launch_bounds__(256) void final2_kernel(
    const int* __restrict__ flags, const void* __restrict__ eidx,
    const float* __restrict__ y, const void* __restrict__ bc,
    void* __restrict__ out) {
  bool is64 = flags[0] != 0, fbf = flags[1] != 0;
  int e = blockIdx.x * 256 + threadIdx.x;
  if (e >= NE) return;
  int src = ldsrc(eidx, e, is64);
  int dst = lddst(eidx, e, is64);
  if ((unsigned)src >= NN) src = 0;
  if ((unsigned)dst >= NN) dst = 0;
  stout(out, e, y[src] + y[dst] + ldf(bc, 0, fbf), fbf);
}

extern "C" void kernel_launch(void* const* d_in, const int* in_sizes, int n_in,
                              void* d_out, int out_size, void* d_ws, size_t ws_size,
                              hipStream_t stream) {
  const void* eidx  = d_in[0];
  const void* rawt  = d_in[1];
  const void* noise = d_in[2];
  const void* nemb  = d_in[3];
  const void *wq1 = d_in[4],  *bq1 = d_in[5];
  const void *wk1 = d_in[6],  *bk1 = d_in[7];
  const void *wv1 = d_in[8],  *bv1 = d_in[9];
  const void *wt1 = d_in[10], *bt1 = d_in[11];
  const void *wq2 = d_in[12], *bq2 = d_in[13];
  const void *wk2 = d_in[14], *bk2 = d_in[15];
  const void *wv2 = d_in[16], *bv2 = d_in[17];
  const void *wt2 = d_in[18], *bt2 = d_in[19];
  const void *wcp = d_in[20], *bcp = d_in[21];

  char* ws = (char*)d_ws;
  size_t off = 0;
  auto alloc = [&](size_t bytes) -> void* {
    void* p = ws + off;
    off += (bytes + 255) & ~(size_t)255;
    return p;
  };
  int*   flags = (int*)alloc(256);
  float* divt  = (float*)alloc(256);
  float* zbias = (float*)alloc(HC * 4);
  u16*   Wt    = (u16*)alloc((size_t)HC * HC * 2);
  u16*   WTt   = (u16*)alloc((size_t)HC * HC * 2);
  u16*   q     = (u16*)alloc((size_t)NN * HC * 2);
  u16*   k     = (u16*)alloc((size_t)NN * HC * 2);
  u16*   v     = (u16*)alloc((size_t)NN * HC * 2);
  u16*   qproj = (u16*)alloc((size_t)NN * HC * 2);
  float* qbt   = (float*)alloc((size_t)NN * 4 * 4);
  float* ynode = (float*)alloc((size_t)NN * 4);
  int* offsets = (int*)alloc((size_t)(NN + 1) * 4);
  int* cursor  = (int*)alloc((size_t)NN * 4);
  int* bsum    = (int*)alloc(256 * 4);
  int* esorted = (int*)alloc((size_t)NE * 4);
  float* alphaS = (float*)alloc((size_t)NE * 4 * 4);
  u16* x1 = qproj;
  u16* x2 = q;
  size_t need = off;

  int gN = (NN + 255) / 256, gE = (NE + 255) / 256, gEdge = (NE + 3) / 4;
  int nb = (NN + 255) / 256;

  if (ws_size < 1024) {
    raw_sentinel_kernel<<<gE, 256, 0, stream>>>((u16*)d_out);
    return;
  }
  devinit_kernel<<<1, 64, 0, stream>>>(eidx, nemb, flags, divt);
  if (need > ws_size) {
    sentinel_kernel<<<gE, 256, 0, stream>>>(flags, d_out);
    return;
  }

  zero_kernel<<<1, 256, 0, stream>>>((int*)zbias, HC);

  // CSR by dst
  zero_kernel<<<gN, 256, 0, stream>>>(cursor, NN);
  hist_kernel<<<gE, 256, 0, stream>>>(flags, eidx, cursor);
  scan1_kernel<<<nb, 256, 0, stream>>>(cursor, offsets, bsum, NN);
  scan2_kernel<<<1, 256, 0, stream>>>(bsum, offsets, nb, NN);
  scan3_kernel<<<nb, 256, 0, stream>>>(offsets, bsum, NN);
  copy_kernel<<<gN, 256, 0, stream>>>(offsets, cursor, NN);
  fill_kernel<<<gE, 256, 0, stream>>>(flags, eidx, cursor, esorted);

  dim3 gg((NN + 63) / 64, 4);
  dim3 gt1(NIN / 64, 4), gt2(HC / 64, 4);
  int gNode = (NN + 3) / 4;

  // Layer 1 (A = raw node_emb, K=128)
  transw_kernel<<<gt1, 256, 0, stream>>>(flags, wq1, Wt, NIN);
  gemm_mfma<false, false><<<gg, 256, 0, stream>>>(flags, nemb, Wt, bq1, q, NN, NIN);
  transw_kernel<<<gt1, 256, 0, stream>>>(flags, wk1, Wt, NIN);
  gemm_mfma<false, false><<<gg, 256, 0, stream>>>(flags, nemb, Wt, bk1, k, NN, NIN);
  transw_kernel<<<gt1, 256, 0, stream>>>(flags, wv1, Wt, NIN);
  gemm_mfma<false, false><<<gg, 256, 0, stream>>>(flags, nemb, Wt, bv1, v, NN, NIN);
  buildwtt_kernel<<<HC, HC, 0, stream>>>(flags, wt1, WTt);
  gemm_mfma<true, true><<<gg, 256, 0, stream>>>(flags, q, WTt, zbias, qproj, NN, HC);
  qbt_kernel<<<NN, 256, 0, stream>>>(flags, q, bt1, qbt);
  alpha_kernel<<<gEdge, 256, 0, stream>>>(flags, eidx, esorted, rawt, noise, q, k, qproj, qbt, divt, alphaS);
  aggregate_kernel<<<gNode, 256, 0, stream>>>(flags, eidx, esorted, offsets, alphaS, v, x1);

  // Layer 2 (A = bf16 x1, K=256)
  transw_kernel<<<gt2, 256, 0, stream>>>(flags, wq2, Wt, HC);
  gemm_mfma<true, false><<<gg, 256, 0, stream>>>(flags, x1, Wt, bq2, q, NN, HC);
  transw_kernel<<<gt2, 256, 0, stream>>>(flags, wk2, Wt, HC);
  gemm_mfma<true, false><<<gg, 256, 0, stream>>>(flags, x1, Wt, bk2, k, NN, HC);
  transw_kernel<<<gt2, 256, 0, stream>>>(flags, wv2, Wt, HC);
  gemm_mfma<true, false><<<gg, 256, 0, stream>>>(flags, x1, Wt, bv2, v, NN, HC);
  buildwtt_kernel<<<HC, HC, 0, stream>>>(flags, wt2, WTt);
  gemm_mfma<true, true><<<gg, 256, 0, stream>>>(flags, q, WTt, zbias, qproj, NN, HC);
  qbt_kernel<<<NN, 256, 0, stream>>>(flags, q, bt2, qbt);
  alpha_kernel<<<gEdge, 256, 0, stream>>>(flags, eidx, esorted, rawt, noise, q, k, qproj, qbt, divt, alphaS);
  aggregate_kernel<<<gNode, 256, 0, stream>>>(flags, eidx, esorted, offsets, alphaS, v, x2);

  // Edge scorer: y[n] = x2[n].wc, then out[e] = y[src]+y[dst]+bc
  xwc_kernel<<<gNode, 256, 0, stream>>>(flags, x2, wcp, ynode);
  final2_kernel<<<gE, 256, 0, stream>>>(flags, eidx, ynode, bcp, d_out);
}

// Round 8
// 574.932 us; speedup vs baseline: 4.2821x; 1.1676x over previous
//
#include <hip/hip_runtime.h>
#include <math.h>

// Problem constants
#define NN   20000     // nodes
#define NE   320000    // edges
#define NIN  128       // node input dim
#define HC   256       // heads(4) * hidden(64)
#define CAP  128       // per-wave LDS alpha cache (degree overflow -> global)

typedef unsigned short u16;
typedef __attribute__((ext_vector_type(8))) short bf16x8;
typedef __attribute__((ext_vector_type(4))) float f32x4;

__device__ __forceinline__ float bf2f(u16 u) {
  union { unsigned int i; float f; } x;
  x.i = ((unsigned int)u) << 16;
  return x.f;
}
__device__ __forceinline__ u16 f2bf(float f) {
  union { float f; unsigned int i; } x;
  x.f = f;
  unsigned int r = x.i + 0x7fffu + ((x.i >> 16) & 1u);
  return (u16)(r >> 16);
}

// dtype-flexible loads (flags detected on device each launch)
__device__ __forceinline__ float ldf(const void* p, int i, bool fbf) {
  return fbf ? bf2f(((const u16*)p)[i]) : ((const float*)p)[i];
}
__device__ __forceinline__ int ldsrc(const void* p, int e, bool is64) {
  const int* p32 = (const int*)p;
  return is64 ? p32[2 * e] : p32[e];
}
__device__ __forceinline__ int lddst(const void* p, int e, bool is64) {
  const int* p32 = (const int*)p;
  return is64 ? p32[2 * (NE + e)] : p32[NE + e];
}
__device__ __forceinline__ void stout(void* p, int i, float v, bool fbf) {
  if (fbf) ((u16*)p)[i] = f2bf(v);
  else ((float*)p)[i] = v;
}

// ---------------- detection + div_term init ----------------
__global__ void devinit_kernel(const void* __restrict__ eidx,
                               const void* __restrict__ nemb,
                               int* __restrict__ flags, float* __restrict__ divt) {
  int lane = threadIdx.x;
  if (lane < 32) {
    const float c32 = (float)(-0.14391156831212787);
    float prod = (float)(2 * lane) * c32;
    divt[lane] = (float)exp((double)prod);
  }
  if (lane == 0) {
    const int* p32 = (const int*)eidx;
    int is64 = 1;
    for (int i = 1; i < 128; i += 2)
      if (p32[i] != 0) { is64 = 0; break; }
    const u16* q16 = (const u16*)nemb;
    int fbf = 1;
    for (int i = 0; i < 128; i += 2) {
      unsigned e = (q16[i] >> 7) & 0xFF;
      if (e < 90 || e > 140) { fbf = 0; break; }
    }
    flags[0] = is64;
    flags[1] = fbf;
  }
}

__global__ void sentinel_kernel(const int* __restrict__ flags, void* __restrict__ out) {
  int i = blockIdx.x * 256 + threadIdx.x;
  if (i < NE) stout(out, i, 3000.0f, flags[1] != 0);
}
__global__ void raw_sentinel_kernel(u16* __restrict__ out) {
  int i = blockIdx.x * 256 + threadIdx.x;
  if (i < NE) out[i] = f2bf(3000.0f);
}

// ---------------- CSR build ----------------
__global__ void zero_kernel(int* __restrict__ p, int n) {
  int i = blockIdx.x * 256 + threadIdx.x;
  if (i < n) p[i] = 0;
}

__global__ void hist_kernel(const int* __restrict__ flags, const void* __restrict__ eidx,
                            int* __restrict__ cnt) {
  bool is64 = flags[0] != 0;
  int e = blockIdx.x * 256 + threadIdx.x;
  if (e < NE) {
    int d = lddst(eidx, e, is64);
    if ((unsigned)d < NN) atomicAdd(&cnt[d], 1);
  }
}

// hierarchical scan
__global__ void scan1_kernel(const int* __restrict__ cnt, int* __restrict__ offs,
                             int* __restrict__ bsum, int n) {
  __shared__ int s[256];
  int b = blockIdx.x, t = threadIdx.x, i = b * 256 + t;
  int x = (i < n) ? cnt[i] : 0;
  s[t] = x;
  __syncthreads();
  for (int off = 1; off < 256; off <<= 1) {
    int y = (t >= off) ? s[t - off] : 0;
    __syncthreads();
    s[t] += y;
    __syncthreads();
  }
  if (i < n) offs[i] = s[t] - x;
  if (t == 255) bsum[b] = s[t];
}

__global__ void scan2_kernel(int* __restrict__ bsum, int* __restrict__ offs,
                             int nb, int n) {
  __shared__ int s[256];
  int t = threadIdx.x;
  int x = (t < nb) ? bsum[t] : 0;
  s[t] = x;
  __syncthreads();
  for (int off = 1; off < 256; off <<= 1) {
    int y = (t >= off) ? s[t - off] : 0;
    __syncthreads();
    s[t] += y;
    __syncthreads();
  }
  if (t < nb) bsum[t] = s[t] - x;
  if (t == 255) offs[n] = s[t];
}

__global__ void scan3_kernel(int* __restrict__ offs, const int* __restrict__ bsum, int n) {
  int i = blockIdx.x * 256 + threadIdx.x;
  if (i < n) offs[i] += bsum[blockIdx.x];
}

__global__ void copy_kernel(const int* __restrict__ a, int* __restrict__ b, int n) {
  int i = blockIdx.x * 256 + threadIdx.x;
  if (i < n) b[i] = a[i];
}

__global__ void fill_kernel(const int* __restrict__ flags, const void* __restrict__ eidx,
                            int* __restrict__ cursor, int* __restrict__ esorted) {
  bool is64 = flags[0] != 0;
  int e = blockIdx.x * 256 + threadIdx.x;
  if (e < NE) {
    int d = lddst(eidx, e, is64);
    if ((unsigned)d < NN) {
      int pos = atomicAdd(&cursor[d], 1);
      if ((unsigned)pos < NE) esorted[pos] = e;
    }
  }
}

// ---------------- weight transpose: W[K,256] -> Wt[256][K] bf16 ----------------
__global__ void transw_kernel(const int* __restrict__ flags, const void* __restrict__ W,
                              u16* __restrict__ Wt, int K) {
  bool fbf = flags[1] != 0;
  __shared__ u16 tile[64][65];
  int kb = blockIdx.x * 64, cb = blockIdx.y * 64;
  int tx = threadIdx.x & 63, ty = threadIdx.x >> 6;
  for (int i = ty; i < 64; i += 4)
    tile[tx][i] = f2bf(ldf(W, (kb + i) * HC + cb + tx, fbf));
  __syncthreads();
  for (int i = ty; i < 64; i += 4)
    Wt[(size_t)(cb + i) * K + kb + tx] = tile[i][tx];
}

// block-diagonal time weight, pre-transposed bf16
__global__ void buildwtt_kernel(const int* __restrict__ flags, const void* __restrict__ wt,
                                u16* __restrict__ WTt) {
  bool fbf = flags[1] != 0;
  int col = blockIdx.x, k = threadIdx.x;
  int h = col >> 6, j = col & 63;
  u16 v = 0;
  if ((k >> 6) == h) v = f2bf(ldf(wt, j * HC + k, fbf));
  WTt[(size_t)col * HC + k] = v;
}

// ---------------- qbt[n,h] = q[n,h,:] . bt[h,:] (q bf16) ----------------
__global__ __launch_bounds__(256) void qbt_kernel(
    const int* __restrict__ flags, const u16* __restrict__ q,
    const void* __restrict__ bt, float* __restrict__ qbt) {
  bool fbf = flags[1] != 0;
  int t = threadIdx.x;
  int n = blockIdx.x;
  int h = t >> 6, j = t & 63;
  float pb = bf2f(q[(size_t)n * HC + t]) * ldf(bt, t, fbf);
  for (int off = 32; off; off >>= 1) pb += __shfl_xor(pb, off);
  if (j == 0) qbt[n * 4 + h] = pb;
}

// ---------------- MFMA GEMM: C[M,256](bf16) = A[M,K] @ Wt^T + bias ----------------
template <bool AWS, bool BF32>
__global__ __launch_bounds__(256) void gemm_mfma(
    const int* __restrict__ flags, const void* __restrict__ Ap,
    const u16* __restrict__ Wt, const void* __restrict__ bias,
    u16* __restrict__ C, int M, int K) {
  bool fbf = flags[1] != 0;
  __shared__ u16 As[64][56];
  __shared__ u16 Bs[64][56];
  int tid = threadIdx.x;
  int rb = blockIdx.x * 64, cb = blockIdx.y * 64;
  int wave = tid >> 6, lane = tid & 63;
  int l15 = lane & 15, quad = lane >> 4;

  f32x4 acc[4];
#pragma unroll
  for (int mt = 0; mt < 4; ++mt)
#pragma unroll
    for (int r = 0; r < 4; ++r) acc[mt][r] = 0.f;

  int srow = tid >> 2;
  int skq  = (tid & 3) * 8;

  for (int kk = 0; kk < K; kk += 32) {
    bf16x8 av;
#pragma unroll
    for (int i = 0; i < 8; ++i) av[i] = 0;
    int grow = rb + srow;
    if (grow < M) {
      if constexpr (AWS) {
        av = *(const bf16x8*)((const u16*)Ap + (size_t)grow * K + kk + skq);
      } else {
        if (fbf) {
          av = *(const bf16x8*)((const u16*)Ap + (size_t)grow * K + kk + skq);
        } else {
          const float* A = (const float*)Ap + (size_t)grow * K + kk + skq;
#pragma unroll
          for (int i = 0; i < 8; ++i) av[i] = (short)f2bf(A[i]);
        }
      }
    }
    *(bf16x8*)&As[srow][skq] = av;
    *(bf16x8*)&Bs[srow][skq] =
        *(const bf16x8*)(Wt + (size_t)(cb + srow) * K + kk + skq);
    __syncthreads();

    bf16x8 bfrag = *(const bf16x8*)&Bs[wave * 16 + l15][quad * 8];
#pragma unroll
    for (int mt = 0; mt < 4; ++mt) {
      bf16x8 afrag = *(const bf16x8*)&As[mt * 16 + l15][quad * 8];
      acc[mt] = __builtin_amdgcn_mfma_f32_16x16x32_bf16(afrag, bfrag, acc[mt], 0, 0, 0);
    }
    __syncthreads();
  }

  int gcol = cb + wave * 16 + l15;
  float bv;
  if constexpr (BF32) bv = ((const float*)bias)[gcol];
  else                bv = ldf(bias, gcol, fbf);
#pragma unroll
  for (int mt = 0; mt < 4; ++mt) {
#pragma unroll
    for (int r = 0; r < 4; ++r) {
      int grow = rb + mt * 16 + quad * 4 + r;
      if (grow < M) C[(size_t)grow * HC + gcol] = f2bf(acc[mt][r] + bv);
    }
  }
}

// ---------------- fused alpha + segment softmax + aggregation + relu ---------------
// One wave per node. q/qproj/qbt node-resident in registers; alpha cached in LDS.
// Per-lane op order identical to the former alpha_kernel/aggregate_kernel pair.
__global__ __launch_bounds__(256) void aggfused_kernel(
    const int* __restrict__ flags, const void* __restrict__ eidx,
    const int* __restrict__ esorted, const int* __restrict__ offsets,
    const void* __restrict__ rawt, const void* __restrict__ noise,
    const u16* __restrict__ q, const u16* __restrict__ k,
    const u16* __restrict__ qproj, const float* __restrict__ qbt,
    const float* __restrict__ divt, const u16* __restrict__ v,
    float* __restrict__ aovf, u16* __restrict__ xout) {
  bool is64 = flags[0] != 0, fbf = flags[1] != 0;
  __shared__ float alds[4][CAP][4];
  __shared__ int sds[4][CAP];
  int w = threadIdx.x >> 6;
  int n = blockIdx.x * 4 + w;
  if (n >= NN) return;
  int lane = threadIdx.x & 63;
  int h = lane >> 4;
  int c = lane * 4;
  int s0 = offsets[n], s1 = offsets[n + 1];
  if (s0 < 0) s0 = 0;
  if (s1 > NE) s1 = NE;

  ushort4 q4 = *(const ushort4*)(q + (size_t)n * HC + c);
  ushort4 p4 = *(const ushort4*)(qproj + (size_t)n * HC + c);
  float qx = bf2f(q4.x), qy = bf2f(q4.y), qz = bf2f(q4.z), qw = bf2f(q4.w);
  float px = bf2f(p4.x), py = bf2f(p4.y), pz = bf2f(p4.z), pw = bf2f(p4.w);
  float qb = qbt[n * 4 + h];
  float dv = divt[lane >> 1];
  int base = (lane * 4) & 63;

  // pass 1: alpha per edge (order-identical to alpha_kernel), running max
  float m = -INFINITY;
  for (int p = s0; p < s1; ++p) {
    int e = esorted[p];
    int src = -1;
    float a = 0.f;
    if ((unsigned)e < NE) {
      src = ldsrc(eidx, e, is64);
      if ((unsigned)src >= NN) src = 0;
      float tt = ldf(rawt, e, fbf) + ldf(noise, e, fbf);
      float argl = tt * dv;
      float tel = (lane & 1) ? cosf(argl) : sinf(argl);
      float te0 = __shfl(tel, base);
      float te1 = __shfl(tel, base + 1);
      float te2 = __shfl(tel, base + 2);
      float te3 = __shfl(tel, base + 3);
      ushort4 k4 = *(const ushort4*)(k + (size_t)src * HC + c);
      float s = qx * bf2f(k4.x) + te0 * px;
      s += qy * bf2f(k4.y) + te1 * py;
      s += qz * bf2f(k4.z) + te2 * pz;
      s += qw * bf2f(k4.w) + te3 * pw;
      s += __shfl_xor(s, 1);
      s += __shfl_xor(s, 2);
      s += __shfl_xor(s, 4);
      s += __shfl_xor(s, 8);
      a = (s + qb) * 0.125f;
    }
    m = fmaxf(m, a);
    int idx = p - s0;
    if (idx < CAP) {
      if ((lane & 15) == 0) alds[w][idx][h] = a;
      if (lane == 0) sds[w][idx] = src;
    } else {
      if ((lane & 15) == 0) aovf[(size_t)p * 4 + h] = a;
    }
  }

  // pass 2: softmax + v-weighted accumulation (order-identical to aggregate_kernel)
  float denom = 0.f;
  float acc0 = 0.f, acc1 = 0.f, acc2 = 0.f, acc3 = 0.f;
  for (int p = s0; p < s1; ++p) {
    int idx = p - s0;
    float a;
    int src;
    if (idx < CAP) {
      a = alds[w][idx][h];
      src = sds[w][idx];
    } else {
      a = aovf[(size_t)p * 4 + h];
      int e = esorted[p];
      if ((unsigned)e < NE) {
        src = ldsrc(eidx, e, is64);
        if ((unsigned)src >= NN) src = 0;
      } else src = -1;
    }
    float ea = expf(a - m);
    denom += ea;
    if (src >= 0) {
      ushort4 v4 = *(const ushort4*)(v + (size_t)src * HC + c);
      acc0 += ea * bf2f(v4.x);
      acc1 += ea * bf2f(v4.y);
      acc2 += ea * bf2f(v4.z);
      acc3 += ea * bf2f(v4.w);
    }
  }
  float inv = 1.f / (denom + 1e-16f);
  ushort4 r;
  r.x = f2bf(fmaxf(acc0 * inv, 0.f));
  r.y = f2bf(fmaxf(acc1 * inv, 0.f));
  r.z = f2bf(fmaxf(acc2 * inv, 0.f));
  r.w = f2bf(fmaxf(acc3 * inv, 0.f));
  *(ushort4*)(xout + (size_t)n * HC + c) = r;
}

// ---------------- y[n] = x[n,:] . wc ----------------
__global__ __launch_bounds__(256) void xwc_kernel(
    const int* __restrict__ flags, const u16* __restrict__ x,
    const void* __restrict__ wc, float* __restrict__ y) {
  bool fbf = flags[1] != 0;
  int n = blockIdx.x * 4 + (threadIdx.x >> 6);
  if (n >= NN) return;
  int lane = threadIdx.x & 63;
  int c = lane * 4;
  ushort4 x4 = *(const ushort4*)(x + (size_t)n * HC + c);
  float s = bf2f(x4.x) * ldf(wc, c + 0, fbf);
  s += bf2f(x4.y) * ldf(wc, c + 1, fbf);
  s += bf2f(x4.z) * ldf(wc, c + 2, fbf);
  s += bf2f(x4.w) * ldf(wc, c + 3, fbf);
  for (int off = 32; off; off >>= 1) s += __shfl_xor(s, off);
  if (lane == 0) y[n] = s;
}

// ---------------- out[e] = y[src] + y[dst] + bc ----------------
__global__ __launch_bounds__(256) void final2_kernel(
    const int* __restrict__ flags, const void* __restrict__ eidx,
    const float* __restrict__ y, const void* __restrict__ bc,
    void* __restrict__ out) {
  bool is64 = flags[0] != 0, fbf = flags[1] != 0;
  int e = blockIdx.x * 256 + threadIdx.x;
  if (e >= NE) return;
  int src = ldsrc(eidx, e, is64);
  int dst = lddst(eidx, e, is64);
  if ((unsigned)src >= NN) src = 0;
  if ((unsigned)dst >= NN) dst = 0;
  stout(out, e, y[src] + y[dst] + ldf(bc, 0, fbf), fbf);
}

extern "C" void kernel_launch(void* const* d_in, const int* in_sizes, int n_in,
                              void* d_out, int out_size, void* d_ws, size_t ws_size,
                              hipStream_t stream) {
  const void* eidx  = d_in[0];
  const void* rawt  = d_in[1];
  const void* noise = d_in[2];
  const void* nemb  = d_in[3];
  const void *wq1 = d_in[4],  *bq1 = d_in[5];
  const void *wk1 = d_in[6],  *bk1 = d_in[7];
  const void *wv1 = d_in[8],  *bv1 = d_in[9];
  const void *wt1 = d_in[10], *bt1 = d_in[11];
  const void *wq2 = d_in[12], *bq2 = d_in[13];
  const void *wk2 = d_in[14], *bk2 = d_in[15];
  const void *wv2 = d_in[16], *bv2 = d_in[17];
  const void *wt2 = d_in[18], *bt2 = d_in[19];
  const void *wcp = d_in[20], *bcp = d_in[21];

  char* ws = (char*)d_ws;
  size_t off = 0;
  auto alloc = [&](size_t bytes) -> void* {
    void* p = ws + off;
    off += (bytes + 255) & ~(size_t)255;
    return p;
  };
  int*   flags = (int*)alloc(256);
  float* divt  = (float*)alloc(256);
  float* zbias = (float*)alloc(HC * 4);
  u16*   Wt    = (u16*)alloc((size_t)HC * HC * 2);
  u16*   WTt   = (u16*)alloc((size_t)HC * HC * 2);
  u16*   q     = (u16*)alloc((size_t)NN * HC * 2);
  u16*   k     = (u16*)alloc((size_t)NN * HC * 2);
  u16*   v     = (u16*)alloc((size_t)NN * HC * 2);
  u16*   qproj = (u16*)alloc((size_t)NN * HC * 2);
  float* qbt   = (float*)alloc((size_t)NN * 4 * 4);
  float* ynode = (float*)alloc((size_t)NN * 4);
  int* offsets = (int*)alloc((size_t)(NN + 1) * 4);
  int* cursor  = (int*)alloc((size_t)NN * 4);
  int* bsum    = (int*)alloc(256 * 4);
  int* esorted = (int*)alloc((size_t)NE * 4);
  float* aovf  = (float*)alloc((size_t)NE * 4 * 4);   // alpha overflow (deg > CAP)
  u16* x1 = qproj;
  u16* x2 = q;
  size_t need = off;

  int gN = (NN + 255) / 256, gE = (NE + 255) / 256;
  int nb = (NN + 255) / 256;

  if (ws_size < 1024) {
    raw_sentinel_kernel<<<gE, 256, 0, stream>>>((u16*)d_out);
    return;
  }
  devinit_kernel<<<1, 64, 0, stream>>>(eidx, nemb, flags, divt);
  if (need > ws_size) {
    sentinel_kernel<<<gE, 256, 0, stream>>>(flags, d_out);
    return;
  }

  zero_kernel<<<1, 256, 0, stream>>>((int*)zbias, HC);

  // CSR by dst
  zero_kernel<<<gN, 256, 0, stream>>>(cursor, NN);
  hist_kernel<<<gE, 256, 0, stream>>>(flags, eidx, cursor);
  scan1_kernel<<<nb, 256, 0, stream>>>(cursor, offsets, bsum, NN);
  scan2_kernel<<<1, 256, 0, stream>>>(bsum, offsets, nb, NN);
  scan3_kernel<<<nb, 256, 0, stream>>>(offsets, bsum, NN);
  copy_kernel<<<gN, 256, 0, stream>>>(offsets, cursor, NN);
  fill_kernel<<<gE, 256, 0, stream>>>(flags, eidx, cursor, esorted);

  dim3 gg((NN + 63) / 64, 4);
  dim3 gt1(NIN / 64, 4), gt2(HC / 64, 4);
  int gNode = (NN + 3) / 4;

  // Layer 1 (A = raw node_emb, K=128)
  transw_kernel<<<gt1, 256, 0, stream>>>(flags, wq1, Wt, NIN);
  gemm_mfma<false, false><<<gg, 256, 0, stream>>>(flags, nemb, Wt, bq1, q, NN, NIN);
  transw_kernel<<<gt1, 256, 0, stream>>>(flags, wk1, Wt, NIN);
  gemm_mfma<false, false><<<gg, 256, 0, stream>>>(flags, nemb, Wt, bk1, k, NN, NIN);
  transw_kernel<<<gt1, 256, 0, stream>>>(flags, wv1, Wt, NIN);
  gemm_mfma<false, false><<<gg, 256, 0, stream>>>(flags, nemb, Wt, bv1, v, NN, NIN);
  buildwtt_kernel<<<HC, HC, 0, stream>>>(flags, wt1, WTt);
  gemm_mfma<true, true><<<gg, 256, 0, stream>>>(flags, q, WTt, zbias, qproj, NN, HC);
  qbt_kernel<<<NN, 256, 0, stream>>>(flags, q, bt1, qbt);
  aggfused_kernel<<<gNode, 256, 0, stream>>>(flags, eidx, esorted, offsets, rawt, noise,
                                             q, k, qproj, qbt, divt, v, aovf, x1);

  // Layer 2 (A = bf16 x1, K=256)
  transw_kernel<<<gt2, 256, 0, stream>>>(flags, wq2, Wt, HC);
  gemm_mfma<true, false><<<gg, 256, 0, stream>>>(flags, x1, Wt, bq2, q, NN, HC);
  transw_kernel<<<gt2, 256, 0, stream>>>(flags, wk2, Wt, HC);
  gemm_mfma<true, false><<<gg, 256, 0, stream>>>(flags, x1, Wt, bk2, k, NN, HC);
  transw_kernel<<<gt2, 256, 0, stream>>>(flags, wv2, Wt, HC);
  gemm_mfma<true, false><<<gg, 256, 0, stream>>>(flags, x1, Wt, bv2, v, NN, HC);
  buildwtt_kernel<<<HC, HC, 0, stream>>>(flags, wt2, WTt);
  gemm_mfma<true, true><<<gg, 256, 0, stream>>>(flags, q, WTt, zbias, qproj, NN, HC);
  qbt_kernel<<<NN, 256, 0, stream>>>(flags, q, bt2, qbt);
  aggfused_kernel<<<gNode, 256, 0, stream>>>(flags, eidx, esorted, offsets, rawt, noise,
                                             q, k, qproj, qbt, divt, v, aovf, x2);

  // Edge scorer: y[n] = x2[n].wc, then out[e] = y[src]+y[dst]+bc
  xwc_kernel<<<gNode, 256, 0, stream>>>(flags, x2, wcp, ynode);
  final2_kernel<<<gE, 256, 0, stream>>>(flags, eidx, ynode, bcp, d_out);
}

// Round 9
// 556.866 us; speedup vs baseline: 4.4210x; 1.0324x over previous
//
#include <hip/hip_runtime.h>
#include <hip/hip_fp16.h>
#include <math.h>

// Problem constants
#define NN   20000     // nodes
#define NE   320000    // edges
#define NIN  128       // node input dim
#define HC   256       // heads(4) * hidden(64)
#define CAP  128       // per-wave LDS alpha cache (degree overflow -> global)

typedef unsigned short u16;
typedef __attribute__((ext_vector_type(8))) short bf16x8;
typedef __attribute__((ext_vector_type(4))) float f32x4;

__device__ __forceinline__ float bf2f(u16 u) {
  union { unsigned int i; float f; } x;
  x.i = ((unsigned int)u) << 16;
  return x.f;
}
__device__ __forceinline__ u16 f2bf(float f) {
  union { float f; unsigned int i; } x;
  x.f = f;
  unsigned int r = x.i + 0x7fffu + ((x.i >> 16) & 1u);
  return (u16)(r >> 16);
}

// dtype-flexible loads (flags detected on device each launch)
__device__ __forceinline__ float ldf(const void* p, int i, bool fbf) {
  return fbf ? bf2f(((const u16*)p)[i]) : ((const float*)p)[i];
}
__device__ __forceinline__ int ldsrc(const void* p, int e, bool is64) {
  const int* p32 = (const int*)p;
  return is64 ? p32[2 * e] : p32[e];
}
__device__ __forceinline__ int lddst(const void* p, int e, bool is64) {
  const int* p32 = (const int*)p;
  return is64 ? p32[2 * (NE + e)] : p32[NE + e];
}
__device__ __forceinline__ void stout(void* p, int i, float v, bool fbf) {
  if (fbf) ((u16*)p)[i] = f2bf(v);
  else ((float*)p)[i] = v;
}

// ---------------- detection + div_term init ----------------
__global__ void devinit_kernel(const void* __restrict__ eidx,
                               const void* __restrict__ nemb,
                               int* __restrict__ flags, float* __restrict__ divt) {
  int lane = threadIdx.x;
  if (lane < 32) {
    const float c32 = (float)(-0.14391156831212787);
    float prod = (float)(2 * lane) * c32;
    divt[lane] = (float)exp((double)prod);
  }
  if (lane == 0) {
    const int* p32 = (const int*)eidx;
    int is64 = 1;
    for (int i = 1; i < 128; i += 2)
      if (p32[i] != 0) { is64 = 0; break; }
    const u16* q16 = (const u16*)nemb;
    int fbf = 1;
    for (int i = 0; i < 128; i += 2) {
      unsigned e = (q16[i] >> 7) & 0xFF;
      if (e < 90 || e > 140) { fbf = 0; break; }
    }
    flags[0] = is64;
    flags[1] = fbf;
  }
}

__global__ void sentinel_kernel(const int* __restrict__ flags, void* __restrict__ out) {
  int i = blockIdx.x * 256 + threadIdx.x;
  if (i < NE) stout(out, i, 3000.0f, flags[1] != 0);
}
__global__ void raw_sentinel_kernel(u16* __restrict__ out) {
  int i = blockIdx.x * 256 + threadIdx.x;
  if (i < NE) out[i] = f2bf(3000.0f);
}

// ---------------- CSR build ----------------
__global__ void zero_kernel(int* __restrict__ p, int n) {
  int i = blockIdx.x * 256 + threadIdx.x;
  if (i < n) p[i] = 0;
}

__global__ void hist_kernel(const int* __restrict__ flags, const void* __restrict__ eidx,
                            int* __restrict__ cnt) {
  bool is64 = flags[0] != 0;
  int e = blockIdx.x * 256 + threadIdx.x;
  if (e < NE) {
    int d = lddst(eidx, e, is64);
    if ((unsigned)d < NN) atomicAdd(&cnt[d], 1);
  }
}

// hierarchical scan
__global__ void scan1_kernel(const int* __restrict__ cnt, int* __restrict__ offs,
                             int* __restrict__ bsum, int n) {
  __shared__ int s[256];
  int b = blockIdx.x, t = threadIdx.x, i = b * 256 + t;
  int x = (i < n) ? cnt[i] : 0;
  s[t] = x;
  __syncthreads();
  for (int off = 1; off < 256; off <<= 1) {
    int y = (t >= off) ? s[t - off] : 0;
    __syncthreads();
    s[t] += y;
    __syncthreads();
  }
  if (i < n) offs[i] = s[t] - x;
  if (t == 255) bsum[b] = s[t];
}

__global__ void scan2_kernel(int* __restrict__ bsum, int* __restrict__ offs,
                             int nb, int n) {
  __shared__ int s[256];
  int t = threadIdx.x;
  int x = (t < nb) ? bsum[t] : 0;
  s[t] = x;
  __syncthreads();
  for (int off = 1; off < 256; off <<= 1) {
    int y = (t >= off) ? s[t - off] : 0;
    __syncthreads();
    s[t] += y;
    __syncthreads();
  }
  if (t < nb) bsum[t] = s[t] - x;
  if (t == 255) offs[n] = s[t];
}

__global__ void scan3_kernel(int* __restrict__ offs, const int* __restrict__ bsum, int n) {
  int i = blockIdx.x * 256 + threadIdx.x;
  if (i < n) offs[i] += bsum[blockIdx.x];
}

__global__ void copy_kernel(const int* __restrict__ a, int* __restrict__ b, int n) {
  int i = blockIdx.x * 256 + threadIdx.x;
  if (i < n) b[i] = a[i];
}

// fill: also materialize src (ssrc) and noisy time (stt) in sorted order
__global__ void fill_kernel(const int* __restrict__ flags, const void* __restrict__ eidx,
                            const void* __restrict__ rawt, const void* __restrict__ noise,
                            int* __restrict__ cursor, int* __restrict__ esorted,
                            int* __restrict__ ssrc, float* __restrict__ stt) {
  bool is64 = flags[0] != 0, fbf = flags[1] != 0;
  int e = blockIdx.x * 256 + threadIdx.x;
  if (e < NE) {
    int d = lddst(eidx, e, is64);
    if ((unsigned)d < NN) {
      int pos = atomicAdd(&cursor[d], 1);
      if ((unsigned)pos < NE) {
        esorted[pos] = e;
        int src = ldsrc(eidx, e, is64);
        if ((unsigned)src >= NN) src = 0;
        ssrc[pos] = src;
        stt[pos] = ldf(rawt, e, fbf) + ldf(noise, e, fbf);
      }
    }
  }
}

// ---------------- te_s[p][64] (f16, sorted order) — computed ONCE ----------------
__global__ __launch_bounds__(256) void te_kernel(
    const float* __restrict__ stt, const float* __restrict__ divt,
    u16* __restrict__ te_s) {
  int p = blockIdx.x * 4 + (threadIdx.x >> 6);
  if (p >= NE) return;
  int j = threadIdx.x & 63;
  float tt = stt[p];
  float arg = tt * divt[j >> 1];
  float te = (j & 1) ? cosf(arg) : sinf(arg);
  __half hv = __float2half(te);
  te_s[(size_t)p * 64 + j] = *(u16*)&hv;
}

// ---------------- weight transpose: W[K,256] -> Wt[256][K] bf16 ----------------
__global__ void transw_kernel(const int* __restrict__ flags, const void* __restrict__ W,
                              u16* __restrict__ Wt, int K) {
  bool fbf = flags[1] != 0;
  __shared__ u16 tile[64][65];
  int kb = blockIdx.x * 64, cb = blockIdx.y * 64;
  int tx = threadIdx.x & 63, ty = threadIdx.x >> 6;
  for (int i = ty; i < 64; i += 4)
    tile[tx][i] = f2bf(ldf(W, (kb + i) * HC + cb + tx, fbf));
  __syncthreads();
  for (int i = ty; i < 64; i += 4)
    Wt[(size_t)(cb + i) * K + kb + tx] = tile[i][tx];
}

// block-diagonal time weight, pre-transposed bf16
__global__ void buildwtt_kernel(const int* __restrict__ flags, const void* __restrict__ wt,
                                u16* __restrict__ WTt) {
  bool fbf = flags[1] != 0;
  int col = blockIdx.x, k = threadIdx.x;
  int h = col >> 6, j = col & 63;
  u16 v = 0;
  if ((k >> 6) == h) v = f2bf(ldf(wt, j * HC + k, fbf));
  WTt[(size_t)col * HC + k] = v;
}

// ---------------- qbt[n,h] = q[n,h,:] . bt[h,:] (q bf16) ----------------
__global__ __launch_bounds__(256) void qbt_kernel(
    const int* __restrict__ flags, const u16* __restrict__ q,
    const void* __restrict__ bt, float* __restrict__ qbt) {
  bool fbf = flags[1] != 0;
  int t = threadIdx.x;
  int n = blockIdx.x;
  int h = t >> 6, j = t & 63;
  float pb = bf2f(q[(size_t)n * HC + t]) * ldf(bt, t, fbf);
  for (int off = 32; off; off >>= 1) pb += __shfl_xor(pb, off);
  if (j == 0) qbt[n * 4 + h] = pb;
}

// ---------------- MFMA GEMM: C[M,256](bf16) = A[M,K] @ Wt^T + bias ----------------
template <bool AWS, bool BF32>
__global__ __launch_bounds__(256) void gemm_mfma(
    const int* __restrict__ flags, const void* __restrict__ Ap,
    const u16* __restrict__ Wt, const void* __restrict__ bias,
    u16* __restrict__ C, int M, int K) {
  bool fbf = flags[1] != 0;
  __shared__ u16 As[64][56];
  __shared__ u16 Bs[64][56];
  int tid = threadIdx.x;
  int rb = blockIdx.x * 64, cb = blockIdx.y * 64;
  int wave = tid >> 6, lane = tid & 63;
  int l15 = lane & 15, quad = lane >> 4;

  f32x4 acc[4];
#pragma unroll
  for (int mt = 0; mt < 4; ++mt)
#pragma unroll
    for (int r = 0; r < 4; ++r) acc[mt][r] = 0.f;

  int srow = tid >> 2;
  int skq  = (tid & 3) * 8;

  for (int kk = 0; kk < K; kk += 32) {
    bf16x8 av;
#pragma unroll
    for (int i = 0; i < 8; ++i) av[i] = 0;
    int grow = rb + srow;
    if (grow < M) {
      if constexpr (AWS) {
        av = *(const bf16x8*)((const u16*)Ap + (size_t)grow * K + kk + skq);
      } else {
        if (fbf) {
          av = *(const bf16x8*)((const u16*)Ap + (size_t)grow * K + kk + skq);
        } else {
          const float* A = (const float*)Ap + (size_t)grow * K + kk + skq;
#pragma unroll
          for (int i = 0; i < 8; ++i) av[i] = (short)f2bf(A[i]);
        }
      }
    }
    *(bf16x8*)&As[srow][skq] = av;
    *(bf16x8*)&Bs[srow][skq] =
        *(const bf16x8*)(Wt + (size_t)(cb + srow) * K + kk + skq);
    __syncthreads();

    bf16x8 bfrag = *(const bf16x8*)&Bs[wave * 16 + l15][quad * 8];
#pragma unroll
    for (int mt = 0; mt < 4; ++mt) {
      bf16x8 afrag = *(const bf16x8*)&As[mt * 16 + l15][quad * 8];
      acc[mt] = __builtin_amdgcn_mfma_f32_16x16x32_bf16(afrag, bfrag, acc[mt], 0, 0, 0);
    }
    __syncthreads();
  }

  int gcol = cb + wave * 16 + l15;
  float bv;
  if constexpr (BF32) bv = ((const float*)bias)[gcol];
  else                bv = ldf(bias, gcol, fbf);
#pragma unroll
  for (int mt = 0; mt < 4; ++mt) {
#pragma unroll
    for (int r = 0; r < 4; ++r) {
      int grow = rb + mt * 16 + quad * 4 + r;
      if (grow < M) C[(size_t)grow * HC + gcol] = f2bf(acc[mt][r] + bv);
    }
  }
}

// ---------------- fused alpha + segment softmax + aggregation + relu ---------------
// One wave per node. q/qproj/qbt node-resident in registers; te precomputed (f16,
// sorted order); src pre-flattened (ssrc). alpha cached in LDS (CAP), overflow->global.
__global__ __launch_bounds__(256) void aggfused_kernel(
    const int* __restrict__ flags, const int* __restrict__ ssrc,
    const int* __restrict__ offsets, const u16* __restrict__ te_s,
    const u16* __restrict__ q, const u16* __restrict__ k,
    const u16* __restrict__ qproj, const float* __restrict__ qbt,
    const u16* __restrict__ v, float* __restrict__ aovf,
    u16* __restrict__ xout) {
  __shared__ float alds[4][CAP][4];
  __shared__ int sds[4][CAP];
  int w = threadIdx.x >> 6;
  int n = blockIdx.x * 4 + w;
  if (n >= NN) return;
  int lane = threadIdx.x & 63;
  int h = lane >> 4;
  int c = lane * 4;
  int s0 = offsets[n], s1 = offsets[n + 1];
  if (s0 < 0) s0 = 0;
  if (s1 > NE) s1 = NE;

  ushort4 q4 = *(const ushort4*)(q + (size_t)n * HC + c);
  ushort4 p4 = *(const ushort4*)(qproj + (size_t)n * HC + c);
  float qx = bf2f(q4.x), qy = bf2f(q4.y), qz = bf2f(q4.z), qw = bf2f(q4.w);
  float px = bf2f(p4.x), py = bf2f(p4.y), pz = bf2f(p4.z), pw = bf2f(p4.w);
  float qb = qbt[n * 4 + h];
  int jb = c & 63;   // te channel base for this lane

  // pass 1: alpha per edge, running max
  float m = -INFINITY;
  for (int p = s0; p < s1; ++p) {
    int src = ssrc[p];
    float a = 0.f;
    if ((unsigned)src < NN) {
      ushort4 t4 = *(const ushort4*)(te_s + (size_t)p * 64 + jb);
      float te0 = __half2float(*(__half*)&t4.x);
      float te1 = __half2float(*(__half*)&t4.y);
      float te2 = __half2float(*(__half*)&t4.z);
      float te3 = __half2float(*(__half*)&t4.w);
      ushort4 k4 = *(const ushort4*)(k + (size_t)src * HC + c);
      float s = qx * bf2f(k4.x) + te0 * px;
      s += qy * bf2f(k4.y) + te1 * py;
      s += qz * bf2f(k4.z) + te2 * pz;
      s += qw * bf2f(k4.w) + te3 * pw;
      s += __shfl_xor(s, 1);
      s += __shfl_xor(s, 2);
      s += __shfl_xor(s, 4);
      s += __shfl_xor(s, 8);
      a = (s + qb) * 0.125f;
    } else src = -1;
    m = fmaxf(m, a);
    int idx = p - s0;
    if (idx < CAP) {
      if ((lane & 15) == 0) alds[w][idx][h] = a;
      if (lane == 0) sds[w][idx] = src;
    } else {
      if ((lane & 15) == 0) aovf[(size_t)p * 4 + h] = a;
    }
  }

  // pass 2: softmax + v-weighted accumulation
  float denom = 0.f;
  float acc0 = 0.f, acc1 = 0.f, acc2 = 0.f, acc3 = 0.f;
  for (int p = s0; p < s1; ++p) {
    int idx = p - s0;
    float a;
    int src;
    if (idx < CAP) {
      a = alds[w][idx][h];
      src = sds[w][idx];
    } else {
      a = aovf[(size_t)p * 4 + h];
      src = ssrc[p];
      if ((unsigned)src >= NN) src = -1;
    }
    float ea = expf(a - m);
    denom += ea;
    if (src >= 0) {
      ushort4 v4 = *(const ushort4*)(v + (size_t)src * HC + c);
      acc0 += ea * bf2f(v4.x);
      acc1 += ea * bf2f(v4.y);
      acc2 += ea * bf2f(v4.z);
      acc3 += ea * bf2f(v4.w);
    }
  }
  float inv = 1.f / (denom + 1e-16f);
  ushort4 r;
  r.x = f2bf(fmaxf(acc0 * inv, 0.f));
  r.y = f2bf(fmaxf(acc1 * inv, 0.f));
  r.z = f2bf(fmaxf(acc2 * inv, 0.f));
  r.w = f2bf(fmaxf(acc3 * inv, 0.f));
  *(ushort4*)(xout + (size_t)n * HC + c) = r;
}

// ---------------- y[n] = x[n,:] . wc ----------------
__global__ __launch_bounds__(256) void xwc_kernel(
    const int* __restrict__ flags, const u16* __restrict__ x,
    const void* __restrict__ wc, float* __restrict__ y) {
  bool fbf = flags[1] != 0;
  int n = blockIdx.x * 4 + (threadIdx.x >> 6);
  if (n >= NN) return;
  int lane = threadIdx.x & 63;
  int c = lane * 4;
  ushort4 x4 = *(const ushort4*)(x + (size_t)n * HC + c);
  float s = bf2f(x4.x) * ldf(wc, c + 0, fbf);
  s += bf2f(x4.y) * ldf(wc, c + 1, fbf);
  s += bf2f(x4.z) * ldf(wc, c + 2, fbf);
  s += bf2f(x4.w) * ldf(wc, c + 3, fbf);
  for (int off = 32; off; off >>= 1) s += __shfl_xor(s, off);
  if (lane == 0) y[n] = s;
}

// ---------------- out[e] = y[src] + y[dst] + bc ----------------
__global__ __launch_bounds__(256) void final2_kernel(
    const int* __restrict__ flags, const void* __restrict__ eidx,
    const float* __restrict__ y, const void* __restrict__ bc,
    void* __restrict__ out) {
  bool is64 = flags[0] != 0, fbf = flags[1] != 0;
  int e = blockIdx.x * 256 + threadIdx.x;
  if (e >= NE) return;
  int src = ldsrc(eidx, e, is64);
  int dst = lddst(eidx, e, is64);
  if ((unsigned)src >= NN) src = 0;
  if ((unsigned)dst >= NN) dst = 0;
  stout(out, e, y[src] + y[dst] + ldf(bc, 0, fbf), fbf);
}

extern "C" void kernel_launch(void* const* d_in, const int* in_sizes, int n_in,
                              void* d_out, int out_size, void* d_ws, size_t ws_size,
                              hipStream_t stream) {
  const void* eidx  = d_in[0];
  const void* rawt  = d_in[1];
  const void* noise = d_in[2];
  const void* nemb  = d_in[3];
  const void *wq1 = d_in[4],  *bq1 = d_in[5];
  const void *wk1 = d_in[6],  *bk1 = d_in[7];
  const void *wv1 = d_in[8],  *bv1 = d_in[9];
  const void *wt1 = d_in[10], *bt1 = d_in[11];
  const void *wq2 = d_in[12], *bq2 = d_in[13];
  const void *wk2 = d_in[14], *bk2 = d_in[15];
  const void *wv2 = d_in[16], *bv2 = d_in[17];
  const void *wt2 = d_in[18], *bt2 = d_in[19];
  const void *wcp = d_in[20], *bcp = d_in[21];

  char* ws = (char*)d_ws;
  size_t off = 0;
  auto alloc = [&](size_t bytes) -> void* {
    void* p = ws + off;
    off += (bytes + 255) & ~(size_t)255;
    return p;
  };
  int*   flags = (int*)alloc(256);
  float* divt  = (float*)alloc(256);
  float* zbias = (float*)alloc(HC * 4);
  u16*   Wt    = (u16*)alloc((size_t)HC * HC * 2);
  u16*   WTt   = (u16*)alloc((size_t)HC * HC * 2);
  u16*   q     = (u16*)alloc((size_t)NN * HC * 2);
  u16*   k     = (u16*)alloc((size_t)NN * HC * 2);
  u16*   v     = (u16*)alloc((size_t)NN * HC * 2);
  u16*   qproj = (u16*)alloc((size_t)NN * HC * 2);
  float* qbt   = (float*)alloc((size_t)NN * 4 * 4);
  float* ynode = (float*)alloc((size_t)NN * 4);
  int* offsets = (int*)alloc((size_t)(NN + 1) * 4);
  int* cursor  = (int*)alloc((size_t)NN * 4);
  int* bsum    = (int*)alloc(256 * 4);
  int* esorted = (int*)alloc((size_t)NE * 4);
  int* ssrc    = (int*)alloc((size_t)NE * 4);
  float* stt   = (float*)alloc((size_t)NE * 4);
  u16* te_s    = (u16*)alloc((size_t)NE * 64 * 2);   // 41 MB, f16 sorted time enc
  float* aovf  = (float*)alloc((size_t)NE * 4 * 4);  // alpha overflow (deg > CAP)
  u16* x1 = qproj;
  u16* x2 = q;
  size_t need = off;

  int gN = (NN + 255) / 256, gE = (NE + 255) / 256;
  int nb = (NN + 255) / 256;

  if (ws_size < 1024) {
    raw_sentinel_kernel<<<gE, 256, 0, stream>>>((u16*)d_out);
    return;
  }
  devinit_kernel<<<1, 64, 0, stream>>>(eidx, nemb, flags, divt);
  if (need > ws_size) {
    sentinel_kernel<<<gE, 256, 0, stream>>>(flags, d_out);
    return;
  }

  zero_kernel<<<1, 256, 0, stream>>>((int*)zbias, HC);

  // CSR by dst (+ sorted src / time)
  zero_kernel<<<gN, 256, 0, stream>>>(cursor, NN);
  hist_kernel<<<gE, 256, 0, stream>>>(flags, eidx, cursor);
  scan1_kernel<<<nb, 256, 0, stream>>>(cursor, offsets, bsum, NN);
  scan2_kernel<<<1, 256, 0, stream>>>(bsum, offsets, nb, NN);
  scan3_kernel<<<nb, 256, 0, stream>>>(offsets, bsum, NN);
  copy_kernel<<<gN, 256, 0, stream>>>(offsets, cursor, NN);
  fill_kernel<<<gE, 256, 0, stream>>>(flags, eidx, rawt, noise, cursor, esorted, ssrc, stt);

  int gEdge4 = (NE + 3) / 4;
  te_kernel<<<gEdge4, 256, 0, stream>>>(stt, divt, te_s);   // once for both layers

  dim3 gg((NN + 63) / 64, 4);
  dim3 gt1(NIN / 64, 4), gt2(HC / 64, 4);
  int gNode = (NN + 3) / 4;

  // Layer 1 (A = raw node_emb, K=128)
  transw_kernel<<<gt1, 256, 0, stream>>>(flags, wq1, Wt, NIN);
  gemm_mfma<false, false><<<gg, 256, 0, stream>>>(flags, nemb, Wt, bq1, q, NN, NIN);
  transw_kernel<<<gt1, 256, 0, stream>>>(flags, wk1, Wt, NIN);
  gemm_mfma<false, false><<<gg, 256, 0, stream>>>(flags, nemb, Wt, bk1, k, NN, NIN);
  transw_kernel<<<gt1, 256, 0, stream>>>(flags, wv1, Wt, NIN);
  gemm_mfma<false, false><<<gg, 256, 0, stream>>>(flags, nemb, Wt, bv1, v, NN, NIN);
  buildwtt_kernel<<<HC, HC, 0, stream>>>(flags, wt1, WTt);
  gemm_mfma<true, true><<<gg, 256, 0, stream>>>(flags, q, WTt, zbias, qproj, NN, HC);
  qbt_kernel<<<NN, 256, 0, stream>>>(flags, q, bt1, qbt);
  aggfused_kernel<<<gNode, 256, 0, stream>>>(flags, ssrc, offsets, te_s,
                                             q, k, qproj, qbt, v, aovf, x1);

  // Layer 2 (A = bf16 x1, K=256)
  transw_kernel<<<gt2, 256, 0, stream>>>(flags, wq2, Wt, HC);
  gemm_mfma<true, false><<<gg, 256, 0, stream>>>(flags, x1, Wt, bq2, q, NN, HC);
  transw_kernel<<<gt2, 256, 0, stream>>>(flags, wk2, Wt, HC);
  gemm_mfma<true, false><<<gg, 256, 0, stream>>>(flags, x1, Wt, bk2, k, NN, HC);
  transw_kernel<<<gt2, 256, 0, stream>>>(flags, wv2, Wt, HC);
  gemm_mfma<true, false><<<gg, 256, 0, stream>>>(flags, x1, Wt, bv2, v, NN, HC);
  buildwtt_kernel<<<HC, HC, 0, stream>>>(flags, wt2, WTt);
  gemm_mfma<true, true><<<gg, 256, 0, stream>>>(flags, q, WTt, zbias, qproj, NN, HC);
  qbt_kernel<<<NN, 256, 0, stream>>>(flags, q, bt2, qbt);
  aggfused_kernel<<<gNode, 256, 0, stream>>>(flags, ssrc, offsets, te_s,
                                             q, k, qproj, qbt, v, aovf, x2);

  // Edge scorer: y[n] = x2[n].wc, then out[e] = y[src]+y[dst]+bc
  xwc_kernel<<<gNode, 256, 0, stream>>>(flags, x2, wcp, ynode);
  final2_kernel<<<gE, 256, 0, stream>>>(flags, eidx, ynode, bcp, d_out);
}

// Round 10
// 515.690 us; speedup vs baseline: 4.7740x; 1.0798x over previous
//
#include <hip/hip_runtime.h>
#include <hip/hip_fp16.h>
#include <math.h>

// Problem constants
#define NN   20000     // nodes
#define NE   320000    // edges
#define NIN  128       // node input dim
#define HC   256       // heads(4) * hidden(64)

typedef unsigned short u16;
typedef __attribute__((ext_vector_type(8))) short bf16x8;
typedef __attribute__((ext_vector_type(4))) float f32x4;

__device__ __forceinline__ float bf2f(u16 u) {
  union { unsigned int i; float f; } x;
  x.i = ((unsigned int)u) << 16;
  return x.f;
}
__device__ __forceinline__ u16 f2bf(float f) {
  union { float f; unsigned int i; } x;
  x.f = f;
  unsigned int r = x.i + 0x7fffu + ((x.i >> 16) & 1u);
  return (u16)(r >> 16);
}

// dtype-flexible loads (flags detected on device each launch)
__device__ __forceinline__ float ldf(const void* p, int i, bool fbf) {
  return fbf ? bf2f(((const u16*)p)[i]) : ((const float*)p)[i];
}
__device__ __forceinline__ int ldsrc(const void* p, int e, bool is64) {
  const int* p32 = (const int*)p;
  return is64 ? p32[2 * e] : p32[e];
}
__device__ __forceinline__ int lddst(const void* p, int e, bool is64) {
  const int* p32 = (const int*)p;
  return is64 ? p32[2 * (NE + e)] : p32[NE + e];
}
__device__ __forceinline__ void stout(void* p, int i, float v, bool fbf) {
  if (fbf) ((u16*)p)[i] = f2bf(v);
  else ((float*)p)[i] = v;
}

// ---------------- detection + div_term init ----------------
__global__ void devinit_kernel(const void* __restrict__ eidx,
                               const void* __restrict__ nemb,
                               int* __restrict__ flags, float* __restrict__ divt) {
  int lane = threadIdx.x;
  if (lane < 32) {
    const float c32 = (float)(-0.14391156831212787);
    float prod = (float)(2 * lane) * c32;
    divt[lane] = (float)exp((double)prod);
  }
  if (lane == 0) {
    const int* p32 = (const int*)eidx;
    int is64 = 1;
    for (int i = 1; i < 128; i += 2)
      if (p32[i] != 0) { is64 = 0; break; }
    const u16* q16 = (const u16*)nemb;
    int fbf = 1;
    for (int i = 0; i < 128; i += 2) {
      unsigned e = (q16[i] >> 7) & 0xFF;
      if (e < 90 || e > 140) { fbf = 0; break; }
    }
    flags[0] = is64;
    flags[1] = fbf;
  }
}

__global__ void sentinel_kernel(const int* __restrict__ flags, void* __restrict__ out) {
  int i = blockIdx.x * 256 + threadIdx.x;
  if (i < NE) stout(out, i, 3000.0f, flags[1] != 0);
}
__global__ void raw_sentinel_kernel(u16* __restrict__ out) {
  int i = blockIdx.x * 256 + threadIdx.x;
  if (i < NE) out[i] = f2bf(3000.0f);
}

// ---------------- CSR build ----------------
__global__ void zero_kernel(int* __restrict__ p, int n) {
  int i = blockIdx.x * 256 + threadIdx.x;
  if (i < n) p[i] = 0;
}

__global__ void hist_kernel(const int* __restrict__ flags, const void* __restrict__ eidx,
                            int* __restrict__ cnt) {
  bool is64 = flags[0] != 0;
  int e = blockIdx.x * 256 + threadIdx.x;
  if (e < NE) {
    int d = lddst(eidx, e, is64);
    if ((unsigned)d < NN) atomicAdd(&cnt[d], 1);
  }
}

// hierarchical scan
__global__ void scan1_kernel(const int* __restrict__ cnt, int* __restrict__ offs,
                             int* __restrict__ bsum, int n) {
  __shared__ int s[256];
  int b = blockIdx.x, t = threadIdx.x, i = b * 256 + t;
  int x = (i < n) ? cnt[i] : 0;
  s[t] = x;
  __syncthreads();
  for (int off = 1; off < 256; off <<= 1) {
    int y = (t >= off) ? s[t - off] : 0;
    __syncthreads();
    s[t] += y;
    __syncthreads();
  }
  if (i < n) offs[i] = s[t] - x;
  if (t == 255) bsum[b] = s[t];
}

__global__ void scan2_kernel(int* __restrict__ bsum, int* __restrict__ offs,
                             int nb, int n) {
  __shared__ int s[256];
  int t = threadIdx.x;
  int x = (t < nb) ? bsum[t] : 0;
  s[t] = x;
  __syncthreads();
  for (int off = 1; off < 256; off <<= 1) {
    int y = (t >= off) ? s[t - off] : 0;
    __syncthreads();
    s[t] += y;
    __syncthreads();
  }
  if (t < nb) bsum[t] = s[t] - x;
  if (t == 255) offs[n] = s[t];
}

__global__ void scan3_kernel(int* __restrict__ offs, const int* __restrict__ bsum, int n) {
  int i = blockIdx.x * 256 + threadIdx.x;
  if (i < n) offs[i] += bsum[blockIdx.x];
}

__global__ void copy_kernel(const int* __restrict__ a, int* __restrict__ b, int n) {
  int i = blockIdx.x * 256 + threadIdx.x;
  if (i < n) b[i] = a[i];
}

// fill: also materialize src (ssrc) and noisy time (stt) in sorted order
__global__ void fill_kernel(const int* __restrict__ flags, const void* __restrict__ eidx,
                            const void* __restrict__ rawt, const void* __restrict__ noise,
                            int* __restrict__ cursor, int* __restrict__ esorted,
                            int* __restrict__ ssrc, float* __restrict__ stt) {
  bool is64 = flags[0] != 0, fbf = flags[1] != 0;
  int e = blockIdx.x * 256 + threadIdx.x;
  if (e < NE) {
    int d = lddst(eidx, e, is64);
    if ((unsigned)d < NN) {
      int pos = atomicAdd(&cursor[d], 1);
      if ((unsigned)pos < NE) {
        esorted[pos] = e;
        int src = ldsrc(eidx, e, is64);
        if ((unsigned)src >= NN) src = 0;
        ssrc[pos] = src;
        stt[pos] = ldf(rawt, e, fbf) + ldf(noise, e, fbf);
      }
    }
  }
}

// ---------------- te_s[p][64] (f16, sorted order) — computed ONCE ----------------
__global__ __launch_bounds__(256) void te_kernel(
    const float* __restrict__ stt, const float* __restrict__ divt,
    u16* __restrict__ te_s) {
  int p = blockIdx.x * 4 + (threadIdx.x >> 6);
  if (p >= NE) return;
  int j = threadIdx.x & 63;
  float tt = stt[p];
  float arg = tt * divt[j >> 1];
  float te = (j & 1) ? cosf(arg) : sinf(arg);
  __half hv = __float2half(te);
  te_s[(size_t)p * 64 + j] = *(u16*)&hv;
}

// ---------------- weight transpose: W[K,256] -> Wt[256][K] bf16 ----------------
__global__ void transw_kernel(const int* __restrict__ flags, const void* __restrict__ W,
                              u16* __restrict__ Wt, int K) {
  bool fbf = flags[1] != 0;
  __shared__ u16 tile[64][65];
  int kb = blockIdx.x * 64, cb = blockIdx.y * 64;
  int tx = threadIdx.x & 63, ty = threadIdx.x >> 6;
  for (int i = ty; i < 64; i += 4)
    tile[tx][i] = f2bf(ldf(W, (kb + i) * HC + cb + tx, fbf));
  __syncthreads();
  for (int i = ty; i < 64; i += 4)
    Wt[(size_t)(cb + i) * K + kb + tx] = tile[i][tx];
}

// block-diagonal time weight, pre-transposed bf16
__global__ void buildwtt_kernel(const int* __restrict__ flags, const void* __restrict__ wt,
                                u16* __restrict__ WTt) {
  bool fbf = flags[1] != 0;
  int col = blockIdx.x, k = threadIdx.x;
  int h = col >> 6, j = col & 63;
  u16 v = 0;
  if ((k >> 6) == h) v = f2bf(ldf(wt, j * HC + k, fbf));
  WTt[(size_t)col * HC + k] = v;
}

// ---------------- qbt[n,h] = q[n,h,:] . bt[h,:] (q bf16) ----------------
__global__ __launch_bounds__(256) void qbt_kernel(
    const int* __restrict__ flags, const u16* __restrict__ q,
    const void* __restrict__ bt, float* __restrict__ qbt) {
  bool fbf = flags[1] != 0;
  int t = threadIdx.x;
  int n = blockIdx.x;
  int h = t >> 6, j = t & 63;
  float pb = bf2f(q[(size_t)n * HC + t]) * ldf(bt, t, fbf);
  for (int off = 32; off; off >>= 1) pb += __shfl_xor(pb, off);
  if (j == 0) qbt[n * 4 + h] = pb;
}

// ---------------- MFMA GEMM: C[M,256](bf16) = A[M,K] @ Wt^T + bias ----------------
template <bool AWS, bool BF32>
__global__ __launch_bounds__(256) void gemm_mfma(
    const int* __restrict__ flags, const void* __restrict__ Ap,
    const u16* __restrict__ Wt, const void* __restrict__ bias,
    u16* __restrict__ C, int M, int K) {
  bool fbf = flags[1] != 0;
  __shared__ u16 As[64][56];
  __shared__ u16 Bs[64][56];
  int tid = threadIdx.x;
  int rb = blockIdx.x * 64, cb = blockIdx.y * 64;
  int wave = tid >> 6, lane = tid & 63;
  int l15 = lane & 15, quad = lane >> 4;

  f32x4 acc[4];
#pragma unroll
  for (int mt = 0; mt < 4; ++mt)
#pragma unroll
    for (int r = 0; r < 4; ++r) acc[mt][r] = 0.f;

  int srow = tid >> 2;
  int skq  = (tid & 3) * 8;

  for (int kk = 0; kk < K; kk += 32) {
    bf16x8 av;
#pragma unroll
    for (int i = 0; i < 8; ++i) av[i] = 0;
    int grow = rb + srow;
    if (grow < M) {
      if constexpr (AWS) {
        av = *(const bf16x8*)((const u16*)Ap + (size_t)grow * K + kk + skq);
      } else {
        if (fbf) {
          av = *(const bf16x8*)((const u16*)Ap + (size_t)grow * K + kk + skq);
        } else {
          const float* A = (const float*)Ap + (size_t)grow * K + kk + skq;
#pragma unroll
          for (int i = 0; i < 8; ++i) av[i] = (short)f2bf(A[i]);
        }
      }
    }
    *(bf16x8*)&As[srow][skq] = av;
    *(bf16x8*)&Bs[srow][skq] =
        *(const bf16x8*)(Wt + (size_t)(cb + srow) * K + kk + skq);
    __syncthreads();

    bf16x8 bfrag = *(const bf16x8*)&Bs[wave * 16 + l15][quad * 8];
#pragma unroll
    for (int mt = 0; mt < 4; ++mt) {
      bf16x8 afrag = *(const bf16x8*)&As[mt * 16 + l15][quad * 8];
      acc[mt] = __builtin_amdgcn_mfma_f32_16x16x32_bf16(afrag, bfrag, acc[mt], 0, 0, 0);
    }
    __syncthreads();
  }

  int gcol = cb + wave * 16 + l15;
  float bv;
  if constexpr (BF32) bv = ((const float*)bias)[gcol];
  else                bv = ldf(bias, gcol, fbf);
#pragma unroll
  for (int mt = 0; mt < 4; ++mt) {
#pragma unroll
    for (int r = 0; r < 4; ++r) {
      int grow = rb + mt * 16 + quad * 4 + r;
      if (grow < M) C[(size_t)grow * HC + gcol] = f2bf(acc[mt][r] + bv);
    }
  }
}

// ---------------- fused alpha + ONLINE segment softmax + aggregation + relu --------
// One wave per node, SINGLE pass over the node's edges: running (m, denom, acc)
// with rescale-on-new-max. k[src] and v[src] gathers issue back-to-back per edge.
__global__ __launch_bounds__(256) void aggfused_kernel(
    const int* __restrict__ flags, const int* __restrict__ ssrc,
    const int* __restrict__ offsets, const u16* __restrict__ te_s,
    const u16* __restrict__ q, const u16* __restrict__ k,
    const u16* __restrict__ qproj, const float* __restrict__ qbt,
    const u16* __restrict__ v, u16* __restrict__ xout) {
  int w = threadIdx.x >> 6;
  int n = blockIdx.x * 4 + w;
  if (n >= NN) return;
  int lane = threadIdx.x & 63;
  int h = lane >> 4;
  int c = lane * 4;
  int s0 = offsets[n], s1 = offsets[n + 1];
  if (s0 < 0) s0 = 0;
  if (s1 > NE) s1 = NE;

  ushort4 q4 = *(const ushort4*)(q + (size_t)n * HC + c);
  ushort4 p4 = *(const ushort4*)(qproj + (size_t)n * HC + c);
  float qx = bf2f(q4.x), qy = bf2f(q4.y), qz = bf2f(q4.z), qw = bf2f(q4.w);
  float px = bf2f(p4.x), py = bf2f(p4.y), pz = bf2f(p4.z), pw = bf2f(p4.w);
  float qb = qbt[n * 4 + h];
  int jb = c & 63;   // te channel base for this lane

  float m = -INFINITY, denom = 0.f;
  float acc0 = 0.f, acc1 = 0.f, acc2 = 0.f, acc3 = 0.f;
  for (int p = s0; p < s1; ++p) {
    int src = ssrc[p];
    bool ok = (unsigned)src < NN;
    if (!ok) src = 0;
    // issue both gathers + te load up-front (independent addresses)
    ushort4 k4 = *(const ushort4*)(k + (size_t)src * HC + c);
    ushort4 v4 = *(const ushort4*)(v + (size_t)src * HC + c);
    ushort4 t4 = *(const ushort4*)(te_s + (size_t)p * 64 + jb);
    float a = 0.f;
    if (ok) {
      float te0 = __half2float(*(__half*)&t4.x);
      float te1 = __half2float(*(__half*)&t4.y);
      float te2 = __half2float(*(__half*)&t4.z);
      float te3 = __half2float(*(__half*)&t4.w);
      float s = qx * bf2f(k4.x) + te0 * px;
      s += qy * bf2f(k4.y) + te1 * py;
      s += qz * bf2f(k4.z) + te2 * pz;
      s += qw * bf2f(k4.w) + te3 * pw;
      s += __shfl_xor(s, 1);
      s += __shfl_xor(s, 2);
      s += __shfl_xor(s, 4);
      s += __shfl_xor(s, 8);
      a = (s + qb) * 0.125f;
    }
    if (a > m) {                       // rescale running state to new max
      float sc = expf(m - a);          // exp(-inf)=0 on first edge
      denom *= sc;
      acc0 *= sc; acc1 *= sc; acc2 *= sc; acc3 *= sc;
      m = a;
    }
    float ea = expf(a - m);
    denom += ea;
    if (ok) {
      acc0 += ea * bf2f(v4.x);
      acc1 += ea * bf2f(v4.y);
      acc2 += ea * bf2f(v4.z);
      acc3 += ea * bf2f(v4.w);
    }
  }
  float inv = 1.f / (denom + 1e-16f);
  ushort4 r;
  r.x = f2bf(fmaxf(acc0 * inv, 0.f));
  r.y = f2bf(fmaxf(acc1 * inv, 0.f));
  r.z = f2bf(fmaxf(acc2 * inv, 0.f));
  r.w = f2bf(fmaxf(acc3 * inv, 0.f));
  *(ushort4*)(xout + (size_t)n * HC + c) = r;
}

// ---------------- y[n] = x[n,:] . wc ----------------
__global__ __launch_bounds__(256) void xwc_kernel(
    const int* __restrict__ flags, const u16* __restrict__ x,
    const void* __restrict__ wc, float* __restrict__ y) {
  bool fbf = flags[1] != 0;
  int n = blockIdx.x * 4 + (threadIdx.x >> 6);
  if (n >= NN) return;
  int lane = threadIdx.x & 63;
  int c = lane * 4;
  ushort4 x4 = *(const ushort4*)(x + (size_t)n * HC + c);
  float s = bf2f(x4.x) * ldf(wc, c + 0, fbf);
  s += bf2f(x4.y) * ldf(wc, c + 1, fbf);
  s += bf2f(x4.z) * ldf(wc, c + 2, fbf);
  s += bf2f(x4.w) * ldf(wc, c + 3, fbf);
  for (int off = 32; off; off >>= 1) s += __shfl_xor(s, off);
  if (lane == 0) y[n] = s;
}

// ---------------- out[e] = y[src] + y[dst] + bc ----------------
__global__ __launch_bounds__(256) void final2_kernel(
    const int* __restrict__ flags, const void* __restrict__ eidx,
    const float* __restrict__ y, const void* __restrict__ bc,
    void* __restrict__ out) {
  bool is64 = flags[0] != 0, fbf = flags[1] != 0;
  int e = blockIdx.x * 256 + threadIdx.x;
  if (e >= NE) return;
  int src = ldsrc(eidx, e, is64);
  int dst = lddst(eidx, e, is64);
  if ((unsigned)src >= NN) src = 0;
  if ((unsigned)dst >= NN) dst = 0;
  stout(out, e, y[src] + y[dst] + ldf(bc, 0, fbf), fbf);
}

extern "C" void kernel_launch(void* const* d_in, const int* in_sizes, int n_in,
                              void* d_out, int out_size, void* d_ws, size_t ws_size,
                              hipStream_t stream) {
  const void* eidx  = d_in[0];
  const void* rawt  = d_in[1];
  const void* noise = d_in[2];
  const void* nemb  = d_in[3];
  const void *wq1 = d_in[4],  *bq1 = d_in[5];
  const void *wk1 = d_in[6],  *bk1 = d_in[7];
  const void *wv1 = d_in[8],  *bv1 = d_in[9];
  const void *wt1 = d_in[10], *bt1 = d_in[11];
  const void *wq2 = d_in[12], *bq2 = d_in[13];
  const void *wk2 = d_in[14], *bk2 = d_in[15];
  const void *wv2 = d_in[16], *bv2 = d_in[17];
  const void *wt2 = d_in[18], *bt2 = d_in[19];
  const void *wcp = d_in[20], *bcp = d_in[21];

  char* ws = (char*)d_ws;
  size_t off = 0;
  auto alloc = [&](size_t bytes) -> void* {
    void* p = ws + off;
    off += (bytes + 255) & ~(size_t)255;
    return p;
  };
  int*   flags = (int*)alloc(256);
  float* divt  = (float*)alloc(256);
  float* zbias = (float*)alloc(HC * 4);
  u16*   Wt    = (u16*)alloc((size_t)HC * HC * 2);
  u16*   WTt   = (u16*)alloc((size_t)HC * HC * 2);
  u16*   q     = (u16*)alloc((size_t)NN * HC * 2);
  u16*   k     = (u16*)alloc((size_t)NN * HC * 2);
  u16*   v     = (u16*)alloc((size_t)NN * HC * 2);
  u16*   qproj = (u16*)alloc((size_t)NN * HC * 2);
  float* qbt   = (float*)alloc((size_t)NN * 4 * 4);
  float* ynode = (float*)alloc((size_t)NN * 4);
  int* offsets = (int*)alloc((size_t)(NN + 1) * 4);
  int* cursor  = (int*)alloc((size_t)NN * 4);
  int* bsum    = (int*)alloc(256 * 4);
  int* esorted = (int*)alloc((size_t)NE * 4);
  int* ssrc    = (int*)alloc((size_t)NE * 4);
  float* stt   = (float*)alloc((size_t)NE * 4);
  u16* te_s    = (u16*)alloc((size_t)NE * 64 * 2);   // 41 MB, f16 sorted time enc
  u16* x1 = qproj;
  u16* x2 = q;
  size_t need = off;

  int gN = (NN + 255) / 256, gE = (NE + 255) / 256;
  int nb = (NN + 255) / 256;

  if (ws_size < 1024) {
    raw_sentinel_kernel<<<gE, 256, 0, stream>>>((u16*)d_out);
    return;
  }
  devinit_kernel<<<1, 64, 0, stream>>>(eidx, nemb, flags, divt);
  if (need > ws_size) {
    sentinel_kernel<<<gE, 256, 0, stream>>>(flags, d_out);
    return;
  }

  zero_kernel<<<1, 256, 0, stream>>>((int*)zbias, HC);

  // CSR by dst (+ sorted src / time)
  zero_kernel<<<gN, 256, 0, stream>>>(cursor, NN);
  hist_kernel<<<gE, 256, 0, stream>>>(flags, eidx, cursor);
  scan1_kernel<<<nb, 256, 0, stream>>>(cursor, offsets, bsum, NN);
  scan2_kernel<<<1, 256, 0, stream>>>(bsum, offsets, nb, NN);
  scan3_kernel<<<nb, 256, 0, stream>>>(offsets, bsum, NN);
  copy_kernel<<<gN, 256, 0, stream>>>(offsets, cursor, NN);
  fill_kernel<<<gE, 256, 0, stream>>>(flags, eidx, rawt, noise, cursor, esorted, ssrc, stt);

  int gEdge4 = (NE + 3) / 4;
  te_kernel<<<gEdge4, 256, 0, stream>>>(stt, divt, te_s);   // once for both layers

  dim3 gg((NN + 63) / 64, 4);
  dim3 gt1(NIN / 64, 4), gt2(HC / 64, 4);
  int gNode = (NN + 3) / 4;

  // Layer 1 (A = raw node_emb, K=128)
  transw_kernel<<<gt1, 256, 0, stream>>>(flags, wq1, Wt, NIN);
  gemm_mfma<false, false><<<gg, 256, 0, stream>>>(flags, nemb, Wt, bq1, q, NN, NIN);
  transw_kernel<<<gt1, 256, 0, stream>>>(flags, wk1, Wt, NIN);
  gemm_mfma<false, false><<<gg, 256, 0, stream>>>(flags, nemb, Wt, bk1, k, NN, NIN);
  transw_kernel<<<gt1, 256, 0, stream>>>(flags, wv1, Wt, NIN);
  gemm_mfma<false, false><<<gg, 256, 0, stream>>>(flags, nemb, Wt, bv1, v, NN, NIN);
  buildwtt_kernel<<<HC, HC, 0, stream>>>(flags, wt1, WTt);
  gemm_mfma<true, true><<<gg, 256, 0, stream>>>(flags, q, WTt, zbias, qproj, NN, HC);
  qbt_kernel<<<NN, 256, 0, stream>>>(flags, q, bt1, qbt);
  aggfused_kernel<<<gNode, 256, 0, stream>>>(flags, ssrc, offsets, te_s,
                                             q, k, qproj, qbt, v, x1);

  // Layer 2 (A = bf16 x1, K=256)
  transw_kernel<<<gt2, 256, 0, stream>>>(flags, wq2, Wt, HC);
  gemm_mfma<true, false><<<gg, 256, 0, stream>>>(flags, x1, Wt, bq2, q, NN, HC);
  transw_kernel<<<gt2, 256, 0, stream>>>(flags, wk2, Wt, HC);
  gemm_mfma<true, false><<<gg, 256, 0, stream>>>(flags, x1, Wt, bk2, k, NN, HC);
  transw_kernel<<<gt2, 256, 0, stream>>>(flags, wv2, Wt, HC);
  gemm_mfma<true, false><<<gg, 256, 0, stream>>>(flags, x1, Wt, bv2, v, NN, HC);
  buildwtt_kernel<<<HC, HC, 0, stream>>>(flags, wt2, WTt);
  gemm_mfma<true, true><<<gg, 256, 0, stream>>>(flags, q, WTt, zbias, qproj, NN, HC);
  qbt_kernel<<<NN, 256, 0, stream>>>(flags, q, bt2, qbt);
  aggfused_kernel<<<gNode, 256, 0, stream>>>(flags, ssrc, offsets, te_s,
                                             q, k, qproj, qbt, v, x2);

  // Edge scorer: y[n] = x2[n].wc, then out[e] = y[src]+y[dst]+bc
  xwc_kernel<<<gNode, 256, 0, stream>>>(flags, x2, wcp, ynode);
  final2_kernel<<<gE, 256, 0, stream>>>(flags, eidx, ynode, bcp, d_out);
}

// Round 11
// 501.325 us; speedup vs baseline: 4.9108x; 1.0287x over previous
//
#include <hip/hip_runtime.h>
#include <hip/hip_fp16.h>
#include <math.h>

// Problem constants
#define NN   20000     // nodes
#define NE   320000    // edges
#define NIN  128       // node input dim
#define HC   256       // heads(4) * hidden(64)
#define NB   1024      // fused GEMM output width: [q|k|v|qproj]

typedef unsigned short u16;
typedef __attribute__((ext_vector_type(8))) short bf16x8;
typedef __attribute__((ext_vector_type(4))) float f32x4;

__device__ __forceinline__ float bf2f(u16 u) {
  union { unsigned int i; float f; } x;
  x.i = ((unsigned int)u) << 16;
  return x.f;
}
__device__ __forceinline__ u16 f2bf(float f) {
  union { float f; unsigned int i; } x;
  x.f = f;
  unsigned int r = x.i + 0x7fffu + ((x.i >> 16) & 1u);
  return (u16)(r >> 16);
}

// dtype-flexible loads (flags detected on device each launch)
__device__ __forceinline__ float ldf(const void* p, int i, bool fbf) {
  return fbf ? bf2f(((const u16*)p)[i]) : ((const float*)p)[i];
}
__device__ __forceinline__ int ldsrc(const void* p, int e, bool is64) {
  const int* p32 = (const int*)p;
  return is64 ? p32[2 * e] : p32[e];
}
__device__ __forceinline__ int lddst(const void* p, int e, bool is64) {
  const int* p32 = (const int*)p;
  return is64 ? p32[2 * (NE + e)] : p32[NE + e];
}
__device__ __forceinline__ void stout(void* p, int i, float v, bool fbf) {
  if (fbf) ((u16*)p)[i] = f2bf(v);
  else ((float*)p)[i] = v;
}

// ---------------- detection + div_term init ----------------
__global__ void devinit_kernel(const void* __restrict__ eidx,
                               const void* __restrict__ nemb,
                               int* __restrict__ flags, float* __restrict__ divt) {
  int lane = threadIdx.x;
  if (lane < 32) {
    const float c32 = (float)(-0.14391156831212787);
    float prod = (float)(2 * lane) * c32;
    divt[lane] = (float)exp((double)prod);
  }
  if (lane == 0) {
    const int* p32 = (const int*)eidx;
    int is64 = 1;
    for (int i = 1; i < 128; i += 2)
      if (p32[i] != 0) { is64 = 0; break; }
    const u16* q16 = (const u16*)nemb;
    int fbf = 1;
    for (int i = 0; i < 128; i += 2) {
      unsigned e = (q16[i] >> 7) & 0xFF;
      if (e < 90 || e > 140) { fbf = 0; break; }
    }
    flags[0] = is64;
    flags[1] = fbf;
  }
}

__global__ void sentinel_kernel(const int* __restrict__ flags, void* __restrict__ out) {
  int i = blockIdx.x * 256 + threadIdx.x;
  if (i < NE) stout(out, i, 3000.0f, flags[1] != 0);
}
__global__ void raw_sentinel_kernel(u16* __restrict__ out) {
  int i = blockIdx.x * 256 + threadIdx.x;
  if (i < NE) out[i] = f2bf(3000.0f);
}

// ---------------- CSR build ----------------
__global__ void zero_kernel(int* __restrict__ p, int n) {
  int i = blockIdx.x * 256 + threadIdx.x;
  if (i < n) p[i] = 0;
}

__global__ void hist_kernel(const int* __restrict__ flags, const void* __restrict__ eidx,
                            int* __restrict__ cnt) {
  bool is64 = flags[0] != 0;
  int e = blockIdx.x * 256 + threadIdx.x;
  if (e < NE) {
    int d = lddst(eidx, e, is64);
    if ((unsigned)d < NN) atomicAdd(&cnt[d], 1);
  }
}

// hierarchical scan
__global__ void scan1_kernel(const int* __restrict__ cnt, int* __restrict__ offs,
                             int* __restrict__ bsum, int n) {
  __shared__ int s[256];
  int b = blockIdx.x, t = threadIdx.x, i = b * 256 + t;
  int x = (i < n) ? cnt[i] : 0;
  s[t] = x;
  __syncthreads();
  for (int off = 1; off < 256; off <<= 1) {
    int y = (t >= off) ? s[t - off] : 0;
    __syncthreads();
    s[t] += y;
    __syncthreads();
  }
  if (i < n) offs[i] = s[t] - x;
  if (t == 255) bsum[b] = s[t];
}

__global__ void scan2_kernel(int* __restrict__ bsum, int* __restrict__ offs,
                             int nb, int n) {
  __shared__ int s[256];
  int t = threadIdx.x;
  int x = (t < nb) ? bsum[t] : 0;
  s[t] = x;
  __syncthreads();
  for (int off = 1; off < 256; off <<= 1) {
    int y = (t >= off) ? s[t - off] : 0;
    __syncthreads();
    s[t] += y;
    __syncthreads();
  }
  if (t < nb) bsum[t] = s[t] - x;
  if (t == 255) offs[n] = s[t];
}

__global__ void scan3_kernel(int* __restrict__ offs, const int* __restrict__ bsum, int n) {
  int i = blockIdx.x * 256 + threadIdx.x;
  if (i < n) offs[i] += bsum[blockIdx.x];
}

__global__ void copy_kernel(const int* __restrict__ a, int* __restrict__ b, int n) {
  int i = blockIdx.x * 256 + threadIdx.x;
  if (i < n) b[i] = a[i];
}

// fill: also materialize src (ssrc) and noisy time (stt) in sorted order
__global__ void fill_kernel(const int* __restrict__ flags, const void* __restrict__ eidx,
                            const void* __restrict__ rawt, const void* __restrict__ noise,
                            int* __restrict__ cursor, int* __restrict__ esorted,
                            int* __restrict__ ssrc, float* __restrict__ stt) {
  bool is64 = flags[0] != 0, fbf = flags[1] != 0;
  int e = blockIdx.x * 256 + threadIdx.x;
  if (e < NE) {
    int d = lddst(eidx, e, is64);
    if ((unsigned)d < NN) {
      int pos = atomicAdd(&cursor[d], 1);
      if ((unsigned)pos < NE) {
        esorted[pos] = e;
        int src = ldsrc(eidx, e, is64);
        if ((unsigned)src >= NN) src = 0;
        ssrc[pos] = src;
        stt[pos] = ldf(rawt, e, fbf) + ldf(noise, e, fbf);
      }
    }
  }
}

// ---------------- te_s[p][64] (f16, sorted order) — computed ONCE ----------------
__global__ __launch_bounds__(256) void te_kernel(
    const float* __restrict__ stt, const float* __restrict__ divt,
    u16* __restrict__ te_s) {
  int p = blockIdx.x * 4 + (threadIdx.x >> 6);
  if (p >= NE) return;
  int j = threadIdx.x & 63;
  float tt = stt[p];
  float arg = tt * divt[j >> 1];
  float te = (j & 1) ? cosf(arg) : sinf(arg);
  __half hv = __float2half(te);
  te_s[(size_t)p * 64 + j] = *(u16*)&hv;
}

// ---------------- weight transpose: W[K,256] -> dst[256][K] bf16 ----------------
__global__ void transw_kernel(const int* __restrict__ flags, const void* __restrict__ W,
                              u16* __restrict__ dst, int K) {
  bool fbf = flags[1] != 0;
  __shared__ u16 tile[64][65];
  int kb = blockIdx.x * 64, cb = blockIdx.y * 64;
  int tx = threadIdx.x & 63, ty = threadIdx.x >> 6;
  for (int i = ty; i < 64; i += 4)
    tile[tx][i] = f2bf(ldf(W, (kb + i) * HC + cb + tx, fbf));
  __syncthreads();
  for (int i = ty; i < 64; i += 4)
    dst[(size_t)(cb + i) * K + kb + tx] = tile[i][tx];
}

// ---------------- Wcomb rows: Wout[j][c] = sum_mm wt[j&63][h*64+mm] * Wqt[h*64+mm][c]
// Wqt = transposed wq (rows 0..255 of WtBig). Wout = WtBig + 768*K.
__global__ void wcomb_kernel(const int* __restrict__ flags, const void* __restrict__ wt,
                             const u16* __restrict__ Wqt, u16* __restrict__ Wout, int K) {
  bool fbf = flags[1] != 0;
  __shared__ float wrow[64];
  int j = blockIdx.x;         // 0..255 (output col within qproj block)
  int h = j >> 6;
  int c = threadIdx.x;        // 0..K-1
  if (threadIdx.x < 64)
    wrow[threadIdx.x] = ldf(wt, (j & 63) * HC + h * 64 + threadIdx.x, fbf);
  __syncthreads();
  float s = 0.f;
#pragma unroll 8
  for (int mm = 0; mm < 64; ++mm)
    s += wrow[mm] * bf2f(Wqt[(size_t)(h * 64 + mm) * K + c]);
  Wout[(size_t)j * K + c] = f2bf(s);
}

// ---------------- biasBig = [bq|bk|bv|bcomb], bcomb[j] = sum_mm bq[.]*wt[.] --------
__global__ void biasbig_kernel(const int* __restrict__ flags, const void* __restrict__ bq,
                               const void* __restrict__ bk, const void* __restrict__ bv,
                               const void* __restrict__ wt, float* __restrict__ biasBig) {
  bool fbf = flags[1] != 0;
  int b = blockIdx.x, t = threadIdx.x;
  if (b < 3) {
    const void* p = (b == 0) ? bq : (b == 1) ? bk : bv;
    biasBig[b * 256 + t] = ldf(p, t, fbf);
  } else {
    int j = t, h = j >> 6;
    float s = 0.f;
    for (int mm = 0; mm < 64; ++mm)
      s += ldf(bq, h * 64 + mm, fbf) * ldf(wt, (j & 63) * HC + h * 64 + mm, fbf);
    biasBig[768 + j] = s;
  }
}

// ---------------- qbt[n,h] = q[n,h,:] . bt[h,:] (q from qkvp, stride NB) ----------
__global__ __launch_bounds__(256) void qbt_kernel(
    const int* __restrict__ flags, const u16* __restrict__ qkvp,
    const void* __restrict__ bt, float* __restrict__ qbt) {
  bool fbf = flags[1] != 0;
  int t = threadIdx.x;
  int n = blockIdx.x;
  int h = t >> 6, j = t & 63;
  float pb = bf2f(qkvp[(size_t)n * NB + t]) * ldf(bt, t, fbf);
  for (int off = 32; off; off >>= 1) pb += __shfl_xor(pb, off);
  if (j == 0) qbt[n * 4 + h] = pb;
}

// ---------------- fused MFMA GEMM: C[M,1024](bf16) = A[M,K] @ WtBig^T + biasBig ----
// AWS: A is bf16 ws (u16); else raw input per flag.
template <bool AWS>
__global__ __launch_bounds__(256) void gemm_mfma(
    const int* __restrict__ flags, const void* __restrict__ Ap,
    const u16* __restrict__ Wt, const float* __restrict__ bias,
    u16* __restrict__ C, int M, int K) {
  bool fbf = flags[1] != 0;
  __shared__ u16 As[64][56];
  __shared__ u16 Bs[64][56];
  int tid = threadIdx.x;
  int rb = blockIdx.x * 64, cb = blockIdx.y * 64;
  int wave = tid >> 6, lane = tid & 63;
  int l15 = lane & 15, quad = lane >> 4;

  f32x4 acc[4];
#pragma unroll
  for (int mt = 0; mt < 4; ++mt)
#pragma unroll
    for (int r = 0; r < 4; ++r) acc[mt][r] = 0.f;

  int srow = tid >> 2;
  int skq  = (tid & 3) * 8;

  for (int kk = 0; kk < K; kk += 32) {
    bf16x8 av;
#pragma unroll
    for (int i = 0; i < 8; ++i) av[i] = 0;
    int grow = rb + srow;
    if (grow < M) {
      if constexpr (AWS) {
        av = *(const bf16x8*)((const u16*)Ap + (size_t)grow * K + kk + skq);
      } else {
        if (fbf) {
          av = *(const bf16x8*)((const u16*)Ap + (size_t)grow * K + kk + skq);
        } else {
          const float* A = (const float*)Ap + (size_t)grow * K + kk + skq;
#pragma unroll
          for (int i = 0; i < 8; ++i) av[i] = (short)f2bf(A[i]);
        }
      }
    }
    *(bf16x8*)&As[srow][skq] = av;
    *(bf16x8*)&Bs[srow][skq] =
        *(const bf16x8*)(Wt + (size_t)(cb + srow) * K + kk + skq);
    __syncthreads();

    bf16x8 bfrag = *(const bf16x8*)&Bs[wave * 16 + l15][quad * 8];
#pragma unroll
    for (int mt = 0; mt < 4; ++mt) {
      bf16x8 afrag = *(const bf16x8*)&As[mt * 16 + l15][quad * 8];
      acc[mt] = __builtin_amdgcn_mfma_f32_16x16x32_bf16(afrag, bfrag, acc[mt], 0, 0, 0);
    }
    __syncthreads();
  }

  int gcol = cb + wave * 16 + l15;
  float bv = bias[gcol];
#pragma unroll
  for (int mt = 0; mt < 4; ++mt) {
#pragma unroll
    for (int r = 0; r < 4; ++r) {
      int grow = rb + mt * 16 + quad * 4 + r;
      if (grow < M) C[(size_t)grow * NB + gcol] = f2bf(acc[mt][r] + bv);
    }
  }
}

// ---------------- fused alpha + ONLINE segment softmax + aggregation + relu --------
// One wave per node, single pass. q/k/v/qproj all live in qkvp rows (stride NB).
__global__ __launch_bounds__(256) void aggfused_kernel(
    const int* __restrict__ flags, const int* __restrict__ ssrc,
    const int* __restrict__ offsets, const u16* __restrict__ te_s,
    const u16* __restrict__ qkvp, const float* __restrict__ qbt,
    u16* __restrict__ xout) {
  int w = threadIdx.x >> 6;
  int n = blockIdx.x * 4 + w;
  if (n >= NN) return;
  int lane = threadIdx.x & 63;
  int h = lane >> 4;
  int c = lane * 4;
  int s0 = offsets[n], s1 = offsets[n + 1];
  if (s0 < 0) s0 = 0;
  if (s1 > NE) s1 = NE;

  ushort4 q4 = *(const ushort4*)(qkvp + (size_t)n * NB + c);
  ushort4 p4 = *(const ushort4*)(qkvp + (size_t)n * NB + 768 + c);
  float qx = bf2f(q4.x), qy = bf2f(q4.y), qz = bf2f(q4.z), qw = bf2f(q4.w);
  float px = bf2f(p4.x), py = bf2f(p4.y), pz = bf2f(p4.z), pw = bf2f(p4.w);
  float qb = qbt[n * 4 + h];
  int jb = c & 63;   // te channel base for this lane

  float m = -INFINITY, denom = 0.f;
  float acc0 = 0.f, acc1 = 0.f, acc2 = 0.f, acc3 = 0.f;
  for (int p = s0; p < s1; ++p) {
    int src = ssrc[p];
    bool ok = (unsigned)src < NN;
    if (!ok) src = 0;
    const u16* row = qkvp + (size_t)src * NB;
    ushort4 k4 = *(const ushort4*)(row + 256 + c);
    ushort4 v4 = *(const ushort4*)(row + 512 + c);
    ushort4 t4 = *(const ushort4*)(te_s + (size_t)p * 64 + jb);
    float a = 0.f;
    if (ok) {
      float te0 = __half2float(*(__half*)&t4.x);
      float te1 = __half2float(*(__half*)&t4.y);
      float te2 = __half2float(*(__half*)&t4.z);
      float te3 = __half2float(*(__half*)&t4.w);
      float s = qx * bf2f(k4.x) + te0 * px;
      s += qy * bf2f(k4.y) + te1 * py;
      s += qz * bf2f(k4.z) + te2 * pz;
      s += qw * bf2f(k4.w) + te3 * pw;
      s += __shfl_xor(s, 1);
      s += __shfl_xor(s, 2);
      s += __shfl_xor(s, 4);
      s += __shfl_xor(s, 8);
      a = (s + qb) * 0.125f;
    }
    if (a > m) {
      float sc = expf(m - a);          // exp(-inf)=0 on first edge
      denom *= sc;
      acc0 *= sc; acc1 *= sc; acc2 *= sc; acc3 *= sc;
      m = a;
    }
    float ea = expf(a - m);
    denom += ea;
    if (ok) {
      acc0 += ea * bf2f(v4.x);
      acc1 += ea * bf2f(v4.y);
      acc2 += ea * bf2f(v4.z);
      acc3 += ea * bf2f(v4.w);
    }
  }
  float inv = 1.f / (denom + 1e-16f);
  ushort4 r;
  r.x = f2bf(fmaxf(acc0 * inv, 0.f));
  r.y = f2bf(fmaxf(acc1 * inv, 0.f));
  r.z = f2bf(fmaxf(acc2 * inv, 0.f));
  r.w = f2bf(fmaxf(acc3 * inv, 0.f));
  *(ushort4*)(xout + (size_t)n * HC + c) = r;
}

// ---------------- y[n] = x[n,:] . wc ----------------
__global__ __launch_bounds__(256) void xwc_kernel(
    const int* __restrict__ flags, const u16* __restrict__ x,
    const void* __restrict__ wc, float* __restrict__ y) {
  bool fbf = flags[1] != 0;
  int n = blockIdx.x * 4 + (threadIdx.x >> 6);
  if (n >= NN) return;
  int lane = threadIdx.x & 63;
  int c = lane * 4;
  ushort4 x4 = *(const ushort4*)(x + (size_t)n * HC + c);
  float s = bf2f(x4.x) * ldf(wc, c + 0, fbf);
  s += bf2f(x4.y) * ldf(wc, c + 1, fbf);
  s += bf2f(x4.z) * ldf(wc, c + 2, fbf);
  s += bf2f(x4.w) * ldf(wc, c + 3, fbf);
  for (int off = 32; off; off >>= 1) s += __shfl_xor(s, off);
  if (lane == 0) y[n] = s;
}

// ---------------- out[e] = y[src] + y[dst] + bc ----------------
__global__ __launch_bounds__(256) void final2_kernel(
    const int* __restrict__ flags, const void* __restrict__ eidx,
    const float* __restrict__ y, const void* __restrict__ bc,
    void* __restrict__ out) {
  bool is64 = flags[0] != 0, fbf = flags[1] != 0;
  int e = blockIdx.x * 256 + threadIdx.x;
  if (e >= NE) return;
  int src = ldsrc(eidx, e, is64);
  int dst = lddst(eidx, e, is64);
  if ((unsigned)src >= NN) src = 0;
  if ((unsigned)dst >= NN) dst = 0;
  stout(out, e, y[src] + y[dst] + ldf(bc, 0, fbf), fbf);
}

extern "C" void kernel_launch(void* const* d_in, const int* in_sizes, int n_in,
                              void* d_out, int out_size, void* d_ws, size_t ws_size,
                              hipStream_t stream) {
  const void* eidx  = d_in[0];
  const void* rawt  = d_in[1];
  const void* noise = d_in[2];
  const void* nemb  = d_in[3];
  const void *wq1 = d_in[4],  *bq1 = d_in[5];
  const void *wk1 = d_in[6],  *bk1 = d_in[7];
  const void *wv1 = d_in[8],  *bv1 = d_in[9];
  const void *wt1 = d_in[10], *bt1 = d_in[11];
  const void *wq2 = d_in[12], *bq2 = d_in[13];
  const void *wk2 = d_in[14], *bk2 = d_in[15];
  const void *wv2 = d_in[16], *bv2 = d_in[17];
  const void *wt2 = d_in[18], *bt2 = d_in[19];
  const void *wcp = d_in[20], *bcp = d_in[21];

  char* ws = (char*)d_ws;
  size_t off = 0;
  auto alloc = [&](size_t bytes) -> void* {
    void* p = ws + off;
    off += (bytes + 255) & ~(size_t)255;
    return p;
  };
  int*   flags  = (int*)alloc(256);
  float* divt   = (float*)alloc(256);
  u16*   WtBig  = (u16*)alloc((size_t)NB * HC * 2);     // [1024][K<=256] bf16
  float* biasBig= (float*)alloc((size_t)NB * 4);
  u16*   qkvp   = (u16*)alloc((size_t)NN * NB * 2);     // 41 MB [q|k|v|qproj]
  u16*   x1     = (u16*)alloc((size_t)NN * HC * 2);
  u16*   x2     = (u16*)alloc((size_t)NN * HC * 2);
  float* qbt    = (float*)alloc((size_t)NN * 4 * 4);
  float* ynode  = (float*)alloc((size_t)NN * 4);
  int* offsets  = (int*)alloc((size_t)(NN + 1) * 4);
  int* cursor   = (int*)alloc((size_t)NN * 4);
  int* bsum     = (int*)alloc(256 * 4);
  int* esorted  = (int*)alloc((size_t)NE * 4);
  int* ssrc     = (int*)alloc((size_t)NE * 4);
  float* stt    = (float*)alloc((size_t)NE * 4);
  u16* te_s     = (u16*)alloc((size_t)NE * 64 * 2);     // 41 MB, f16 sorted time enc
  size_t need = off;

  int gN = (NN + 255) / 256, gE = (NE + 255) / 256;
  int nb = (NN + 255) / 256;

  if (ws_size < 1024) {
    raw_sentinel_kernel<<<gE, 256, 0, stream>>>((u16*)d_out);
    return;
  }
  devinit_kernel<<<1, 64, 0, stream>>>(eidx, nemb, flags, divt);
  if (need > ws_size) {
    sentinel_kernel<<<gE, 256, 0, stream>>>(flags, d_out);
    return;
  }

  // CSR by dst (+ sorted src / time)
  zero_kernel<<<gN, 256, 0, stream>>>(cursor, NN);
  hist_kernel<<<gE, 256, 0, stream>>>(flags, eidx, cursor);
  scan1_kernel<<<nb, 256, 0, stream>>>(cursor, offsets, bsum, NN);
  scan2_kernel<<<1, 256, 0, stream>>>(bsum, offsets, nb, NN);
  scan3_kernel<<<nb, 256, 0, stream>>>(offsets, bsum, NN);
  copy_kernel<<<gN, 256, 0, stream>>>(offsets, cursor, NN);
  fill_kernel<<<gE, 256, 0, stream>>>(flags, eidx, rawt, noise, cursor, esorted, ssrc, stt);

  int gEdge4 = (NE + 3) / 4;
  te_kernel<<<gEdge4, 256, 0, stream>>>(stt, divt, te_s);   // once for both layers

  dim3 ggemm((NN + 63) / 64, NB / 64);   // 313 x 16
  dim3 gt1(NIN / 64, 4), gt2(HC / 64, 4);
  int gNode = (NN + 3) / 4;

  // ---- Layer 1 (A = raw node_emb, K=128) ----
  transw_kernel<<<gt1, 256, 0, stream>>>(flags, wq1, WtBig + 0 * NIN, NIN);
  transw_kernel<<<gt1, 256, 0, stream>>>(flags, wk1, WtBig + (size_t)256 * NIN, NIN);
  transw_kernel<<<gt1, 256, 0, stream>>>(flags, wv1, WtBig + (size_t)512 * NIN, NIN);
  wcomb_kernel<<<256, NIN, 0, stream>>>(flags, wt1, WtBig, WtBig + (size_t)768 * NIN, NIN);
  biasbig_kernel<<<4, 256, 0, stream>>>(flags, bq1, bk1, bv1, wt1, biasBig);
  gemm_mfma<false><<<ggemm, 256, 0, stream>>>(flags, nemb, WtBig, biasBig, qkvp, NN, NIN);
  qbt_kernel<<<NN, 256, 0, stream>>>(flags, qkvp, bt1, qbt);
  aggfused_kernel<<<gNode, 256, 0, stream>>>(flags, ssrc, offsets, te_s, qkvp, qbt, x1);

  // ---- Layer 2 (A = bf16 x1, K=256) ----
  transw_kernel<<<gt2, 256, 0, stream>>>(flags, wq2, WtBig + 0 * HC, HC);
  transw_kernel<<<gt2, 256, 0, stream>>>(flags, wk2, WtBig + (size_t)256 * HC, HC);
  transw_kernel<<<gt2, 256, 0, stream>>>(flags, wv2, WtBig + (size_t)512 * HC, HC);
  wcomb_kernel<<<256, HC, 0, stream>>>(flags, wt2, WtBig, WtBig + (size_t)768 * HC, HC);
  biasbig_kernel<<<4, 256, 0, stream>>>(flags, bq2, bk2, bv2, wt2, biasBig);
  gemm_mfma<true><<<ggemm, 256, 0, stream>>>(flags, x1, WtBig, biasBig, qkvp, NN, HC);
  qbt_kernel<<<NN, 256, 0, stream>>>(flags, qkvp, bt2, qbt);
  aggfused_kernel<<<gNode, 256, 0, stream>>>(flags, ssrc, offsets, te_s, qkvp, qbt, x2);

  // Edge scorer: y[n] = x2[n].wc, then out[e] = y[src]+y[dst]+bc
  xwc_kernel<<<gNode, 256, 0, stream>>>(flags, x2, wcp, ynode);
  final2_kernel<<<gE, 256, 0, stream>>>(flags, eidx, ynode, bcp, d_out);
}

// Round 12
// 475.968 us; speedup vs baseline: 5.1724x; 1.0533x over previous
//
#include <hip/hip_runtime.h>
#include <hip/hip_fp16.h>
#include <math.h>

// Problem constants
#define NN   20000     // nodes
#define NE   320000    // edges
#define NIN  128       // node input dim
#define HC   256       // heads(4) * hidden(64)
#define NB   1024      // fused GEMM output width: [q|k|v|qproj]

typedef unsigned short u16;
typedef __attribute__((ext_vector_type(8))) short bf16x8;
typedef __attribute__((ext_vector_type(4))) float f32x4;

__device__ __forceinline__ float bf2f(u16 u) {
  union { unsigned int i; float f; } x;
  x.i = ((unsigned int)u) << 16;
  return x.f;
}
__device__ __forceinline__ u16 f2bf(float f) {
  union { float f; unsigned int i; } x;
  x.f = f;
  unsigned int r = x.i + 0x7fffu + ((x.i >> 16) & 1u);
  return (u16)(r >> 16);
}

// dtype-flexible loads (flags detected on device each launch)
__device__ __forceinline__ float ldf(const void* p, int i, bool fbf) {
  return fbf ? bf2f(((const u16*)p)[i]) : ((const float*)p)[i];
}
__device__ __forceinline__ int ldsrc(const void* p, int e, bool is64) {
  const int* p32 = (const int*)p;
  return is64 ? p32[2 * e] : p32[e];
}
__device__ __forceinline__ int lddst(const void* p, int e, bool is64) {
  const int* p32 = (const int*)p;
  return is64 ? p32[2 * (NE + e)] : p32[NE + e];
}
__device__ __forceinline__ void stout(void* p, int i, float v, bool fbf) {
  if (fbf) ((u16*)p)[i] = f2bf(v);
  else ((float*)p)[i] = v;
}

// ---------------- detection + div_term init ----------------
__global__ void devinit_kernel(const void* __restrict__ eidx,
                               const void* __restrict__ nemb,
                               int* __restrict__ flags, float* __restrict__ divt) {
  int lane = threadIdx.x;
  if (lane < 32) {
    const float c32 = (float)(-0.14391156831212787);
    float prod = (float)(2 * lane) * c32;
    divt[lane] = (float)exp((double)prod);
  }
  if (lane == 0) {
    const int* p32 = (const int*)eidx;
    int is64 = 1;
    for (int i = 1; i < 128; i += 2)
      if (p32[i] != 0) { is64 = 0; break; }
    const u16* q16 = (const u16*)nemb;
    int fbf = 1;
    for (int i = 0; i < 128; i += 2) {
      unsigned e = (q16[i] >> 7) & 0xFF;
      if (e < 90 || e > 140) { fbf = 0; break; }
    }
    flags[0] = is64;
    flags[1] = fbf;
  }
}

__global__ void sentinel_kernel(const int* __restrict__ flags, void* __restrict__ out) {
  int i = blockIdx.x * 256 + threadIdx.x;
  if (i < NE) stout(out, i, 3000.0f, flags[1] != 0);
}
__global__ void raw_sentinel_kernel(u16* __restrict__ out) {
  int i = blockIdx.x * 256 + threadIdx.x;
  if (i < NE) out[i] = f2bf(3000.0f);
}

// ---------------- CSR build ----------------
__global__ void zero_kernel(int* __restrict__ p, int n) {
  int i = blockIdx.x * 256 + threadIdx.x;
  if (i < n) p[i] = 0;
}

__global__ void hist_kernel(const int* __restrict__ flags, const void* __restrict__ eidx,
                            int* __restrict__ cnt) {
  bool is64 = flags[0] != 0;
  int e = blockIdx.x * 256 + threadIdx.x;
  if (e < NE) {
    int d = lddst(eidx, e, is64);
    if ((unsigned)d < NN) atomicAdd(&cnt[d], 1);
  }
}

// hierarchical scan
__global__ void scan1_kernel(const int* __restrict__ cnt, int* __restrict__ offs,
                             int* __restrict__ bsum, int n) {
  __shared__ int s[256];
  int b = blockIdx.x, t = threadIdx.x, i = b * 256 + t;
  int x = (i < n) ? cnt[i] : 0;
  s[t] = x;
  __syncthreads();
  for (int off = 1; off < 256; off <<= 1) {
    int y = (t >= off) ? s[t - off] : 0;
    __syncthreads();
    s[t] += y;
    __syncthreads();
  }
  if (i < n) offs[i] = s[t] - x;
  if (t == 255) bsum[b] = s[t];
}

__global__ void scan2_kernel(int* __restrict__ bsum, int* __restrict__ offs,
                             int nb, int n) {
  __shared__ int s[256];
  int t = threadIdx.x;
  int x = (t < nb) ? bsum[t] : 0;
  s[t] = x;
  __syncthreads();
  for (int off = 1; off < 256; off <<= 1) {
    int y = (t >= off) ? s[t - off] : 0;
    __syncthreads();
    s[t] += y;
    __syncthreads();
  }
  if (t < nb) bsum[t] = s[t] - x;
  if (t == 255) offs[n] = s[t];
}

__global__ void scan3_kernel(int* __restrict__ offs, const int* __restrict__ bsum, int n) {
  int i = blockIdx.x * 256 + threadIdx.x;
  if (i < n) offs[i] += bsum[blockIdx.x];
}

__global__ void copy_kernel(const int* __restrict__ a, int* __restrict__ b, int n) {
  int i = blockIdx.x * 256 + threadIdx.x;
  if (i < n) b[i] = a[i];
}

// fill: also materialize src (ssrc) and noisy time (stt) in sorted order
__global__ void fill_kernel(const int* __restrict__ flags, const void* __restrict__ eidx,
                            const void* __restrict__ rawt, const void* __restrict__ noise,
                            int* __restrict__ cursor, int* __restrict__ esorted,
                            int* __restrict__ ssrc, float* __restrict__ stt) {
  bool is64 = flags[0] != 0, fbf = flags[1] != 0;
  int e = blockIdx.x * 256 + threadIdx.x;
  if (e < NE) {
    int d = lddst(eidx, e, is64);
    if ((unsigned)d < NN) {
      int pos = atomicAdd(&cursor[d], 1);
      if ((unsigned)pos < NE) {
        esorted[pos] = e;
        int src = ldsrc(eidx, e, is64);
        if ((unsigned)src >= NN) src = 0;
        ssrc[pos] = src;
        stt[pos] = ldf(rawt, e, fbf) + ldf(noise, e, fbf);
      }
    }
  }
}

// ---------------- te_s[p][64] (f16, sorted order) — computed ONCE ----------------
__global__ __launch_bounds__(256) void te_kernel(
    const float* __restrict__ stt, const float* __restrict__ divt,
    u16* __restrict__ te_s) {
  int p = blockIdx.x * 4 + (threadIdx.x >> 6);
  if (p >= NE) return;
  int j = threadIdx.x & 63;
  float tt = stt[p];
  float arg = tt * divt[j >> 1];
  float te = (j & 1) ? cosf(arg) : sinf(arg);
  __half hv = __float2half(te);
  te_s[(size_t)p * 64 + j] = *(u16*)&hv;
}

// ---------------- weight transpose: W[K,256] -> dst[256][K] bf16 ----------------
__global__ void transw_kernel(const int* __restrict__ flags, const void* __restrict__ W,
                              u16* __restrict__ dst, int K) {
  bool fbf = flags[1] != 0;
  __shared__ u16 tile[64][65];
  int kb = blockIdx.x * 64, cb = blockIdx.y * 64;
  int tx = threadIdx.x & 63, ty = threadIdx.x >> 6;
  for (int i = ty; i < 64; i += 4)
    tile[tx][i] = f2bf(ldf(W, (kb + i) * HC + cb + tx, fbf));
  __syncthreads();
  for (int i = ty; i < 64; i += 4)
    dst[(size_t)(cb + i) * K + kb + tx] = tile[i][tx];
}

// ---------------- Wcomb rows: Wout[j][c] = sum_mm wt[j&63][h*64+mm] * Wqt[h*64+mm][c]
__global__ void wcomb_kernel(const int* __restrict__ flags, const void* __restrict__ wt,
                             const u16* __restrict__ Wqt, u16* __restrict__ Wout, int K) {
  bool fbf = flags[1] != 0;
  __shared__ float wrow[64];
  int j = blockIdx.x;
  int h = j >> 6;
  int c = threadIdx.x;
  if (threadIdx.x < 64)
    wrow[threadIdx.x] = ldf(wt, (j & 63) * HC + h * 64 + threadIdx.x, fbf);
  __syncthreads();
  float s = 0.f;
#pragma unroll 8
  for (int mm = 0; mm < 64; ++mm)
    s += wrow[mm] * bf2f(Wqt[(size_t)(h * 64 + mm) * K + c]);
  Wout[(size_t)j * K + c] = f2bf(s);
}

// ---------------- biasBig = [bq|bk|bv|bcomb] ----------------
__global__ void biasbig_kernel(const int* __restrict__ flags, const void* __restrict__ bq,
                               const void* __restrict__ bk, const void* __restrict__ bv,
                               const void* __restrict__ wt, float* __restrict__ biasBig) {
  bool fbf = flags[1] != 0;
  int b = blockIdx.x, t = threadIdx.x;
  if (b < 3) {
    const void* p = (b == 0) ? bq : (b == 1) ? bk : bv;
    biasBig[b * 256 + t] = ldf(p, t, fbf);
  } else {
    int j = t, h = j >> 6;
    float s = 0.f;
    for (int mm = 0; mm < 64; ++mm)
      s += ldf(bq, h * 64 + mm, fbf) * ldf(wt, (j & 63) * HC + h * 64 + mm, fbf);
    biasBig[768 + j] = s;
  }
}

// ---------------- qbt[n,h] = q[n,h,:] . bt[h,:] (q from qkvp, stride NB) ----------
__global__ __launch_bounds__(256) void qbt_kernel(
    const int* __restrict__ flags, const u16* __restrict__ qkvp,
    const void* __restrict__ bt, float* __restrict__ qbt) {
  bool fbf = flags[1] != 0;
  int t = threadIdx.x;
  int n = blockIdx.x;
  int h = t >> 6, j = t & 63;
  float pb = bf2f(qkvp[(size_t)n * NB + t]) * ldf(bt, t, fbf);
  for (int off = 32; off; off >>= 1) pb += __shfl_xor(pb, off);
  if (j == 0) qbt[n * 4 + h] = pb;
}

// ---------------- fused MFMA GEMM: C[M,1024](bf16) = A[M,K] @ WtBig^T + biasBig ----
template <bool AWS>
__global__ __launch_bounds__(256) void gemm_mfma(
    const int* __restrict__ flags, const void* __restrict__ Ap,
    const u16* __restrict__ Wt, const float* __restrict__ bias,
    u16* __restrict__ C, int M, int K) {
  bool fbf = flags[1] != 0;
  __shared__ u16 As[64][56];
  __shared__ u16 Bs[64][56];
  int tid = threadIdx.x;
  int rb = blockIdx.x * 64, cb = blockIdx.y * 64;
  int wave = tid >> 6, lane = tid & 63;
  int l15 = lane & 15, quad = lane >> 4;

  f32x4 acc[4];
#pragma unroll
  for (int mt = 0; mt < 4; ++mt)
#pragma unroll
    for (int r = 0; r < 4; ++r) acc[mt][r] = 0.f;

  int srow = tid >> 2;
  int skq  = (tid & 3) * 8;

  for (int kk = 0; kk < K; kk += 32) {
    bf16x8 av;
#pragma unroll
    for (int i = 0; i < 8; ++i) av[i] = 0;
    int grow = rb + srow;
    if (grow < M) {
      if constexpr (AWS) {
        av = *(const bf16x8*)((const u16*)Ap + (size_t)grow * K + kk + skq);
      } else {
        if (fbf) {
          av = *(const bf16x8*)((const u16*)Ap + (size_t)grow * K + kk + skq);
        } else {
          const float* A = (const float*)Ap + (size_t)grow * K + kk + skq;
#pragma unroll
          for (int i = 0; i < 8; ++i) av[i] = (short)f2bf(A[i]);
        }
      }
    }
    *(bf16x8*)&As[srow][skq] = av;
    *(bf16x8*)&Bs[srow][skq] =
        *(const bf16x8*)(Wt + (size_t)(cb + srow) * K + kk + skq);
    __syncthreads();

    bf16x8 bfrag = *(const bf16x8*)&Bs[wave * 16 + l15][quad * 8];
#pragma unroll
    for (int mt = 0; mt < 4; ++mt) {
      bf16x8 afrag = *(const bf16x8*)&As[mt * 16 + l15][quad * 8];
      acc[mt] = __builtin_amdgcn_mfma_f32_16x16x32_bf16(afrag, bfrag, acc[mt], 0, 0, 0);
    }
    __syncthreads();
  }

  int gcol = cb + wave * 16 + l15;
  float bv = bias[gcol];
#pragma unroll
  for (int mt = 0; mt < 4; ++mt) {
#pragma unroll
    for (int r = 0; r < 4; ++r) {
      int grow = rb + mt * 16 + quad * 4 + r;
      if (grow < M) C[(size_t)grow * NB + gcol] = f2bf(acc[mt][r] + bv);
    }
  }
}

// ---------------- fused alpha + ONLINE softmax + aggregation + relu, 2-edge unroll --
// One wave per node, single pass; two independent load chains per iteration.
// State updates applied sequentially per edge -> numerics identical to 1-edge loop.
__global__ __launch_bounds__(256) void aggfused_kernel(
    const int* __restrict__ flags, const int* __restrict__ ssrc,
    const int* __restrict__ offsets, const u16* __restrict__ te_s,
    const u16* __restrict__ qkvp, const float* __restrict__ qbt,
    u16* __restrict__ xout) {
  int w = threadIdx.x >> 6;
  int n = blockIdx.x * 4 + w;
  if (n >= NN) return;
  int lane = threadIdx.x & 63;
  int h = lane >> 4;
  int c = lane * 4;
  int s0 = offsets[n], s1 = offsets[n + 1];
  if (s0 < 0) s0 = 0;
  if (s1 > NE) s1 = NE;

  ushort4 q4 = *(const ushort4*)(qkvp + (size_t)n * NB + c);
  ushort4 p4 = *(const ushort4*)(qkvp + (size_t)n * NB + 768 + c);
  float qx = bf2f(q4.x), qy = bf2f(q4.y), qz = bf2f(q4.z), qw = bf2f(q4.w);
  float px = bf2f(p4.x), py = bf2f(p4.y), pz = bf2f(p4.z), pw = bf2f(p4.w);
  float qb = qbt[n * 4 + h];
  int jb = c & 63;

  float m = -INFINITY, denom = 0.f;
  float acc0 = 0.f, acc1 = 0.f, acc2 = 0.f, acc3 = 0.f;

  int p = s0;
  for (; p + 1 < s1; p += 2) {
    int srcA = ssrc[p], srcB = ssrc[p + 1];
    bool okA = (unsigned)srcA < NN, okB = (unsigned)srcB < NN;
    if (!okA) srcA = 0;
    if (!okB) srcB = 0;
    const u16* rowA = qkvp + (size_t)srcA * NB;
    const u16* rowB = qkvp + (size_t)srcB * NB;
    // six independent loads in flight
    ushort4 kA = *(const ushort4*)(rowA + 256 + c);
    ushort4 vA = *(const ushort4*)(rowA + 512 + c);
    ushort4 tA = *(const ushort4*)(te_s + (size_t)p * 64 + jb);
    ushort4 kB = *(const ushort4*)(rowB + 256 + c);
    ushort4 vB = *(const ushort4*)(rowB + 512 + c);
    ushort4 tB = *(const ushort4*)(te_s + (size_t)(p + 1) * 64 + jb);

    float aA = 0.f, aB = 0.f;
    {
      float s = qx * bf2f(kA.x) + __half2float(*(__half*)&tA.x) * px;
      s += qy * bf2f(kA.y) + __half2float(*(__half*)&tA.y) * py;
      s += qz * bf2f(kA.z) + __half2float(*(__half*)&tA.z) * pz;
      s += qw * bf2f(kA.w) + __half2float(*(__half*)&tA.w) * pw;
      float s2 = qx * bf2f(kB.x) + __half2float(*(__half*)&tB.x) * px;
      s2 += qy * bf2f(kB.y) + __half2float(*(__half*)&tB.y) * py;
      s2 += qz * bf2f(kB.z) + __half2float(*(__half*)&tB.z) * pz;
      s2 += qw * bf2f(kB.w) + __half2float(*(__half*)&tB.w) * pw;
      s += __shfl_xor(s, 1);   s2 += __shfl_xor(s2, 1);
      s += __shfl_xor(s, 2);   s2 += __shfl_xor(s2, 2);
      s += __shfl_xor(s, 4);   s2 += __shfl_xor(s2, 4);
      s += __shfl_xor(s, 8);   s2 += __shfl_xor(s2, 8);
      if (okA) aA = (s + qb) * 0.125f;
      if (okB) aB = (s2 + qb) * 0.125f;
    }
    // sequential state updates (same order as 1-edge loop)
    if (aA > m) {
      float sc = expf(m - aA);
      denom *= sc;
      acc0 *= sc; acc1 *= sc; acc2 *= sc; acc3 *= sc;
      m = aA;
    }
    {
      float ea = expf(aA - m);
      denom += ea;
      if (okA) {
        acc0 += ea * bf2f(vA.x);
        acc1 += ea * bf2f(vA.y);
        acc2 += ea * bf2f(vA.z);
        acc3 += ea * bf2f(vA.w);
      }
    }
    if (aB > m) {
      float sc = expf(m - aB);
      denom *= sc;
      acc0 *= sc; acc1 *= sc; acc2 *= sc; acc3 *= sc;
      m = aB;
    }
    {
      float ea = expf(aB - m);
      denom += ea;
      if (okB) {
        acc0 += ea * bf2f(vB.x);
        acc1 += ea * bf2f(vB.y);
        acc2 += ea * bf2f(vB.z);
        acc3 += ea * bf2f(vB.w);
      }
    }
  }
  // tail edge
  for (; p < s1; ++p) {
    int src = ssrc[p];
    bool ok = (unsigned)src < NN;
    if (!ok) src = 0;
    const u16* row = qkvp + (size_t)src * NB;
    ushort4 k4 = *(const ushort4*)(row + 256 + c);
    ushort4 v4 = *(const ushort4*)(row + 512 + c);
    ushort4 t4 = *(const ushort4*)(te_s + (size_t)p * 64 + jb);
    float a = 0.f;
    if (ok) {
      float s = qx * bf2f(k4.x) + __half2float(*(__half*)&t4.x) * px;
      s += qy * bf2f(k4.y) + __half2float(*(__half*)&t4.y) * py;
      s += qz * bf2f(k4.z) + __half2float(*(__half*)&t4.z) * pz;
      s += qw * bf2f(k4.w) + __half2float(*(__half*)&t4.w) * pw;
      s += __shfl_xor(s, 1);
      s += __shfl_xor(s, 2);
      s += __shfl_xor(s, 4);
      s += __shfl_xor(s, 8);
      a = (s + qb) * 0.125f;
    }
    if (a > m) {
      float sc = expf(m - a);
      denom *= sc;
      acc0 *= sc; acc1 *= sc; acc2 *= sc; acc3 *= sc;
      m = a;
    }
    float ea = expf(a - m);
    denom += ea;
    if (ok) {
      acc0 += ea * bf2f(v4.x);
      acc1 += ea * bf2f(v4.y);
      acc2 += ea * bf2f(v4.z);
      acc3 += ea * bf2f(v4.w);
    }
  }

  float inv = 1.f / (denom + 1e-16f);
  ushort4 r;
  r.x = f2bf(fmaxf(acc0 * inv, 0.f));
  r.y = f2bf(fmaxf(acc1 * inv, 0.f));
  r.z = f2bf(fmaxf(acc2 * inv, 0.f));
  r.w = f2bf(fmaxf(acc3 * inv, 0.f));
  *(ushort4*)(xout + (size_t)n * HC + c) = r;
}

// ---------------- y[n] = x[n,:] . wc ----------------
__global__ __launch_bounds__(256) void xwc_kernel(
    const int* __restrict__ flags, const u16* __restrict__ x,
    const void* __restrict__ wc, float* __restrict__ y) {
  bool fbf = flags[1] != 0;
  int n = blockIdx.x * 4 + (threadIdx.x >> 6);
  if (n >= NN) return;
  int lane = threadIdx.x & 63;
  int c = lane * 4;
  ushort4 x4 = *(const ushort4*)(x + (size_t)n * HC + c);
  float s = bf2f(x4.x) * ldf(wc, c + 0, fbf);
  s += bf2f(x4.y) * ldf(wc, c + 1, fbf);
  s += bf2f(x4.z) * ldf(wc, c + 2, fbf);
  s += bf2f(x4.w) * ldf(wc, c + 3, fbf);
  for (int off = 32; off; off >>= 1) s += __shfl_xor(s, off);
  if (lane == 0) y[n] = s;
}

// ---------------- out[e] = y[src] + y[dst] + bc ----------------
__global__ __launch_bounds__(256) void final2_kernel(
    const int* __restrict__ flags, const void* __restrict__ eidx,
    const float* __restrict__ y, const void* __restrict__ bc,
    void* __restrict__ out) {
  bool is64 = flags[0] != 0, fbf = flags[1] != 0;
  int e = blockIdx.x * 256 + threadIdx.x;
  if (e >= NE) return;
  int src = ldsrc(eidx, e, is64);
  int dst = lddst(eidx, e, is64);
  if ((unsigned)src >= NN) src = 0;
  if ((unsigned)dst >= NN) dst = 0;
  stout(out, e, y[src] + y[dst] + ldf(bc, 0, fbf), fbf);
}

extern "C" void kernel_launch(void* const* d_in, const int* in_sizes, int n_in,
                              void* d_out, int out_size, void* d_ws, size_t ws_size,
                              hipStream_t stream) {
  const void* eidx  = d_in[0];
  const void* rawt  = d_in[1];
  const void* noise = d_in[2];
  const void* nemb  = d_in[3];
  const void *wq1 = d_in[4],  *bq1 = d_in[5];
  const void *wk1 = d_in[6],  *bk1 = d_in[7];
  const void *wv1 = d_in[8],  *bv1 = d_in[9];
  const void *wt1 = d_in[10], *bt1 = d_in[11];
  const void *wq2 = d_in[12], *bq2 = d_in[13];
  const void *wk2 = d_in[14], *bk2 = d_in[15];
  const void *wv2 = d_in[16], *bv2 = d_in[17];
  const void *wt2 = d_in[18], *bt2 = d_in[19];
  const void *wcp = d_in[20], *bcp = d_in[21];

  char* ws = (char*)d_ws;
  size_t off = 0;
  auto alloc = [&](size_t bytes) -> void* {
    void* p = ws + off;
    off += (bytes + 255) & ~(size_t)255;
    return p;
  };
  int*   flags  = (int*)alloc(256);
  float* divt   = (float*)alloc(256);
  u16*   WtBig  = (u16*)alloc((size_t)NB * HC * 2);
  float* biasBig= (float*)alloc((size_t)NB * 4);
  u16*   qkvp   = (u16*)alloc((size_t)NN * NB * 2);
  u16*   x1     = (u16*)alloc((size_t)NN * HC * 2);
  u16*   x2     = (u16*)alloc((size_t)NN * HC * 2);
  float* qbt    = (float*)alloc((size_t)NN * 4 * 4);
  float* ynode  = (float*)alloc((size_t)NN * 4);
  int* offsets  = (int*)alloc((size_t)(NN + 1) * 4);
  int* cursor   = (int*)alloc((size_t)NN * 4);
  int* bsum     = (int*)alloc(256 * 4);
  int* esorted  = (int*)alloc((size_t)NE * 4);
  int* ssrc     = (int*)alloc((size_t)NE * 4);
  float* stt    = (float*)alloc((size_t)NE * 4);
  u16* te_s     = (u16*)alloc((size_t)NE * 64 * 2);
  size_t need = off;

  int gN = (NN + 255) / 256, gE = (NE + 255) / 256;
  int nb = (NN + 255) / 256;

  if (ws_size < 1024) {
    raw_sentinel_kernel<<<gE, 256, 0, stream>>>((u16*)d_out);
    return;
  }
  devinit_kernel<<<1, 64, 0, stream>>>(eidx, nemb, flags, divt);
  if (need > ws_size) {
    sentinel_kernel<<<gE, 256, 0, stream>>>(flags, d_out);
    return;
  }

  // CSR by dst (+ sorted src / time)
  zero_kernel<<<gN, 256, 0, stream>>>(cursor, NN);
  hist_kernel<<<gE, 256, 0, stream>>>(flags, eidx, cursor);
  scan1_kernel<<<nb, 256, 0, stream>>>(cursor, offsets, bsum, NN);
  scan2_kernel<<<1, 256, 0, stream>>>(bsum, offsets, nb, NN);
  scan3_kernel<<<nb, 256, 0, stream>>>(offsets, bsum, NN);
  copy_kernel<<<gN, 256, 0, stream>>>(offsets, cursor, NN);
  fill_kernel<<<gE, 256, 0, stream>>>(flags, eidx, rawt, noise, cursor, esorted, ssrc, stt);

  int gEdge4 = (NE + 3) / 4;
  te_kernel<<<gEdge4, 256, 0, stream>>>(stt, divt, te_s);   // once for both layers

  dim3 ggemm((NN + 63) / 64, NB / 64);   // 313 x 16
  dim3 gt1(NIN / 64, 4), gt2(HC / 64, 4);
  int gNode = (NN + 3) / 4;

  // ---- Layer 1 (A = raw node_emb, K=128) ----
  transw_kernel<<<gt1, 256, 0, stream>>>(flags, wq1, WtBig + 0 * NIN, NIN);
  transw_kernel<<<gt1, 256, 0, stream>>>(flags, wk1, WtBig + (size_t)256 * NIN, NIN);
  transw_kernel<<<gt1, 256, 0, stream>>>(flags, wv1, WtBig + (size_t)512 * NIN, NIN);
  wcomb_kernel<<<256, NIN, 0, stream>>>(flags, wt1, WtBig, WtBig + (size_t)768 * NIN, NIN);
  biasbig_kernel<<<4, 256, 0, stream>>>(flags, bq1, bk1, bv1, wt1, biasBig);
  gemm_mfma<false><<<ggemm, 256, 0, stream>>>(flags, nemb, WtBig, biasBig, qkvp, NN, NIN);
  qbt_kernel<<<NN, 256, 0, stream>>>(flags, qkvp, bt1, qbt);
  aggfused_kernel<<<gNode, 256, 0, stream>>>(flags, ssrc, offsets, te_s, qkvp, qbt, x1);

  // ---- Layer 2 (A = bf16 x1, K=256) ----
  transw_kernel<<<gt2, 256, 0, stream>>>(flags, wq2, WtBig + 0 * HC, HC);
  transw_kernel<<<gt2, 256, 0, stream>>>(flags, wk2, WtBig + (size_t)256 * HC, HC);
  transw_kernel<<<gt2, 256, 0, stream>>>(flags, wv2, WtBig + (size_t)512 * HC, HC);
  wcomb_kernel<<<256, HC, 0, stream>>>(flags, wt2, WtBig, WtBig + (size_t)768 * HC, HC);
  biasbig_kernel<<<4, 256, 0, stream>>>(flags, bq2, bk2, bv2, wt2, biasBig);
  gemm_mfma<true><<<ggemm, 256, 0, stream>>>(flags, x1, WtBig, biasBig, qkvp, NN, HC);
  qbt_kernel<<<NN, 256, 0, stream>>>(flags, qkvp, bt2, qbt);
  aggfused_kernel<<<gNode, 256, 0, stream>>>(flags, ssrc, offsets, te_s, qkvp, qbt, x2);

  // Edge scorer: y[n] = x2[n].wc, then out[e] = y[src]+y[dst]+bc
  xwc_kernel<<<gNode, 256, 0, stream>>>(flags, x2, wcp, ynode);
  final2_kernel<<<gE, 256, 0, stream>>>(flags, eidx, ynode, bcp, d_out);
}